// Round 4
// baseline (477.513 us; speedup 1.0000x reference)
//
#include <hip/hip_runtime.h>
#include <hip/hip_bf16.h>

#define N_NODES  20000
#define MPAD     20096
#define N_EDGES  320000
#define N_EP     (N_EDGES + N_NODES)
#define D_IN     256
#define N_GRAPHS 32
#define HH1 4
#define CC1 128
#define HH2 4
#define CC2 64
#define MAXDEG   128

// ---- workspace layout (bytes) ----
#define XB_OFF      0ull                    // 10,289,152 : x bf16 [MPAD,256]
#define HB1_OFF     10289152ull             // 20,578,304 : h1 bf16 [MPAD,512]
#define AGG1_OFF    30867456ull             // 20,578,304 : agg1 bf16 [MPAD,512] (in-place BN)
#define HB2_OFF     51445760ull             // 10,289,152 : h2 bf16 [MPAD,256]
#define OUT2_OFF    61734912ull             //  5,120,000 : head-mean fp32 [20000,64] (pre-BN)
#define EAF_OFF     66854912ull             //  1,280,000
#define W1BT_OFF    68134912ull             //    262,144
#define W2BT_OFF    68397056ull             //    262,144
#define CSR_OFF     68659200ull             //  2,720,000 (int2: s, edge-id -> s, eav-bits)
#define ROWPTR_OFF  71379200ull             //     80,064
#define GSTART_OFF  71459264ull             //        256
#define SMALL_OFF   71459520ull             //     25,600
#define SBUF_OFF    71485120ull             //         64
#define EAP_OFF     71485184ull             //      1,280
#define PMU1_OFF    72772608ull             //    524,288
#define PM21_OFF    73296896ull             //    524,288
#define PMU2_OFF    73821184ull             //     65,536
#define PM22_OFF    73886720ull             //     65,536
#define A1_OFF      73952256ull             //      2,048
#define B1_OFF      73954304ull             //      2,048
#define A2_OFF      73956352ull             //        256
#define B2_OFF      73956608ull             //        256
#define EAACC_OFF   73956864ull             //         64
// ---- zeroed-at-start region ----
#define DEG_OFF     74600000ull             //     80,000
#define CURS_OFF    74680000ull             //     80,000
#define FLAGZ_OFF   74760000ull             //        128
#define PP_OFF      74760128ull             //     65,536 (unused-zeroing harmless)
#define ALS1_OFF    74825664ull             //    321,536 : layer1 als [MPAD*4] (atomic-accum)
#define ALD1_OFF    75147200ull             //    321,536
#define ALS2_OFF    75468736ull             //    321,536 : layer2
#define ALD2_OFF    75790272ull             //    321,536
#define ZERO0_START DEG_OFF
#define ZERO0_SIZE  1511808ull              // deg+cursor+flag+pp+als/ald x4

// small-region float offsets
#define S_AS1 0
#define S_AD1 512
#define S_WE1 1024
#define S_AE1 1536
#define S_G1  2048
#define S_BE1 2560
#define S_AS2 3072
#define S_AD2 3328
#define S_WE2 3584
#define S_AE2 3840
#define S_G2  4096
#define S_BE2 4160
#define S_FW1 4224
#define S_FB1 6272
#define S_FW2 6304
#define S_FB2 6336

typedef __attribute__((ext_vector_type(8))) short bf8_t;
typedef __attribute__((ext_vector_type(4))) float f4_t;

// ---- detect fp32 (1) vs bf16 (0); flag pre-zeroed ----
__global__ void detect_dtype(const unsigned short* __restrict__ xr, int* __restrict__ flag) {
    int i = blockIdx.x * blockDim.x + threadIdx.x;
    unsigned short u = xr[i];
    if ((u & 0x7F80) == 0x7F80) atomicOr(flag, 1);
}

__device__ __forceinline__ float loadF(const void* p, int i, int fp32) {
    return fp32 ? ((const float*)p)[i]
                : __bfloat162float(((const __hip_bfloat16*)p)[i]);
}

// ---- fused prep ----
#define PB_XB  5024
#define PB_EAF 313
#define PB_W   512
#define PB_SM  16
#define PREP_BLOCKS (PB_XB + PB_EAF + 2 * PB_W + PB_SM + 1)
__global__ __launch_bounds__(256) void prep(
        const int* __restrict__ flag,
        const void* x, const void* ea, const void* W1, const void* W2,
        const void* as1, const void* ad1, const void* We1, const void* ae1,
        const void* g1, const void* be1, const void* as2, const void* ad2,
        const void* We2, const void* ae2, const void* g2, const void* be2,
        const void* fw1, const void* fb1, const void* fw2, const void* fb2,
        __hip_bfloat16* __restrict__ xb, float* __restrict__ eaf, float* __restrict__ eap,
        __hip_bfloat16* __restrict__ W1bt, __hip_bfloat16* __restrict__ W2bt,
        float* __restrict__ smalls, float* __restrict__ sbuf) {
    __shared__ float sh[256];
    int b = blockIdx.x, t = threadIdx.x;
    int fp32 = flag[0];
    if (b < PB_XB) {
        int base = (b * 256 + t) * 4;
        __hip_bfloat16 tmp[4];
#pragma unroll
        for (int j = 0; j < 4; ++j) {
            int i = base + j;
            float v = (i < N_NODES * D_IN) ? loadF(x, i, fp32) : 0.f;
            tmp[j] = __float2bfloat16(v);
        }
        *(uint2*)&xb[base] = *(uint2*)tmp;
        return;
    }
    b -= PB_XB;
    if (b < PB_EAF) {
        int base = (b * 256 + t) * 4;
        float s = 0.f;
#pragma unroll
        for (int j = 0; j < 4; ++j) {
            int i = base + j;
            if (i < N_EDGES) { float v = loadF(ea, i, fp32); eaf[i] = v; s += v; }
        }
        sh[t] = s;
        __syncthreads();
        for (int st = 128; st; st >>= 1) {
            if (t < st) sh[t] += sh[t + st];
            __syncthreads();
        }
        if (t == 0) eap[b] = sh[0];
        return;
    }
    b -= PB_EAF;
    if (b < PB_W) {
        int i = b * 256 + t;
        int k = i >> 9, n = i & 511;
        W1bt[(size_t)n * 256 + k] = __float2bfloat16(loadF(W1, i, fp32));
        return;
    }
    b -= PB_W;
    if (b < PB_W) {
        int i = b * 256 + t;
        int k = i >> 8, n = i & 255;
        W2bt[(size_t)n * 512 + k] = __float2bfloat16(loadF(W2, i, fp32));
        return;
    }
    b -= PB_W;
    if (b < PB_SM) {
        const void* srcs[16] = {as1, ad1, We1, ae1, g1, be1, as2, ad2, We2, ae2, g2, be2, fw1, fb1, fw2, fb2};
        const int cnts[16] = {512, 512, 512, 512, 512, 512, 256, 256, 256, 256, 64, 64, 2048, 32, 32, 1};
        const int offs[16] = {S_AS1, S_AD1, S_WE1, S_AE1, S_G1, S_BE1, S_AS2, S_AD2,
                              S_WE2, S_AE2, S_G2, S_BE2, S_FW1, S_FB1, S_FW2, S_FB2};
        for (int i = t; i < cnts[b]; i += 256)
            smalls[offs[b] + i] = loadF(srcs[b], i, fp32);
        return;
    }
    if (t < 4) {
        float s = 0.f;
        for (int c = 0; c < CC1; ++c) s += loadF(We1, t * CC1 + c, fp32) * loadF(ae1, t * CC1 + c, fp32);
        sbuf[t] = s;
    } else if (t < 8) {
        int h = t - 4;
        float s = 0.f;
        for (int c = 0; c < CC2; ++c) s += loadF(We2, h * CC2 + c, fp32) * loadF(ae2, h * CC2 + c, fp32);
        sbuf[4 + h] = s;
    }
}

// ---- fused hist + graph bounds ----
#define HIST_BLOCKS 1329
__global__ void hist_bounds(const int* __restrict__ ei, int* __restrict__ deg,
                            const int* __restrict__ batch, int* __restrict__ gstart) {
    int b = blockIdx.x, t = threadIdx.x;
    if (b < HIST_BLOCKS) {
        int e = b * 256 + t;
        if (e >= N_EP) return;
        int d = (e < N_EDGES) ? ei[N_EDGES + e] : e - N_EDGES;
        atomicAdd(&deg[d], 1);
        return;
    }
    int i = (b - HIST_BLOCKS) * 256 + t;
    if (i >= N_NODES) return;
    int bb = batch[i];
    if (i == 0) {
        for (int g = 0; g <= bb; ++g) gstart[g] = 0;
    } else {
        int pb = batch[i - 1];
        for (int g = pb + 1; g <= bb; ++g) gstart[g] = i;
    }
    if (i == N_NODES - 1) {
        for (int g = bb + 1; g <= N_GRAPHS; ++g) gstart[g] = N_NODES;
    }
}

__global__ __launch_bounds__(1024) void deg_scan(const int* __restrict__ deg, int* __restrict__ rowptr,
                                                 const float* __restrict__ eap, float* __restrict__ ea_acc) {
    __shared__ int part[1024];
    __shared__ float fsh[512];
    int t = threadIdx.x;
    int lo = t * 20;
    int hi = lo + 20; if (hi > N_NODES) hi = N_NODES; if (lo > N_NODES) lo = N_NODES;
    int s = 0;
    for (int i = lo; i < hi; ++i) s += deg[i];
    part[t] = s;
    __syncthreads();
    for (int off = 1; off < 1024; off <<= 1) {
        int u = (t >= off) ? part[t - off] : 0;
        __syncthreads();
        if (t >= off) part[t] += u;
        __syncthreads();
    }
    int run = part[t] - s;
    for (int i = lo; i < hi; ++i) { rowptr[i] = run; run += deg[i]; }
    if (hi == N_NODES && lo < N_NODES) rowptr[N_NODES] = run;
    // parallel eap reduction (was serial on t==0)
    if (t < 512) fsh[t] = (t < PB_EAF) ? eap[t] : 0.f;
    __syncthreads();
    for (int st = 256; st; st >>= 1) {
        if (t < st) fsh[t] += fsh[t + st];
        __syncthreads();
    }
    if (t == 0) ea_acc[0] = fsh[0];
}

__global__ void edge_scatter(const int* __restrict__ ei, const int* __restrict__ rowptr,
                             int* __restrict__ cursor, int2* __restrict__ csr_se) {
    int e = blockIdx.x * blockDim.x + threadIdx.x;
    if (e >= N_EP) return;
    int s, d;
    if (e < N_EDGES) { s = ei[e]; d = ei[N_EDGES + e]; }
    else { s = d = e - N_EDGES; }
    int pos = rowptr[d] + atomicAdd(&cursor[d], 1);
    csr_se[pos] = make_int2(s, e);
}

// ---- canonical CSR sort (parallel odd-even, unique keys => deterministic) + eav fill ----
__global__ __launch_bounds__(64) void csr_sort_fill(const int* __restrict__ rowptr, int2* __restrict__ cs,
                                                    const float* __restrict__ eaf,
                                                    const float* __restrict__ ea_acc) {
    __shared__ int2 buf[128];
    int d = blockIdx.x;
    int beg = rowptr[d], end = rowptr[d + 1], n = end - beg;
    int lane = threadIdx.x;
    float ea_mean = ea_acc[0] * (1.0f / N_EDGES);
    if (n <= 0) return;
    if (n <= 128) {
        for (int i = lane; i < n; i += 64) buf[i] = cs[beg + i];
        __syncthreads();
        for (int r = 0; r < n; ++r) {
            int i = 2 * lane + (r & 1);
            if (i + 1 < n) {
                int2 a = buf[i], b = buf[i + 1];
                if (a.y > b.y) { buf[i] = b; buf[i + 1] = a; }
            }
            __syncthreads();
        }
        for (int i = lane; i < n; i += 64) {
            int2 se = buf[i];
            float eav = (se.y < N_EDGES) ? eaf[se.y] : ea_mean;
            se.y = __float_as_int(eav);
            cs[beg + i] = se;
        }
    } else {
        if (lane == 0) {
            for (int i = beg + 1; i < end; ++i) {
                int2 key = cs[i]; int j = i - 1;
                while (j >= beg && cs[j].y > key.y) { cs[j + 1] = cs[j]; --j; }
                cs[j + 1] = key;
            }
        }
        __syncthreads();
        for (int i = lane; i < n; i += 64) {
            int2 se = cs[beg + i];
            float eav = (se.y < N_EDGES) ? eaf[se.y] : ea_mean;
            se.y = __float_as_int(eav);
            cs[beg + i] = se;
        }
    }
}

// ---- MFMA bf16 GEMM + al epilogue: atomicAdd into pre-zeroed als/ald ----
// (exactly <=2 contributions per slot from 0: fp add is commutative -> deterministic)
__global__ __launch_bounds__(256) void gemm_mfma_al(
        const short* __restrict__ A, const short* __restrict__ Bt,
        __hip_bfloat16* __restrict__ Cb, int N, int K,
        float* __restrict__ als, float* __restrict__ ald,
        const float* __restrict__ asv, const float* __restrict__ adv, int cshift) {
    __shared__ short As[128 * 40];
    __shared__ short Bs[64 * 40];
    int t = threadIdx.x;
    int wv = t >> 6, lane = t & 63, quad = lane >> 4, lr = lane & 15;
    int m0 = blockIdx.y * 128, n0 = blockIdx.x * 64;
    f4_t acc[2][4] = {};
    int ra0 = t >> 2, sa0 = t & 3;
    int ra1 = (t + 256) >> 2;
    for (int k0 = 0; k0 < K; k0 += 32) {
        *(uint4*)&As[ra0 * 40 + sa0 * 8] = *(const uint4*)&A[(size_t)(m0 + ra0) * K + k0 + sa0 * 8];
        *(uint4*)&As[ra1 * 40 + sa0 * 8] = *(const uint4*)&A[(size_t)(m0 + ra1) * K + k0 + sa0 * 8];
        *(uint4*)&Bs[ra0 * 40 + sa0 * 8] = *(const uint4*)&Bt[(size_t)(n0 + ra0) * K + k0 + sa0 * 8];
        __syncthreads();
        bf8_t a0 = *(const bf8_t*)&As[(wv * 16 + lr) * 40 + quad * 8];
        bf8_t a1 = *(const bf8_t*)&As[((wv + 4) * 16 + lr) * 40 + quad * 8];
#pragma unroll
        for (int nt = 0; nt < 4; ++nt) {
            bf8_t b = *(const bf8_t*)&Bs[(nt * 16 + lr) * 40 + quad * 8];
            acc[0][nt] = __builtin_amdgcn_mfma_f32_16x16x32_bf16(a0, b, acc[0][nt], 0, 0, 0);
            acc[1][nt] = __builtin_amdgcn_mfma_f32_16x16x32_bf16(a1, b, acc[1][nt], 0, 0, 0);
        }
        __syncthreads();
    }
#pragma unroll
    for (int si = 0; si < 2; ++si) {
        int mrow = m0 + (wv + si * 4) * 16 + quad * 4;
#pragma unroll
        for (int nt = 0; nt < 4; ++nt) {
            int col = n0 + nt * 16 + lr;
#pragma unroll
            for (int r = 0; r < 4; ++r)
                Cb[(size_t)(mrow + r) * N + col] = __float2bfloat16(acc[si][nt][r]);
        }
    }
    float asv4[4], adv4[4];
#pragma unroll
    for (int nt = 0; nt < 4; ++nt) {
        asv4[nt] = asv[n0 + nt * 16 + lr];
        adv4[nt] = adv[n0 + nt * 16 + lr];
    }
    int hsel = n0 >> cshift;
#pragma unroll
    for (int si = 0; si < 2; ++si) {
#pragma unroll
        for (int r = 0; r < 4; ++r) {
            float ps = 0.f, pd = 0.f;
#pragma unroll
            for (int nt = 0; nt < 4; ++nt) {
                ps += acc[si][nt][r] * asv4[nt];
                pd += acc[si][nt][r] * adv4[nt];
            }
#pragma unroll
            for (int m = 1; m < 16; m <<= 1) {
                ps += __shfl_xor(ps, m);
                pd += __shfl_xor(pd, m);
            }
            if (lr == 0) {
                int row = m0 + (wv + si * 4) * 16 + quad * 4 + r;
                atomicAdd(&als[row * 4 + hsel], ps);
                atomicAdd(&ald[row * 4 + hsel], pd);
            }
        }
    }
}

// ---- FUSED deterministic softmax+agg, layer 1: ONE WAVE per dst (4 dst / 256-thr block) ----
__global__ __launch_bounds__(256) void fused_agg1(
        const int* __restrict__ rowptr, const int2* __restrict__ cs,
        const float* __restrict__ als, const float* __restrict__ ald,
        const float* __restrict__ sbuf, const __hip_bfloat16* __restrict__ hb,
        __hip_bfloat16* __restrict__ outb) {
    __shared__ float lg[4][MAXDEG * 4];
    __shared__ int   ssrc[4][MAXDEG];
    int wv = threadIdx.x >> 6, t = threadIdx.x & 63;
    int d = blockIdx.x * 4 + wv;
    int beg = rowptr[d], n = rowptr[d + 1] - beg;
    bool fit = (n <= MAXDEG);
    float4 adv = *(const float4*)&ald[d * 4];
    float adh[4] = {adv.x, adv.y, adv.z, adv.w};
    float sb4[4] = {sbuf[0], sbuf[1], sbuf[2], sbuf[3]};
    float mx[4] = {-INFINITY, -INFINITY, -INFINITY, -INFINITY};
    for (int p = t; p < n; p += 64) {
        int2 se = cs[beg + p];
        float eav = __int_as_float(se.y);
        float4 as = *(const float4*)&als[se.x * 4];
        float l[4] = {as.x, as.y, as.z, as.w};
#pragma unroll
        for (int hh = 0; hh < 4; ++hh) {
            float v = l[hh] + adh[hh] + eav * sb4[hh];
            v = v > 0.f ? v : 0.2f * v;
            l[hh] = v;
            mx[hh] = fmaxf(mx[hh], v);
        }
        if (fit) {
            *(float4*)&lg[wv][p * 4] = make_float4(l[0], l[1], l[2], l[3]);
            ssrc[wv][p] = se.x;
        }
    }
#pragma unroll
    for (int m = 1; m < 64; m <<= 1)
#pragma unroll
        for (int hh = 0; hh < 4; ++hh)
            mx[hh] = fmaxf(mx[hh], __shfl_xor(mx[hh], m));
    // wave-local LDS producer/consumer: drain this wave's LDS writes only.
    asm volatile("s_waitcnt lgkmcnt(0)" ::: "memory");
    int h = t >> 4;                       // 8 channels/lane, 128 ch/head -> head = t>>4
    float mh = mx[h];
    float a[8] = {};
    float ds = 0.f;
    const __hip_bfloat16* hrow = hb + 8 * t;
#define ACC8(rr, wt) { \
    unsigned q0 = (rr).x, q1 = (rr).y, q2 = (rr).z, q3 = (rr).w; \
    a[0] += (wt) * __uint_as_float(q0 << 16); a[1] += (wt) * __uint_as_float(q0 & 0xFFFF0000u); \
    a[2] += (wt) * __uint_as_float(q1 << 16); a[3] += (wt) * __uint_as_float(q1 & 0xFFFF0000u); \
    a[4] += (wt) * __uint_as_float(q2 << 16); a[5] += (wt) * __uint_as_float(q2 & 0xFFFF0000u); \
    a[6] += (wt) * __uint_as_float(q3 << 16); a[7] += (wt) * __uint_as_float(q3 & 0xFFFF0000u); }
    if (fit) {
        int p = 0;
        for (; p + 8 <= n; p += 8) {
            int s0 = ssrc[wv][p],     s1 = ssrc[wv][p + 1], s2 = ssrc[wv][p + 2], s3 = ssrc[wv][p + 3];
            int s4 = ssrc[wv][p + 4], s5 = ssrc[wv][p + 5], s6 = ssrc[wv][p + 6], s7 = ssrc[wv][p + 7];
            uint4 r0 = *(const uint4*)&hrow[(size_t)s0 * 512];
            uint4 r1 = *(const uint4*)&hrow[(size_t)s1 * 512];
            uint4 r2 = *(const uint4*)&hrow[(size_t)s2 * 512];
            uint4 r3 = *(const uint4*)&hrow[(size_t)s3 * 512];
            uint4 r4 = *(const uint4*)&hrow[(size_t)s4 * 512];
            uint4 r5 = *(const uint4*)&hrow[(size_t)s5 * 512];
            uint4 r6 = *(const uint4*)&hrow[(size_t)s6 * 512];
            uint4 r7 = *(const uint4*)&hrow[(size_t)s7 * 512];
            float w0 = __expf(lg[wv][p * 4 + h] - mh);
            float w1 = __expf(lg[wv][p * 4 + 4 + h] - mh);
            float w2 = __expf(lg[wv][p * 4 + 8 + h] - mh);
            float w3 = __expf(lg[wv][p * 4 + 12 + h] - mh);
            float w4 = __expf(lg[wv][p * 4 + 16 + h] - mh);
            float w5 = __expf(lg[wv][p * 4 + 20 + h] - mh);
            float w6 = __expf(lg[wv][p * 4 + 24 + h] - mh);
            float w7 = __expf(lg[wv][p * 4 + 28 + h] - mh);
            ds += ((w0 + w1) + (w2 + w3)) + ((w4 + w5) + (w6 + w7));
            ACC8(r0, w0); ACC8(r1, w1); ACC8(r2, w2); ACC8(r3, w3);
            ACC8(r4, w4); ACC8(r5, w5); ACC8(r6, w6); ACC8(r7, w7);
        }
        for (; p + 4 <= n; p += 4) {
            int s0 = ssrc[wv][p], s1 = ssrc[wv][p + 1], s2 = ssrc[wv][p + 2], s3 = ssrc[wv][p + 3];
            uint4 r0 = *(const uint4*)&hrow[(size_t)s0 * 512];
            uint4 r1 = *(const uint4*)&hrow[(size_t)s1 * 512];
            uint4 r2 = *(const uint4*)&hrow[(size_t)s2 * 512];
            uint4 r3 = *(const uint4*)&hrow[(size_t)s3 * 512];
            float w0 = __expf(lg[wv][p * 4 + h] - mh);
            float w1 = __expf(lg[wv][p * 4 + 4 + h] - mh);
            float w2 = __expf(lg[wv][p * 4 + 8 + h] - mh);
            float w3 = __expf(lg[wv][p * 4 + 12 + h] - mh);
            ds += (w0 + w1) + (w2 + w3);
            ACC8(r0, w0); ACC8(r1, w1); ACC8(r2, w2); ACC8(r3, w3);
        }
        for (; p < n; ++p) {
            int s0 = ssrc[wv][p];
            uint4 r0 = *(const uint4*)&hrow[(size_t)s0 * 512];
            float w0 = __expf(lg[wv][p * 4 + h] - mh);
            ds += w0;
            ACC8(r0, w0);
        }
    } else {
        for (int p = 0; p < n; ++p) {
            int2 se = cs[beg + p];
            float eav = __int_as_float(se.y);
            float l = als[se.x * 4 + h] + adh[h] + eav * sb4[h];
            l = l > 0.f ? l : 0.2f * l;
            float w = __expf(l - mh);
            uint4 r0 = *(const uint4*)&hrow[(size_t)se.x * 512];
            ds += w;
            ACC8(r0, w);
        }
    }
#undef ACC8
    float rdn = 1.0f / (ds + 1e-16f);
    __hip_bfloat16 tmp[8];
#pragma unroll
    for (int j = 0; j < 8; ++j) tmp[j] = __float2bfloat16(a[j] * rdn);
    *(uint4*)&outb[(size_t)d * 512 + 8 * t] = *(uint4*)tmp;
}

// ---- FUSED softmax+agg+head-mean, layer 2: ONE WAVE per dst (4 dst / 256-thr block) ----
__global__ __launch_bounds__(256) void fused_agg2(
        const int* __restrict__ rowptr, const int2* __restrict__ cs,
        const float* __restrict__ als, const float* __restrict__ ald,
        const float* __restrict__ sbuf, const __hip_bfloat16* __restrict__ hb,
        float* __restrict__ out2) {
    __shared__ float lg[4][MAXDEG * 4];
    __shared__ int   ssrc[4][MAXDEG];
    int wv = threadIdx.x >> 6, t = threadIdx.x & 63;
    int d = blockIdx.x * 4 + wv;
    int beg = rowptr[d], n = rowptr[d + 1] - beg;
    bool fit = (n <= MAXDEG);
    float4 adv = *(const float4*)&ald[d * 4];
    float adh[4] = {adv.x, adv.y, adv.z, adv.w};
    float sb4[4] = {sbuf[4], sbuf[5], sbuf[6], sbuf[7]};
    float mx[4] = {-INFINITY, -INFINITY, -INFINITY, -INFINITY};
    for (int p = t; p < n; p += 64) {
        int2 se = cs[beg + p];
        float eav = __int_as_float(se.y);
        float4 as = *(const float4*)&als[se.x * 4];
        float l[4] = {as.x, as.y, as.z, as.w};
#pragma unroll
        for (int hh = 0; hh < 4; ++hh) {
            float v = l[hh] + adh[hh] + eav * sb4[hh];
            v = v > 0.f ? v : 0.2f * v;
            l[hh] = v;
            mx[hh] = fmaxf(mx[hh], v);
        }
        if (fit) {
            *(float4*)&lg[wv][p * 4] = make_float4(l[0], l[1], l[2], l[3]);
            ssrc[wv][p] = se.x;
        }
    }
#pragma unroll
    for (int m = 1; m < 64; m <<= 1)
#pragma unroll
        for (int hh = 0; hh < 4; ++hh)
            mx[hh] = fmaxf(mx[hh], __shfl_xor(mx[hh], m));
    asm volatile("s_waitcnt lgkmcnt(0)" ::: "memory");
    int h = t >> 4;                       // 4 channels/lane, 64 ch/head -> head = t>>4
    float mh = mx[h];
    float a4[4] = {};
    float ds = 0.f;
    const __hip_bfloat16* hrow = hb + 4 * t;
#define ACC4(rr, wt) { \
    unsigned q0 = (rr).x, q1 = (rr).y; \
    a4[0] += (wt) * __uint_as_float(q0 << 16); a4[1] += (wt) * __uint_as_float(q0 & 0xFFFF0000u); \
    a4[2] += (wt) * __uint_as_float(q1 << 16); a4[3] += (wt) * __uint_as_float(q1 & 0xFFFF0000u); }
    if (fit) {
        int p = 0;
        for (; p + 8 <= n; p += 8) {
            int s0 = ssrc[wv][p],     s1 = ssrc[wv][p + 1], s2 = ssrc[wv][p + 2], s3 = ssrc[wv][p + 3];
            int s4 = ssrc[wv][p + 4], s5 = ssrc[wv][p + 5], s6 = ssrc[wv][p + 6], s7 = ssrc[wv][p + 7];
            uint2 r0 = *(const uint2*)&hrow[(size_t)s0 * 256];
            uint2 r1 = *(const uint2*)&hrow[(size_t)s1 * 256];
            uint2 r2 = *(const uint2*)&hrow[(size_t)s2 * 256];
            uint2 r3 = *(const uint2*)&hrow[(size_t)s3 * 256];
            uint2 r4 = *(const uint2*)&hrow[(size_t)s4 * 256];
            uint2 r5 = *(const uint2*)&hrow[(size_t)s5 * 256];
            uint2 r6 = *(const uint2*)&hrow[(size_t)s6 * 256];
            uint2 r7 = *(const uint2*)&hrow[(size_t)s7 * 256];
            float w0 = __expf(lg[wv][p * 4 + h] - mh);
            float w1 = __expf(lg[wv][p * 4 + 4 + h] - mh);
            float w2 = __expf(lg[wv][p * 4 + 8 + h] - mh);
            float w3 = __expf(lg[wv][p * 4 + 12 + h] - mh);
            float w4 = __expf(lg[wv][p * 4 + 16 + h] - mh);
            float w5 = __expf(lg[wv][p * 4 + 20 + h] - mh);
            float w6 = __expf(lg[wv][p * 4 + 24 + h] - mh);
            float w7 = __expf(lg[wv][p * 4 + 28 + h] - mh);
            ds += ((w0 + w1) + (w2 + w3)) + ((w4 + w5) + (w6 + w7));
            ACC4(r0, w0); ACC4(r1, w1); ACC4(r2, w2); ACC4(r3, w3);
            ACC4(r4, w4); ACC4(r5, w5); ACC4(r6, w6); ACC4(r7, w7);
        }
        for (; p + 4 <= n; p += 4) {
            int s0 = ssrc[wv][p], s1 = ssrc[wv][p + 1], s2 = ssrc[wv][p + 2], s3 = ssrc[wv][p + 3];
            uint2 r0 = *(const uint2*)&hrow[(size_t)s0 * 256];
            uint2 r1 = *(const uint2*)&hrow[(size_t)s1 * 256];
            uint2 r2 = *(const uint2*)&hrow[(size_t)s2 * 256];
            uint2 r3 = *(const uint2*)&hrow[(size_t)s3 * 256];
            float w0 = __expf(lg[wv][p * 4 + h] - mh);
            float w1 = __expf(lg[wv][p * 4 + 4 + h] - mh);
            float w2 = __expf(lg[wv][p * 4 + 8 + h] - mh);
            float w3 = __expf(lg[wv][p * 4 + 12 + h] - mh);
            ds += (w0 + w1) + (w2 + w3);
            ACC4(r0, w0); ACC4(r1, w1); ACC4(r2, w2); ACC4(r3, w3);
        }
        for (; p < n; ++p) {
            int s0 = ssrc[wv][p];
            uint2 r0 = *(const uint2*)&hrow[(size_t)s0 * 256];
            float w0 = __expf(lg[wv][p * 4 + h] - mh);
            ds += w0;
            ACC4(r0, w0);
        }
    } else {
        for (int p = 0; p < n; ++p) {
            int2 se = cs[beg + p];
            float eav = __int_as_float(se.y);
            float l = als[se.x * 4 + h] + adh[h] + eav * sb4[h];
            l = l > 0.f ? l : 0.2f * l;
            float w = __expf(l - mh);
            uint2 r0 = *(const uint2*)&hrow[(size_t)se.x * 256];
            ds += w;
            ACC4(r0, w);
        }
    }
#undef ACC4
    float rdn = 1.0f / (ds + 1e-16f);
    // normalize, then head-mean across lanes {t, t^16, t^32, t^48} (same local channel)
#pragma unroll
    for (int j = 0; j < 4; ++j) {
        float v = a4[j] * rdn;
        v += __shfl_xor(v, 16);
        v += __shfl_xor(v, 32);
        a4[j] = v * 0.25f;
    }
    if (t < 16)
        *(float4*)&out2[(size_t)d * 64 + 4 * t] = make_float4(a4[0], a4[1], a4[2], a4[3]);
}

// ---- BN1 stats: per-block partials ----
__global__ __launch_bounds__(256) void bn_part_b(const __hip_bfloat16* __restrict__ x,
                                                 float* __restrict__ pmu, float* __restrict__ pm2) {
    int t = threadIdx.x, b = blockIdx.x;
    float s0 = 0.f, s20 = 0.f, s1 = 0.f, s21 = 0.f;
    for (int i = b; i < N_NODES; i += gridDim.x) {
        unsigned u = *(const unsigned*)&x[(size_t)i * 512 + 2 * t];
        float v0 = __uint_as_float(u << 16);
        float v1 = __uint_as_float(u & 0xFFFF0000u);
        s0 += v0; s20 += v0 * v0; s1 += v1; s21 += v1 * v1;
    }
    pmu[b * 512 + 2 * t] = s0;     pm2[b * 512 + 2 * t] = s20;
    pmu[b * 512 + 2 * t + 1] = s1; pm2[b * 512 + 2 * t + 1] = s21;
}

// ---- reduce partials -> affine a,b (fixed order) ----
__global__ void bn_reduce_affine(const float* __restrict__ pmu, const float* __restrict__ pm2,
                                 const float* __restrict__ smalls, int s_g, int s_be,
                                 float* __restrict__ a, float* __restrict__ b, int nch) {
    int c = blockIdx.x * blockDim.x + threadIdx.x;
    if (c >= nch) return;
    float s = 0.f, s2 = 0.f;
    for (int bk = 0; bk < 256; ++bk) { s += pmu[bk * nch + c]; s2 += pm2[bk * nch + c]; }
    float m = s * (1.0f / N_NODES);
    float var = s2 * (1.0f / N_NODES) - m * m;
    float aa = smalls[s_g + c] * rsqrtf(var + 1e-5f);
    a[c] = aa;
    b[c] = smalls[s_be + c] - m * aa;
}

// ---- BN1 apply + ELU in place on bf16 [N_NODES,512] ----
__global__ __launch_bounds__(256) void bn_apply_elu_b16(__hip_bfloat16* __restrict__ x,
                                                        const float* __restrict__ a,
                                                        const float* __restrict__ b) {
    int q = blockIdx.x * blockDim.x + threadIdx.x;
    if (q >= N_NODES * 512 / 4) return;
    int base = q * 4;
    int j = base & 511;
    uint2 raw = *(uint2*)&x[base];
    float v[4] = {__uint_as_float(raw.x << 16), __uint_as_float(raw.x & 0xFFFF0000u),
                  __uint_as_float(raw.y << 16), __uint_as_float(raw.y & 0xFFFF0000u)};
    __hip_bfloat16 tmp[4];
#pragma unroll
    for (int k = 0; k < 4; ++k) {
        float y = a[j + k] * v[k] + b[j + k];
        y = y > 0.f ? y : expm1f(y);
        tmp[k] = __float2bfloat16(y);
    }
    *(uint2*)&x[base] = *(uint2*)tmp;
}

// ---- BN2 stats: per-block partials ----
__global__ __launch_bounds__(256) void bn2_stats(const float* __restrict__ x,
                                                 float* __restrict__ pmu, float* __restrict__ pm2) {
    int t = threadIdx.x;
    int c = t & 63, j = t >> 6;
    float ls = 0.f, ls2 = 0.f;
    for (int nd = blockIdx.x * 4 + j; nd < N_NODES; nd += gridDim.x * 4) {
        float v = x[(size_t)nd * 64 + c];
        ls += v; ls2 += v * v;
    }
    __shared__ float shs[4][64], sh2[4][64];
    shs[j][c] = ls; sh2[j][c] = ls2;
    __syncthreads();
    if (j == 0) {
        pmu[blockIdx.x * 64 + c] = shs[0][c] + shs[1][c] + shs[2][c] + shs[3][c];
        pm2[blockIdx.x * 64 + c] = sh2[0][c] + sh2[1][c] + sh2[2][c] + sh2[3][c];
    }
}

// ---- merged BN2-affine+ELU+mean-pool + MLP: one block per graph ----
__global__ __launch_bounds__(256) void pool_mlp(const float* __restrict__ x, const int* __restrict__ gstart,
                                                const float* __restrict__ a2, const float* __restrict__ b2,
                                                const float* __restrict__ smalls, const int* __restrict__ flag,
                                                void* __restrict__ outp) {
    int g = blockIdx.x, t = threadIdx.x;
    int c = t & 63, j = t >> 6;
    int beg = gstart[g], end = gstart[g + 1];
    float ac = a2[c], bc = b2[c];
    float s = 0.f;
    for (int i = beg + j; i < end; i += 4) {
        float y = ac * x[(size_t)i * 64 + c] + bc;
        s += (y > 0.f ? y : expm1f(y));
    }
    __shared__ float sh[4][64];
    __shared__ float pooled[64];
    __shared__ float hsh[32];
    sh[j][c] = s;
    __syncthreads();
    if (t < 64) {
        int n = end - beg;
        pooled[t] = (sh[0][t] + sh[1][t] + sh[2][t] + sh[3][t]) / fmaxf((float)n, 1.0f);
    }
    __syncthreads();
    if (t < 32) {
        float acc = smalls[S_FB1 + t];
        for (int cc = 0; cc < 64; ++cc)
            acc += pooled[cc] * smalls[S_FW1 + cc * 32 + t];
        hsh[t] = acc > 0.f ? acc : expm1f(acc);
    }
    __syncthreads();
    if (t == 0) {
        float o = smalls[S_FB2];
        for (int k = 0; k < 32; ++k) o += hsh[k] * smalls[S_FW2 + k];
        if (flag[0]) ((float*)outp)[g] = o;
        else ((__hip_bfloat16*)outp)[g] = __float2bfloat16(o);
    }
}

extern "C" void kernel_launch(void* const* d_in, const int* in_sizes, int n_in,
                              void* d_out, int out_size, void* d_ws, size_t ws_size,
                              hipStream_t stream) {
    const void* x    = d_in[0];
    const int* ei    = (const int*)d_in[1];
    const int* batch = (const int*)d_in[2];
    const void* ea   = d_in[3];
    const void* W1   = d_in[4];
    const void* as1  = d_in[5];
    const void* ad1  = d_in[6];
    const void* We1  = d_in[7];
    const void* ae1  = d_in[8];
    const void* g1   = d_in[10];
    const void* be1  = d_in[11];
    const void* W2   = d_in[12];
    const void* as2  = d_in[13];
    const void* ad2  = d_in[14];
    const void* We2  = d_in[15];
    const void* ae2  = d_in[16];
    const void* g2   = d_in[18];
    const void* be2  = d_in[19];
    const void* fw1  = d_in[20];
    const void* fb1  = d_in[21];
    const void* fw2  = d_in[22];
    const void* fb2  = d_in[23];

    char* ws = (char*)d_ws;
    __hip_bfloat16* xb   = (__hip_bfloat16*)(ws + XB_OFF);
    __hip_bfloat16* hb1  = (__hip_bfloat16*)(ws + HB1_OFF);
    __hip_bfloat16* agg1 = (__hip_bfloat16*)(ws + AGG1_OFF);
    __hip_bfloat16* hb2  = (__hip_bfloat16*)(ws + HB2_OFF);
    float* out2   = (float*)(ws + OUT2_OFF);
    float* eaf    = (float*)(ws + EAF_OFF);
    __hip_bfloat16* W1bt = (__hip_bfloat16*)(ws + W1BT_OFF);
    __hip_bfloat16* W2bt = (__hip_bfloat16*)(ws + W2BT_OFF);
    int2*  csr_se = (int2*)(ws + CSR_OFF);
    int*   rowptr = (int*)(ws + ROWPTR_OFF);
    int*   gstart = (int*)(ws + GSTART_OFF);
    float* smalls = (float*)(ws + SMALL_OFF);
    float* sbuf   = (float*)(ws + SBUF_OFF);
    float* eap    = (float*)(ws + EAP_OFF);
    float* pmu1   = (float*)(ws + PMU1_OFF);
    float* pm21   = (float*)(ws + PM21_OFF);
    float* pmu2   = (float*)(ws + PMU2_OFF);
    float* pm22   = (float*)(ws + PM22_OFF);
    float* a1     = (float*)(ws + A1_OFF);
    float* b1     = (float*)(ws + B1_OFF);
    float* a2     = (float*)(ws + A2_OFF);
    float* b2     = (float*)(ws + B2_OFF);
    float* ea_acc = (float*)(ws + EAACC_OFF);
    float* als1   = (float*)(ws + ALS1_OFF);
    float* ald1   = (float*)(ws + ALD1_OFF);
    float* als2   = (float*)(ws + ALS2_OFF);
    float* ald2   = (float*)(ws + ALD2_OFF);
    int*   deg    = (int*)(ws + DEG_OFF);
    int*   cursor = (int*)(ws + CURS_OFF);
    int*   flag   = (int*)(ws + FLAGZ_OFF);

    hipMemsetAsync(ws + ZERO0_START, 0, ZERO0_SIZE, stream);

    detect_dtype<<<256, 256, 0, stream>>>((const unsigned short*)x, flag);
    prep<<<PREP_BLOCKS, 256, 0, stream>>>(flag, x, ea, W1, W2,
                                          as1, ad1, We1, ae1, g1, be1, as2, ad2,
                                          We2, ae2, g2, be2, fw1, fb1, fw2, fb2,
                                          xb, eaf, eap, W1bt, W2bt, smalls, sbuf);

    hist_bounds<<<HIST_BLOCKS + 79, 256, 0, stream>>>(ei, deg, batch, gstart);
    deg_scan<<<1, 1024, 0, stream>>>(deg, rowptr, eap, ea_acc);
    edge_scatter<<<HIST_BLOCKS, 256, 0, stream>>>(ei, rowptr, cursor, csr_se);
    csr_sort_fill<<<N_NODES, 64, 0, stream>>>(rowptr, csr_se, eaf, ea_acc);

    // ---------- layer 1 ----------
    gemm_mfma_al<<<dim3(512 / 64, MPAD / 128), 256, 0, stream>>>(
        (const short*)xb, (const short*)W1bt, hb1, 512, 256,
        als1, ald1, smalls + S_AS1, smalls + S_AD1, 7);
    fused_agg1<<<N_NODES / 4, 256, 0, stream>>>(rowptr, csr_se, als1, ald1, sbuf, hb1, agg1);
    bn_part_b<<<256, 256, 0, stream>>>(agg1, pmu1, pm21);
    bn_reduce_affine<<<2, 256, 0, stream>>>(pmu1, pm21, smalls, S_G1, S_BE1, a1, b1, 512);
    bn_apply_elu_b16<<<10000, 256, 0, stream>>>(agg1, a1, b1);

    // ---------- layer 2 ----------
    gemm_mfma_al<<<dim3(256 / 64, MPAD / 128), 256, 0, stream>>>(
        (const short*)agg1, (const short*)W2bt, hb2, 256, 512,
        als2, ald2, smalls + S_AS2, smalls + S_AD2, 6);
    fused_agg2<<<N_NODES / 4, 256, 0, stream>>>(rowptr, csr_se, als2, ald2, sbuf, hb2, out2);
    bn2_stats<<<256, 256, 0, stream>>>(out2, pmu2, pm22);
    bn_reduce_affine<<<1, 64, 0, stream>>>(pmu2, pm22, smalls, S_G2, S_BE2, a2, b2, 64);

    // ---------- BN2+ELU+pool+MLP (merged) ----------
    pool_mlp<<<N_GRAPHS, 256, 0, stream>>>(out2, gstart, a2, b2, smalls, flag, d_out);
}

// Round 5
// 445.143 us; speedup vs baseline: 1.0727x; 1.0727x over previous
//
#include <hip/hip_runtime.h>
#include <hip/hip_bf16.h>

#define N_NODES  20000
#define MPAD     20096
#define N_EDGES  320000
#define N_EP     (N_EDGES + N_NODES)
#define D_IN     256
#define N_GRAPHS 32
#define HH1 4
#define CC1 128
#define HH2 4
#define CC2 64
#define MAXDEG   128

// ---- workspace layout (bytes) ----
#define XB_OFF      0ull                    // 10,289,152 : x bf16 [MPAD,256] (dead after gemm1)
#define HB1_OFF     10289152ull             // 20,578,304 : h1 bf16 [MPAD,512]
#define AGG1_OFF    30867456ull             // 20,578,304 : agg1 bf16 [MPAD,512] (in-place BN)
#define HB2_OFF     51445760ull             // 10,289,152 : h2 bf16 [MPAD,256]
#define OUT2_OFF    61734912ull             //  5,120,000 : head-mean fp32 [20000,64] (pre-BN)
#define EAF_OFF     66854912ull             //  1,280,000
#define W1BT_OFF    68134912ull             //    262,144
#define W2BT_OFF    68397056ull             //    262,144
#define CSR_OFF     68659200ull             //  2,720,000 (int2: s, edge-id -> s, eav-bits)
#define ROWPTR_OFF  71379200ull             //     80,064
#define GSTART_OFF  71459264ull             //        256
#define SMALL_OFF   71459520ull             //     25,600
#define SBUF_OFF    71485120ull             //         64
#define EAP_OFF     71485184ull             //      1,280
#define PMU1_OFF    72772608ull             //    524,288
#define PM21_OFF    73296896ull             //    524,288
#define PMU2_OFF    73821184ull             //     65,536
#define PM22_OFF    73886720ull             //     65,536
#define A1_OFF      73952256ull             //      2,048
#define B1_OFF      73954304ull             //      2,048
#define A2_OFF      73956352ull             //        256
#define B2_OFF      73956608ull             //        256
#define EAACC_OFF   73956864ull             //         64
// ---- zeroed-at-start region ----
#define DEG_OFF     74600000ull             //     80,000
#define CURS_OFF    74680000ull             //     80,000
#define FLAGZ_OFF   74760000ull             //        128
#define PP_OFF      74760128ull             //     65,536 : pool partials [256][64]
#define ALS1_OFF    74825664ull             //    321,536 : layer1 als [MPAD*4] (atomic-accum)
#define ALD1_OFF    75147200ull             //    321,536
#define ALS2_OFF    75468736ull             //    321,536 : layer2
#define ALD2_OFF    75790272ull             //    321,536
#define ZERO0_START DEG_OFF
#define ZERO0_SIZE  1511808ull              // deg+cursor+flag+pp+als/ald x4
// ---- alpha/srcs overlay on dead xb region (used only between gemm1 and agg1_slice) ----
#define ALPHA_OFF   XB_OFF                  //  5,440,000 : alpha fp32 [N_EP][4]
#define SRCS_OFF    5440000ull              //  1,360,000 : srcs int [N_EP]

// small-region float offsets
#define S_AS1 0
#define S_AD1 512
#define S_WE1 1024
#define S_AE1 1536
#define S_G1  2048
#define S_BE1 2560
#define S_AS2 3072
#define S_AD2 3328
#define S_WE2 3584
#define S_AE2 3840
#define S_G2  4096
#define S_BE2 4160
#define S_FW1 4224
#define S_FB1 6272
#define S_FW2 6304
#define S_FB2 6336

typedef __attribute__((ext_vector_type(8))) short bf8_t;
typedef __attribute__((ext_vector_type(4))) float f4_t;

// ---- detect fp32 (1) vs bf16 (0); flag pre-zeroed ----
__global__ void detect_dtype(const unsigned short* __restrict__ xr, int* __restrict__ flag) {
    int i = blockIdx.x * blockDim.x + threadIdx.x;
    unsigned short u = xr[i];
    if ((u & 0x7F80) == 0x7F80) atomicOr(flag, 1);
}

__device__ __forceinline__ float loadF(const void* p, int i, int fp32) {
    return fp32 ? ((const float*)p)[i]
                : __bfloat162float(((const __hip_bfloat16*)p)[i]);
}

// ---- fused prep ----
#define PB_XB  5024
#define PB_EAF 313
#define PB_W   512
#define PB_SM  16
#define PREP_BLOCKS (PB_XB + PB_EAF + 2 * PB_W + PB_SM + 1)
__global__ __launch_bounds__(256) void prep(
        const int* __restrict__ flag,
        const void* x, const void* ea, const void* W1, const void* W2,
        const void* as1, const void* ad1, const void* We1, const void* ae1,
        const void* g1, const void* be1, const void* as2, const void* ad2,
        const void* We2, const void* ae2, const void* g2, const void* be2,
        const void* fw1, const void* fb1, const void* fw2, const void* fb2,
        __hip_bfloat16* __restrict__ xb, float* __restrict__ eaf, float* __restrict__ eap,
        __hip_bfloat16* __restrict__ W1bt, __hip_bfloat16* __restrict__ W2bt,
        float* __restrict__ smalls, float* __restrict__ sbuf) {
    __shared__ float sh[256];
    int b = blockIdx.x, t = threadIdx.x;
    int fp32 = flag[0];
    if (b < PB_XB) {
        int base = (b * 256 + t) * 4;
        __hip_bfloat16 tmp[4];
#pragma unroll
        for (int j = 0; j < 4; ++j) {
            int i = base + j;
            float v = (i < N_NODES * D_IN) ? loadF(x, i, fp32) : 0.f;
            tmp[j] = __float2bfloat16(v);
        }
        *(uint2*)&xb[base] = *(uint2*)tmp;
        return;
    }
    b -= PB_XB;
    if (b < PB_EAF) {
        int base = (b * 256 + t) * 4;
        float s = 0.f;
#pragma unroll
        for (int j = 0; j < 4; ++j) {
            int i = base + j;
            if (i < N_EDGES) { float v = loadF(ea, i, fp32); eaf[i] = v; s += v; }
        }
        sh[t] = s;
        __syncthreads();
        for (int st = 128; st; st >>= 1) {
            if (t < st) sh[t] += sh[t + st];
            __syncthreads();
        }
        if (t == 0) eap[b] = sh[0];
        return;
    }
    b -= PB_EAF;
    if (b < PB_W) {
        int i = b * 256 + t;
        int k = i >> 9, n = i & 511;
        W1bt[(size_t)n * 256 + k] = __float2bfloat16(loadF(W1, i, fp32));
        return;
    }
    b -= PB_W;
    if (b < PB_W) {
        int i = b * 256 + t;
        int k = i >> 8, n = i & 255;
        W2bt[(size_t)n * 512 + k] = __float2bfloat16(loadF(W2, i, fp32));
        return;
    }
    b -= PB_W;
    if (b < PB_SM) {
        const void* srcs[16] = {as1, ad1, We1, ae1, g1, be1, as2, ad2, We2, ae2, g2, be2, fw1, fb1, fw2, fb2};
        const int cnts[16] = {512, 512, 512, 512, 512, 512, 256, 256, 256, 256, 64, 64, 2048, 32, 32, 1};
        const int offs[16] = {S_AS1, S_AD1, S_WE1, S_AE1, S_G1, S_BE1, S_AS2, S_AD2,
                              S_WE2, S_AE2, S_G2, S_BE2, S_FW1, S_FB1, S_FW2, S_FB2};
        for (int i = t; i < cnts[b]; i += 256)
            smalls[offs[b] + i] = loadF(srcs[b], i, fp32);
        return;
    }
    if (t < 4) {
        float s = 0.f;
        for (int c = 0; c < CC1; ++c) s += loadF(We1, t * CC1 + c, fp32) * loadF(ae1, t * CC1 + c, fp32);
        sbuf[t] = s;
    } else if (t < 8) {
        int h = t - 4;
        float s = 0.f;
        for (int c = 0; c < CC2; ++c) s += loadF(We2, h * CC2 + c, fp32) * loadF(ae2, h * CC2 + c, fp32);
        sbuf[4 + h] = s;
    }
}

// ---- fused hist + graph bounds ----
#define HIST_BLOCKS 1329
__global__ void hist_bounds(const int* __restrict__ ei, int* __restrict__ deg,
                            const int* __restrict__ batch, int* __restrict__ gstart) {
    int b = blockIdx.x, t = threadIdx.x;
    if (b < HIST_BLOCKS) {
        int e = b * 256 + t;
        if (e >= N_EP) return;
        int d = (e < N_EDGES) ? ei[N_EDGES + e] : e - N_EDGES;
        atomicAdd(&deg[d], 1);
        return;
    }
    int i = (b - HIST_BLOCKS) * 256 + t;
    if (i >= N_NODES) return;
    int bb = batch[i];
    if (i == 0) {
        for (int g = 0; g <= bb; ++g) gstart[g] = 0;
    } else {
        int pb = batch[i - 1];
        for (int g = pb + 1; g <= bb; ++g) gstart[g] = i;
    }
    if (i == N_NODES - 1) {
        for (int g = bb + 1; g <= N_GRAPHS; ++g) gstart[g] = N_NODES;
    }
}

__global__ __launch_bounds__(1024) void deg_scan(const int* __restrict__ deg, int* __restrict__ rowptr,
                                                 const float* __restrict__ eap, float* __restrict__ ea_acc) {
    __shared__ int part[1024];
    __shared__ float fsh[512];
    int t = threadIdx.x;
    int lo = t * 20;
    int hi = lo + 20; if (hi > N_NODES) hi = N_NODES; if (lo > N_NODES) lo = N_NODES;
    int s = 0;
    for (int i = lo; i < hi; ++i) s += deg[i];
    part[t] = s;
    __syncthreads();
    for (int off = 1; off < 1024; off <<= 1) {
        int u = (t >= off) ? part[t - off] : 0;
        __syncthreads();
        if (t >= off) part[t] += u;
        __syncthreads();
    }
    int run = part[t] - s;
    for (int i = lo; i < hi; ++i) { rowptr[i] = run; run += deg[i]; }
    if (hi == N_NODES && lo < N_NODES) rowptr[N_NODES] = run;
    if (t < 512) fsh[t] = (t < PB_EAF) ? eap[t] : 0.f;
    __syncthreads();
    for (int st = 256; st; st >>= 1) {
        if (t < st) fsh[t] += fsh[t + st];
        __syncthreads();
    }
    if (t == 0) ea_acc[0] = fsh[0];
}

__global__ void edge_scatter(const int* __restrict__ ei, const int* __restrict__ rowptr,
                             int* __restrict__ cursor, int2* __restrict__ csr_se) {
    int e = blockIdx.x * blockDim.x + threadIdx.x;
    if (e >= N_EP) return;
    int s, d;
    if (e < N_EDGES) { s = ei[e]; d = ei[N_EDGES + e]; }
    else { s = d = e - N_EDGES; }
    int pos = rowptr[d] + atomicAdd(&cursor[d], 1);
    csr_se[pos] = make_int2(s, e);
}

// ---- canonical CSR sort (parallel odd-even, unique keys => deterministic) + eav fill ----
__global__ __launch_bounds__(64) void csr_sort_fill(const int* __restrict__ rowptr, int2* __restrict__ cs,
                                                    const float* __restrict__ eaf,
                                                    const float* __restrict__ ea_acc) {
    __shared__ int2 buf[128];
    int d = blockIdx.x;
    int beg = rowptr[d], end = rowptr[d + 1], n = end - beg;
    int lane = threadIdx.x;
    float ea_mean = ea_acc[0] * (1.0f / N_EDGES);
    if (n <= 0) return;
    if (n <= 128) {
        for (int i = lane; i < n; i += 64) buf[i] = cs[beg + i];
        __syncthreads();
        for (int r = 0; r < n; ++r) {
            int i = 2 * lane + (r & 1);
            if (i + 1 < n) {
                int2 a = buf[i], b = buf[i + 1];
                if (a.y > b.y) { buf[i] = b; buf[i + 1] = a; }
            }
            __syncthreads();
        }
        for (int i = lane; i < n; i += 64) {
            int2 se = buf[i];
            float eav = (se.y < N_EDGES) ? eaf[se.y] : ea_mean;
            se.y = __float_as_int(eav);
            cs[beg + i] = se;
        }
    } else {
        if (lane == 0) {
            for (int i = beg + 1; i < end; ++i) {
                int2 key = cs[i]; int j = i - 1;
                while (j >= beg && cs[j].y > key.y) { cs[j + 1] = cs[j]; --j; }
                cs[j + 1] = key;
            }
        }
        __syncthreads();
        for (int i = lane; i < n; i += 64) {
            int2 se = cs[beg + i];
            float eav = (se.y < N_EDGES) ? eaf[se.y] : ea_mean;
            se.y = __float_as_int(eav);
            cs[beg + i] = se;
        }
    }
}

// ---- MFMA bf16 GEMM + al epilogue: atomicAdd into pre-zeroed als/ald ----
__global__ __launch_bounds__(256) void gemm_mfma_al(
        const short* __restrict__ A, const short* __restrict__ Bt,
        __hip_bfloat16* __restrict__ Cb, int N, int K,
        float* __restrict__ als, float* __restrict__ ald,
        const float* __restrict__ asv, const float* __restrict__ adv, int cshift) {
    __shared__ short As[128 * 40];
    __shared__ short Bs[64 * 40];
    int t = threadIdx.x;
    int wv = t >> 6, lane = t & 63, quad = lane >> 4, lr = lane & 15;
    int m0 = blockIdx.y * 128, n0 = blockIdx.x * 64;
    f4_t acc[2][4] = {};
    int ra0 = t >> 2, sa0 = t & 3;
    int ra1 = (t + 256) >> 2;
    for (int k0 = 0; k0 < K; k0 += 32) {
        *(uint4*)&As[ra0 * 40 + sa0 * 8] = *(const uint4*)&A[(size_t)(m0 + ra0) * K + k0 + sa0 * 8];
        *(uint4*)&As[ra1 * 40 + sa0 * 8] = *(const uint4*)&A[(size_t)(m0 + ra1) * K + k0 + sa0 * 8];
        *(uint4*)&Bs[ra0 * 40 + sa0 * 8] = *(const uint4*)&Bt[(size_t)(n0 + ra0) * K + k0 + sa0 * 8];
        __syncthreads();
        bf8_t a0 = *(const bf8_t*)&As[(wv * 16 + lr) * 40 + quad * 8];
        bf8_t a1 = *(const bf8_t*)&As[((wv + 4) * 16 + lr) * 40 + quad * 8];
#pragma unroll
        for (int nt = 0; nt < 4; ++nt) {
            bf8_t b = *(const bf8_t*)&Bs[(nt * 16 + lr) * 40 + quad * 8];
            acc[0][nt] = __builtin_amdgcn_mfma_f32_16x16x32_bf16(a0, b, acc[0][nt], 0, 0, 0);
            acc[1][nt] = __builtin_amdgcn_mfma_f32_16x16x32_bf16(a1, b, acc[1][nt], 0, 0, 0);
        }
        __syncthreads();
    }
#pragma unroll
    for (int si = 0; si < 2; ++si) {
        int mrow = m0 + (wv + si * 4) * 16 + quad * 4;
#pragma unroll
        for (int nt = 0; nt < 4; ++nt) {
            int col = n0 + nt * 16 + lr;
#pragma unroll
            for (int r = 0; r < 4; ++r)
                Cb[(size_t)(mrow + r) * N + col] = __float2bfloat16(acc[si][nt][r]);
        }
    }
    float asv4[4], adv4[4];
#pragma unroll
    for (int nt = 0; nt < 4; ++nt) {
        asv4[nt] = asv[n0 + nt * 16 + lr];
        adv4[nt] = adv[n0 + nt * 16 + lr];
    }
    int hsel = n0 >> cshift;
#pragma unroll
    for (int si = 0; si < 2; ++si) {
#pragma unroll
        for (int r = 0; r < 4; ++r) {
            float ps = 0.f, pd = 0.f;
#pragma unroll
            for (int nt = 0; nt < 4; ++nt) {
                ps += acc[si][nt][r] * asv4[nt];
                pd += acc[si][nt][r] * adv4[nt];
            }
#pragma unroll
            for (int m = 1; m < 16; m <<= 1) {
                ps += __shfl_xor(ps, m);
                pd += __shfl_xor(pd, m);
            }
            if (lr == 0) {
                int row = m0 + (wv + si * 4) * 16 + quad * 4 + r;
                atomicAdd(&als[row * 4 + hsel], ps);
                atomicAdd(&ald[row * 4 + hsel], pd);
            }
        }
    }
}

// ---- alpha pass, layer 1: per-edge normalized softmax weight (deterministic, no LDS) ----
__global__ __launch_bounds__(256) void alpha1(
        const int* __restrict__ rowptr, const int2* __restrict__ cs,
        const float* __restrict__ als, const float* __restrict__ ald,
        const float* __restrict__ sbuf, float* __restrict__ alpha, int* __restrict__ srcs) {
    int wv = threadIdx.x >> 6, t = threadIdx.x & 63;
    int d = blockIdx.x * 4 + wv;
    int beg = rowptr[d], n = rowptr[d + 1] - beg;
    float4 adv = *(const float4*)&ald[d * 4];
    float adh[4] = {adv.x, adv.y, adv.z, adv.w};
    float sb4[4] = {sbuf[0], sbuf[1], sbuf[2], sbuf[3]};
    float mx[4] = {-INFINITY, -INFINITY, -INFINITY, -INFINITY};
    for (int p = t; p < n; p += 64) {
        int2 se = cs[beg + p];
        float eav = __int_as_float(se.y);
        float4 as = *(const float4*)&als[se.x * 4];
        float l4[4] = {as.x, as.y, as.z, as.w};
#pragma unroll
        for (int hh = 0; hh < 4; ++hh) {
            float v = l4[hh] + adh[hh] + eav * sb4[hh];
            v = v > 0.f ? v : 0.2f * v;
            mx[hh] = fmaxf(mx[hh], v);
        }
    }
#pragma unroll
    for (int m = 1; m < 64; m <<= 1)
#pragma unroll
        for (int hh = 0; hh < 4; ++hh)
            mx[hh] = fmaxf(mx[hh], __shfl_xor(mx[hh], m));
    float sm[4] = {0.f, 0.f, 0.f, 0.f};
    for (int p = t; p < n; p += 64) {
        int2 se = cs[beg + p];
        float eav = __int_as_float(se.y);
        float4 as = *(const float4*)&als[se.x * 4];
        float l4[4] = {as.x, as.y, as.z, as.w};
#pragma unroll
        for (int hh = 0; hh < 4; ++hh) {
            float v = l4[hh] + adh[hh] + eav * sb4[hh];
            v = v > 0.f ? v : 0.2f * v;
            sm[hh] += __expf(v - mx[hh]);
        }
    }
#pragma unroll
    for (int m = 1; m < 64; m <<= 1)
#pragma unroll
        for (int hh = 0; hh < 4; ++hh)
            sm[hh] += __shfl_xor(sm[hh], m);
    float rdn[4];
#pragma unroll
    for (int hh = 0; hh < 4; ++hh) rdn[hh] = 1.0f / (sm[hh] + 1e-16f);
    for (int p = t; p < n; p += 64) {
        int2 se = cs[beg + p];
        float eav = __int_as_float(se.y);
        float4 as = *(const float4*)&als[se.x * 4];
        float l4[4] = {as.x, as.y, as.z, as.w};
        float av[4];
#pragma unroll
        for (int hh = 0; hh < 4; ++hh) {
            float v = l4[hh] + adh[hh] + eav * sb4[hh];
            v = v > 0.f ? v : 0.2f * v;
            av[hh] = __expf(v - mx[hh]) * rdn[hh];
        }
        *(float4*)&alpha[(size_t)(beg + p) * 4] = make_float4(av[0], av[1], av[2], av[3]);
        srcs[beg + p] = se.x;
    }
}

// ---- L2-resident sliced gather, layer 1: slice=bid&7 pins a 64-ch slice per XCD ----
// slice table = 20096*64*2B = 2.57 MB < 4 MiB L2 -> gather hits L2 after first touch
__global__ __launch_bounds__(256) void agg1_slice(
        const int* __restrict__ rowptr, const int* __restrict__ srcs,
        const float* __restrict__ alpha, const __hip_bfloat16* __restrict__ hb,
        __hip_bfloat16* __restrict__ outb) {
    int slice = blockIdx.x & 7;
    int chunk = blockIdx.x >> 3;
    int t = threadIdx.x;
    int grp = t >> 4, lane = t & 15;      // 16 dsts/block, 16 lanes/dst
    int d = chunk * 16 + grp;
    int beg = rowptr[d], n = rowptr[d + 1] - beg;
    int h0 = slice >> 1;                  // 128-ch heads, 64-ch slices
    const __hip_bfloat16* hcol = hb + slice * 64 + lane * 4;
    const float* ap = alpha + (size_t)beg * 4 + h0;
    const int* sp = srcs + beg;
    float a0 = 0.f, a1 = 0.f, a2 = 0.f, a3 = 0.f;
#define ACCS(rr, wt) { \
    a0 += (wt) * __uint_as_float((rr).x << 16); a1 += (wt) * __uint_as_float((rr).x & 0xFFFF0000u); \
    a2 += (wt) * __uint_as_float((rr).y << 16); a3 += (wt) * __uint_as_float((rr).y & 0xFFFF0000u); }
    int p = 0;
    for (; p + 4 <= n; p += 4) {
        int s0 = sp[p], s1 = sp[p + 1], s2 = sp[p + 2], s3 = sp[p + 3];
        float w0 = ap[4 * p], w1 = ap[4 * p + 4], w2 = ap[4 * p + 8], w3 = ap[4 * p + 12];
        uint2 r0 = *(const uint2*)&hcol[(size_t)s0 * 512];
        uint2 r1 = *(const uint2*)&hcol[(size_t)s1 * 512];
        uint2 r2 = *(const uint2*)&hcol[(size_t)s2 * 512];
        uint2 r3 = *(const uint2*)&hcol[(size_t)s3 * 512];
        ACCS(r0, w0); ACCS(r1, w1); ACCS(r2, w2); ACCS(r3, w3);
    }
    for (; p < n; ++p) {
        int s0 = sp[p];
        float w0 = ap[4 * p];
        uint2 r0 = *(const uint2*)&hcol[(size_t)s0 * 512];
        ACCS(r0, w0);
    }
#undef ACCS
    __hip_bfloat16 tmp[4] = {__float2bfloat16(a0), __float2bfloat16(a1),
                             __float2bfloat16(a2), __float2bfloat16(a3)};
    *(uint2*)&outb[(size_t)d * 512 + slice * 64 + lane * 4] = *(uint2*)tmp;
}

// ---- FUSED softmax+agg+head-mean, layer 2: ONE WAVE per dst (4 dst / 256-thr block) ----
__global__ __launch_bounds__(256) void fused_agg2(
        const int* __restrict__ rowptr, const int2* __restrict__ cs,
        const float* __restrict__ als, const float* __restrict__ ald,
        const float* __restrict__ sbuf, const __hip_bfloat16* __restrict__ hb,
        float* __restrict__ out2) {
    __shared__ float lg[4][MAXDEG * 4];
    __shared__ int   ssrc[4][MAXDEG];
    int wv = threadIdx.x >> 6, t = threadIdx.x & 63;
    int d = blockIdx.x * 4 + wv;
    int beg = rowptr[d], n = rowptr[d + 1] - beg;
    bool fit = (n <= MAXDEG);
    float4 adv = *(const float4*)&ald[d * 4];
    float adh[4] = {adv.x, adv.y, adv.z, adv.w};
    float sb4[4] = {sbuf[4], sbuf[5], sbuf[6], sbuf[7]};
    float mx[4] = {-INFINITY, -INFINITY, -INFINITY, -INFINITY};
    for (int p = t; p < n; p += 64) {
        int2 se = cs[beg + p];
        float eav = __int_as_float(se.y);
        float4 as = *(const float4*)&als[se.x * 4];
        float l[4] = {as.x, as.y, as.z, as.w};
#pragma unroll
        for (int hh = 0; hh < 4; ++hh) {
            float v = l[hh] + adh[hh] + eav * sb4[hh];
            v = v > 0.f ? v : 0.2f * v;
            l[hh] = v;
            mx[hh] = fmaxf(mx[hh], v);
        }
        if (fit) {
            *(float4*)&lg[wv][p * 4] = make_float4(l[0], l[1], l[2], l[3]);
            ssrc[wv][p] = se.x;
        }
    }
#pragma unroll
    for (int m = 1; m < 64; m <<= 1)
#pragma unroll
        for (int hh = 0; hh < 4; ++hh)
            mx[hh] = fmaxf(mx[hh], __shfl_xor(mx[hh], m));
    asm volatile("s_waitcnt lgkmcnt(0)" ::: "memory");
    int h = t >> 4;
    float mh = mx[h];
    float a4[4] = {};
    float ds = 0.f;
    const __hip_bfloat16* hrow = hb + 4 * t;
#define ACC4(rr, wt) { \
    unsigned q0 = (rr).x, q1 = (rr).y; \
    a4[0] += (wt) * __uint_as_float(q0 << 16); a4[1] += (wt) * __uint_as_float(q0 & 0xFFFF0000u); \
    a4[2] += (wt) * __uint_as_float(q1 << 16); a4[3] += (wt) * __uint_as_float(q1 & 0xFFFF0000u); }
    if (fit) {
        int p = 0;
        for (; p + 8 <= n; p += 8) {
            int s0 = ssrc[wv][p],     s1 = ssrc[wv][p + 1], s2 = ssrc[wv][p + 2], s3 = ssrc[wv][p + 3];
            int s4 = ssrc[wv][p + 4], s5 = ssrc[wv][p + 5], s6 = ssrc[wv][p + 6], s7 = ssrc[wv][p + 7];
            uint2 r0 = *(const uint2*)&hrow[(size_t)s0 * 256];
            uint2 r1 = *(const uint2*)&hrow[(size_t)s1 * 256];
            uint2 r2 = *(const uint2*)&hrow[(size_t)s2 * 256];
            uint2 r3 = *(const uint2*)&hrow[(size_t)s3 * 256];
            uint2 r4 = *(const uint2*)&hrow[(size_t)s4 * 256];
            uint2 r5 = *(const uint2*)&hrow[(size_t)s5 * 256];
            uint2 r6 = *(const uint2*)&hrow[(size_t)s6 * 256];
            uint2 r7 = *(const uint2*)&hrow[(size_t)s7 * 256];
            float w0 = __expf(lg[wv][p * 4 + h] - mh);
            float w1 = __expf(lg[wv][p * 4 + 4 + h] - mh);
            float w2 = __expf(lg[wv][p * 4 + 8 + h] - mh);
            float w3 = __expf(lg[wv][p * 4 + 12 + h] - mh);
            float w4 = __expf(lg[wv][p * 4 + 16 + h] - mh);
            float w5 = __expf(lg[wv][p * 4 + 20 + h] - mh);
            float w6 = __expf(lg[wv][p * 4 + 24 + h] - mh);
            float w7 = __expf(lg[wv][p * 4 + 28 + h] - mh);
            ds += ((w0 + w1) + (w2 + w3)) + ((w4 + w5) + (w6 + w7));
            ACC4(r0, w0); ACC4(r1, w1); ACC4(r2, w2); ACC4(r3, w3);
            ACC4(r4, w4); ACC4(r5, w5); ACC4(r6, w6); ACC4(r7, w7);
        }
        for (; p + 4 <= n; p += 4) {
            int s0 = ssrc[wv][p], s1 = ssrc[wv][p + 1], s2 = ssrc[wv][p + 2], s3 = ssrc[wv][p + 3];
            uint2 r0 = *(const uint2*)&hrow[(size_t)s0 * 256];
            uint2 r1 = *(const uint2*)&hrow[(size_t)s1 * 256];
            uint2 r2 = *(const uint2*)&hrow[(size_t)s2 * 256];
            uint2 r3 = *(const uint2*)&hrow[(size_t)s3 * 256];
            float w0 = __expf(lg[wv][p * 4 + h] - mh);
            float w1 = __expf(lg[wv][p * 4 + 4 + h] - mh);
            float w2 = __expf(lg[wv][p * 4 + 8 + h] - mh);
            float w3 = __expf(lg[wv][p * 4 + 12 + h] - mh);
            ds += (w0 + w1) + (w2 + w3);
            ACC4(r0, w0); ACC4(r1, w1); ACC4(r2, w2); ACC4(r3, w3);
        }
        for (; p < n; ++p) {
            int s0 = ssrc[wv][p];
            uint2 r0 = *(const uint2*)&hrow[(size_t)s0 * 256];
            float w0 = __expf(lg[wv][p * 4 + h] - mh);
            ds += w0;
            ACC4(r0, w0);
        }
    } else {
        for (int p = 0; p < n; ++p) {
            int2 se = cs[beg + p];
            float eav = __int_as_float(se.y);
            float l = als[se.x * 4 + h] + adh[h] + eav * sb4[h];
            l = l > 0.f ? l : 0.2f * l;
            float w = __expf(l - mh);
            uint2 r0 = *(const uint2*)&hrow[(size_t)se.x * 256];
            ds += w;
            ACC4(r0, w);
        }
    }
#undef ACC4
    float rdn = 1.0f / (ds + 1e-16f);
#pragma unroll
    for (int j = 0; j < 4; ++j) {
        float v = a4[j] * rdn;
        v += __shfl_xor(v, 16);
        v += __shfl_xor(v, 32);
        a4[j] = v * 0.25f;
    }
    if (t < 16)
        *(float4*)&out2[(size_t)d * 64 + 4 * t] = make_float4(a4[0], a4[1], a4[2], a4[3]);
}

// ---- BN1 stats: per-block partials ----
__global__ __launch_bounds__(256) void bn_part_b(const __hip_bfloat16* __restrict__ x,
                                                 float* __restrict__ pmu, float* __restrict__ pm2) {
    int t = threadIdx.x, b = blockIdx.x;
    float s0 = 0.f, s20 = 0.f, s1 = 0.f, s21 = 0.f;
    for (int i = b; i < N_NODES; i += gridDim.x) {
        unsigned u = *(const unsigned*)&x[(size_t)i * 512 + 2 * t];
        float v0 = __uint_as_float(u << 16);
        float v1 = __uint_as_float(u & 0xFFFF0000u);
        s0 += v0; s20 += v0 * v0; s1 += v1; s21 += v1 * v1;
    }
    pmu[b * 512 + 2 * t] = s0;     pm2[b * 512 + 2 * t] = s20;
    pmu[b * 512 + 2 * t + 1] = s1; pm2[b * 512 + 2 * t + 1] = s21;
}

// ---- reduce partials -> affine a,b (fixed order) ----
__global__ void bn_reduce_affine(const float* __restrict__ pmu, const float* __restrict__ pm2,
                                 const float* __restrict__ smalls, int s_g, int s_be,
                                 float* __restrict__ a, float* __restrict__ b, int nch) {
    int c = blockIdx.x * blockDim.x + threadIdx.x;
    if (c >= nch) return;
    float s = 0.f, s2 = 0.f;
    for (int bk = 0; bk < 256; ++bk) { s += pmu[bk * nch + c]; s2 += pm2[bk * nch + c]; }
    float m = s * (1.0f / N_NODES);
    float var = s2 * (1.0f / N_NODES) - m * m;
    float aa = smalls[s_g + c] * rsqrtf(var + 1e-5f);
    a[c] = aa;
    b[c] = smalls[s_be + c] - m * aa;
}

// ---- BN1 apply + ELU in place on bf16 [N_NODES,512] ----
__global__ __launch_bounds__(256) void bn_apply_elu_b16(__hip_bfloat16* __restrict__ x,
                                                        const float* __restrict__ a,
                                                        const float* __restrict__ b) {
    int q = blockIdx.x * blockDim.x + threadIdx.x;
    if (q >= N_NODES * 512 / 4) return;
    int base = q * 4;
    int j = base & 511;
    uint2 raw = *(uint2*)&x[base];
    float v[4] = {__uint_as_float(raw.x << 16), __uint_as_float(raw.x & 0xFFFF0000u),
                  __uint_as_float(raw.y << 16), __uint_as_float(raw.y & 0xFFFF0000u)};
    __hip_bfloat16 tmp[4];
#pragma unroll
    for (int k = 0; k < 4; ++k) {
        float y = a[j + k] * v[k] + b[j + k];
        y = y > 0.f ? y : expm1f(y);
        tmp[k] = __float2bfloat16(y);
    }
    *(uint2*)&x[base] = *(uint2*)tmp;
}

// ---- BN2 stats: per-block partials ----
__global__ __launch_bounds__(256) void bn2_stats(const float* __restrict__ x,
                                                 float* __restrict__ pmu, float* __restrict__ pm2) {
    int t = threadIdx.x;
    int c = t & 63, j = t >> 6;
    float ls = 0.f, ls2 = 0.f;
    for (int nd = blockIdx.x * 4 + j; nd < N_NODES; nd += gridDim.x * 4) {
        float v = x[(size_t)nd * 64 + c];
        ls += v; ls2 += v * v;
    }
    __shared__ float shs[4][64], sh2[4][64];
    shs[j][c] = ls; sh2[j][c] = ls2;
    __syncthreads();
    if (j == 0) {
        pmu[blockIdx.x * 64 + c] = shs[0][c] + shs[1][c] + shs[2][c] + shs[3][c];
        pm2[blockIdx.x * 64 + c] = sh2[0][c] + sh2[1][c] + sh2[2][c] + sh2[3][c];
    }
}

// ---- pool stage 1: 8 chunks per graph, BN2 affine+ELU fused, partial sums ----
__global__ __launch_bounds__(256) void pool_part(const float* __restrict__ x, const int* __restrict__ gstart,
                                                 const float* __restrict__ a2, const float* __restrict__ b2,
                                                 float* __restrict__ pp) {
    int g = blockIdx.x >> 3, ck = blockIdx.x & 7;
    int t = threadIdx.x;
    int c = t & 63, j = t >> 6;
    int beg = gstart[g], end = gstart[g + 1], n = end - beg;
    int cb = beg + (n * ck) / 8, ce = beg + (n * (ck + 1)) / 8;
    float ac = a2[c], bc = b2[c];
    float s = 0.f;
    for (int i = cb + j; i < ce; i += 4) {
        float y = ac * x[(size_t)i * 64 + c] + bc;
        s += (y > 0.f ? y : expm1f(y));
    }
    __shared__ float sh[4][64];
    sh[j][c] = s;
    __syncthreads();
    if (j == 0)
        pp[blockIdx.x * 64 + c] = sh[0][c] + sh[1][c] + sh[2][c] + sh[3][c];
}

// ---- pool stage 2: reduce 8 chunks (fixed order) + MLP ----
__global__ __launch_bounds__(64) void pool_mlp_fin(const float* __restrict__ pp, const int* __restrict__ gstart,
                                                   const float* __restrict__ smalls, const int* __restrict__ flag,
                                                   void* __restrict__ outp) {
    int g = blockIdx.x, t = threadIdx.x;
    __shared__ float pooled[64];
    __shared__ float hsh[32];
    float s = 0.f;
    for (int k = 0; k < 8; ++k) s += pp[(g * 8 + k) * 64 + t];
    int n = gstart[g + 1] - gstart[g];
    pooled[t] = s / fmaxf((float)n, 1.0f);
    __syncthreads();
    if (t < 32) {
        float acc = smalls[S_FB1 + t];
        for (int cc = 0; cc < 64; ++cc)
            acc += pooled[cc] * smalls[S_FW1 + cc * 32 + t];
        hsh[t] = acc > 0.f ? acc : expm1f(acc);
    }
    __syncthreads();
    if (t == 0) {
        float o = smalls[S_FB2];
        for (int k = 0; k < 32; ++k) o += hsh[k] * smalls[S_FW2 + k];
        if (flag[0]) ((float*)outp)[g] = o;
        else ((__hip_bfloat16*)outp)[g] = __float2bfloat16(o);
    }
}

extern "C" void kernel_launch(void* const* d_in, const int* in_sizes, int n_in,
                              void* d_out, int out_size, void* d_ws, size_t ws_size,
                              hipStream_t stream) {
    const void* x    = d_in[0];
    const int* ei    = (const int*)d_in[1];
    const int* batch = (const int*)d_in[2];
    const void* ea   = d_in[3];
    const void* W1   = d_in[4];
    const void* as1  = d_in[5];
    const void* ad1  = d_in[6];
    const void* We1  = d_in[7];
    const void* ae1  = d_in[8];
    const void* g1   = d_in[10];
    const void* be1  = d_in[11];
    const void* W2   = d_in[12];
    const void* as2  = d_in[13];
    const void* ad2  = d_in[14];
    const void* We2  = d_in[15];
    const void* ae2  = d_in[16];
    const void* g2   = d_in[18];
    const void* be2  = d_in[19];
    const void* fw1  = d_in[20];
    const void* fb1  = d_in[21];
    const void* fw2  = d_in[22];
    const void* fb2  = d_in[23];

    char* ws = (char*)d_ws;
    __hip_bfloat16* xb   = (__hip_bfloat16*)(ws + XB_OFF);
    __hip_bfloat16* hb1  = (__hip_bfloat16*)(ws + HB1_OFF);
    __hip_bfloat16* agg1 = (__hip_bfloat16*)(ws + AGG1_OFF);
    __hip_bfloat16* hb2  = (__hip_bfloat16*)(ws + HB2_OFF);
    float* out2   = (float*)(ws + OUT2_OFF);
    float* eaf    = (float*)(ws + EAF_OFF);
    __hip_bfloat16* W1bt = (__hip_bfloat16*)(ws + W1BT_OFF);
    __hip_bfloat16* W2bt = (__hip_bfloat16*)(ws + W2BT_OFF);
    int2*  csr_se = (int2*)(ws + CSR_OFF);
    int*   rowptr = (int*)(ws + ROWPTR_OFF);
    int*   gstart = (int*)(ws + GSTART_OFF);
    float* smalls = (float*)(ws + SMALL_OFF);
    float* sbuf   = (float*)(ws + SBUF_OFF);
    float* eap    = (float*)(ws + EAP_OFF);
    float* pmu1   = (float*)(ws + PMU1_OFF);
    float* pm21   = (float*)(ws + PM21_OFF);
    float* pmu2   = (float*)(ws + PMU2_OFF);
    float* pm22   = (float*)(ws + PM22_OFF);
    float* a1     = (float*)(ws + A1_OFF);
    float* b1     = (float*)(ws + B1_OFF);
    float* a2     = (float*)(ws + A2_OFF);
    float* b2     = (float*)(ws + B2_OFF);
    float* ea_acc = (float*)(ws + EAACC_OFF);
    float* als1   = (float*)(ws + ALS1_OFF);
    float* ald1   = (float*)(ws + ALD1_OFF);
    float* als2   = (float*)(ws + ALS2_OFF);
    float* ald2   = (float*)(ws + ALD2_OFF);
    float* alpha  = (float*)(ws + ALPHA_OFF);   // overlays xb (dead after gemm1)
    int*   srcs   = (int*)(ws + SRCS_OFF);      // overlays xb
    float* pp     = (float*)(ws + PP_OFF);
    int*   deg    = (int*)(ws + DEG_OFF);
    int*   cursor = (int*)(ws + CURS_OFF);
    int*   flag   = (int*)(ws + FLAGZ_OFF);

    hipMemsetAsync(ws + ZERO0_START, 0, ZERO0_SIZE, stream);

    detect_dtype<<<256, 256, 0, stream>>>((const unsigned short*)x, flag);
    prep<<<PREP_BLOCKS, 256, 0, stream>>>(flag, x, ea, W1, W2,
                                          as1, ad1, We1, ae1, g1, be1, as2, ad2,
                                          We2, ae2, g2, be2, fw1, fb1, fw2, fb2,
                                          xb, eaf, eap, W1bt, W2bt, smalls, sbuf);

    hist_bounds<<<HIST_BLOCKS + 79, 256, 0, stream>>>(ei, deg, batch, gstart);
    deg_scan<<<1, 1024, 0, stream>>>(deg, rowptr, eap, ea_acc);
    edge_scatter<<<HIST_BLOCKS, 256, 0, stream>>>(ei, rowptr, cursor, csr_se);
    csr_sort_fill<<<N_NODES, 64, 0, stream>>>(rowptr, csr_se, eaf, ea_acc);

    // ---------- layer 1 ----------
    gemm_mfma_al<<<dim3(512 / 64, MPAD / 128), 256, 0, stream>>>(
        (const short*)xb, (const short*)W1bt, hb1, 512, 256,
        als1, ald1, smalls + S_AS1, smalls + S_AD1, 7);
    alpha1<<<N_NODES / 4, 256, 0, stream>>>(rowptr, csr_se, als1, ald1, sbuf, alpha, srcs);
    agg1_slice<<<(N_NODES / 16) * 8, 256, 0, stream>>>(rowptr, srcs, alpha, hb1, agg1);
    bn_part_b<<<256, 256, 0, stream>>>(agg1, pmu1, pm21);
    bn_reduce_affine<<<2, 256, 0, stream>>>(pmu1, pm21, smalls, S_G1, S_BE1, a1, b1, 512);
    bn_apply_elu_b16<<<10000, 256, 0, stream>>>(agg1, a1, b1);

    // ---------- layer 2 ----------
    gemm_mfma_al<<<dim3(256 / 64, MPAD / 128), 256, 0, stream>>>(
        (const short*)agg1, (const short*)W2bt, hb2, 256, 512,
        als2, ald2, smalls + S_AS2, smalls + S_AD2, 6);
    fused_agg2<<<N_NODES / 4, 256, 0, stream>>>(rowptr, csr_se, als2, ald2, sbuf, hb2, out2);
    bn2_stats<<<256, 256, 0, stream>>>(out2, pmu2, pm22);
    bn_reduce_affine<<<1, 64, 0, stream>>>(pmu2, pm22, smalls, S_G2, S_BE2, a2, b2, 64);

    // ---------- BN2+ELU+pool (2-stage) + MLP ----------
    pool_part<<<N_GRAPHS * 8, 256, 0, stream>>>(out2, gstart, a2, b2, pp);
    pool_mlp_fin<<<N_GRAPHS, 64, 0, stream>>>(pp, gstart, smalls, flag, d_out);
}

// Round 6
// 444.589 us; speedup vs baseline: 1.0741x; 1.0012x over previous
//
#include <hip/hip_runtime.h>
#include <hip/hip_bf16.h>

#define N_NODES  20000
#define MPAD     20096
#define N_EDGES  320000
#define N_EP     (N_EDGES + N_NODES)
#define D_IN     256
#define N_GRAPHS 32
#define HH1 4
#define CC1 128
#define HH2 4
#define CC2 64
#define MAXDEG   128

// ---- workspace layout (bytes) ----
#define XB_OFF      0ull                    // 10,289,152 : x bf16 [MPAD,256]
#define HB1_OFF     10289152ull             // 20,578,304 : h1 bf16 [MPAD,512]
#define AGG1_OFF    30867456ull             // 20,578,304 : agg1 bf16 [MPAD,512] (in-place BN)
#define HB2_OFF     51445760ull             // 10,289,152 : h2 bf16 [MPAD,256]
#define OUT2_OFF    61734912ull             //  5,120,000 : head-mean fp32 [20000,64] (pre-BN)
#define EAF_OFF     66854912ull             //  1,280,000
#define W1BT_OFF    68134912ull             //    262,144
#define W2BT_OFF    68397056ull             //    262,144
#define CSR_OFF     68659200ull             //  2,720,000 (int2: s, edge-id -> s, eav-bits)
#define ROWPTR_OFF  71379200ull             //     80,064
#define GSTART_OFF  71459264ull             //        256
#define SMALL_OFF   71459520ull             //     25,600
#define SBUF_OFF    71485120ull             //         64
#define EAP_OFF     71485184ull             //      1,280
#define PMU1_OFF    72772608ull             //    524,288
#define PM21_OFF    73296896ull             //    524,288
#define PMU2_OFF    73821184ull             //     65,536
#define PM22_OFF    73886720ull             //     65,536
#define A1_OFF      73952256ull             //      2,048
#define B1_OFF      73954304ull             //      2,048
#define A2_OFF      73956352ull             //        256
#define B2_OFF      73956608ull             //        256
#define EAACC_OFF   73956864ull             //         64
// ---- zeroed-at-start region ----
#define DEG_OFF     74600000ull             //     80,000
#define CURS_OFF    74680000ull             //     80,000
#define FLAGZ_OFF   74760000ull             //        128
#define PP_OFF      74760128ull             //     65,536 : pool partials [256][64]
#define ALS1_OFF    74825664ull             //    321,536 : layer1 als [MPAD*4] (atomic-accum)
#define ALD1_OFF    75147200ull             //    321,536
#define ALS2_OFF    75468736ull             //    321,536 : layer2
#define ALD2_OFF    75790272ull             //    321,536
#define ZERO0_START DEG_OFF
#define ZERO0_SIZE  1511808ull              // deg+cursor+flag+pp+als/ald x4

// small-region float offsets
#define S_AS1 0
#define S_AD1 512
#define S_WE1 1024
#define S_AE1 1536
#define S_G1  2048
#define S_BE1 2560
#define S_AS2 3072
#define S_AD2 3328
#define S_WE2 3584
#define S_AE2 3840
#define S_G2  4096
#define S_BE2 4160
#define S_FW1 4224
#define S_FB1 6272
#define S_FW2 6304
#define S_FB2 6336

typedef __attribute__((ext_vector_type(8))) short bf8_t;
typedef __attribute__((ext_vector_type(4))) float f4_t;

// ---- detect fp32 (1) vs bf16 (0); flag pre-zeroed ----
__global__ void detect_dtype(const unsigned short* __restrict__ xr, int* __restrict__ flag) {
    int i = blockIdx.x * blockDim.x + threadIdx.x;
    unsigned short u = xr[i];
    if ((u & 0x7F80) == 0x7F80) atomicOr(flag, 1);
}

__device__ __forceinline__ float loadF(const void* p, int i, int fp32) {
    return fp32 ? ((const float*)p)[i]
                : __bfloat162float(((const __hip_bfloat16*)p)[i]);
}

// ---- fused prep ----
#define PB_XB  5024
#define PB_EAF 313
#define PB_W   512
#define PB_SM  16
#define PREP_BLOCKS (PB_XB + PB_EAF + 2 * PB_W + PB_SM + 1)
__global__ __launch_bounds__(256) void prep(
        const int* __restrict__ flag,
        const void* x, const void* ea, const void* W1, const void* W2,
        const void* as1, const void* ad1, const void* We1, const void* ae1,
        const void* g1, const void* be1, const void* as2, const void* ad2,
        const void* We2, const void* ae2, const void* g2, const void* be2,
        const void* fw1, const void* fb1, const void* fw2, const void* fb2,
        __hip_bfloat16* __restrict__ xb, float* __restrict__ eaf, float* __restrict__ eap,
        __hip_bfloat16* __restrict__ W1bt, __hip_bfloat16* __restrict__ W2bt,
        float* __restrict__ smalls, float* __restrict__ sbuf) {
    __shared__ float shw[4];
    int b = blockIdx.x, t = threadIdx.x;
    int fp32 = flag[0];
    if (b < PB_XB) {
        int base = (b * 256 + t) * 4;
        __hip_bfloat16 tmp[4];
#pragma unroll
        for (int j = 0; j < 4; ++j) {
            int i = base + j;
            float v = (i < N_NODES * D_IN) ? loadF(x, i, fp32) : 0.f;
            tmp[j] = __float2bfloat16(v);
        }
        *(uint2*)&xb[base] = *(uint2*)tmp;
        return;
    }
    b -= PB_XB;
    if (b < PB_EAF) {
        int base = (b * 256 + t) * 4;
        float s = 0.f;
#pragma unroll
        for (int j = 0; j < 4; ++j) {
            int i = base + j;
            if (i < N_EDGES) { float v = loadF(ea, i, fp32); eaf[i] = v; s += v; }
        }
#pragma unroll
        for (int m = 1; m < 64; m <<= 1) s += __shfl_xor(s, m);
        if ((t & 63) == 0) shw[t >> 6] = s;
        __syncthreads();
        if (t == 0) eap[b] = shw[0] + shw[1] + shw[2] + shw[3];
        return;
    }
    b -= PB_EAF;
    if (b < PB_W) {
        int i = b * 256 + t;
        int k = i >> 9, n = i & 511;
        W1bt[(size_t)n * 256 + k] = __float2bfloat16(loadF(W1, i, fp32));
        return;
    }
    b -= PB_W;
    if (b < PB_W) {
        int i = b * 256 + t;
        int k = i >> 8, n = i & 255;
        W2bt[(size_t)n * 512 + k] = __float2bfloat16(loadF(W2, i, fp32));
        return;
    }
    b -= PB_W;
    if (b < PB_SM) {
        const void* srcs[16] = {as1, ad1, We1, ae1, g1, be1, as2, ad2, We2, ae2, g2, be2, fw1, fb1, fw2, fb2};
        const int cnts[16] = {512, 512, 512, 512, 512, 512, 256, 256, 256, 256, 64, 64, 2048, 32, 32, 1};
        const int offs[16] = {S_AS1, S_AD1, S_WE1, S_AE1, S_G1, S_BE1, S_AS2, S_AD2,
                              S_WE2, S_AE2, S_G2, S_BE2, S_FW1, S_FB1, S_FW2, S_FB2};
        for (int i = t; i < cnts[b]; i += 256)
            smalls[offs[b] + i] = loadF(srcs[b], i, fp32);
        return;
    }
    if (t < 4) {
        float s = 0.f;
        for (int c = 0; c < CC1; ++c) s += loadF(We1, t * CC1 + c, fp32) * loadF(ae1, t * CC1 + c, fp32);
        sbuf[t] = s;
    } else if (t < 8) {
        int h = t - 4;
        float s = 0.f;
        for (int c = 0; c < CC2; ++c) s += loadF(We2, h * CC2 + c, fp32) * loadF(ae2, h * CC2 + c, fp32);
        sbuf[4 + h] = s;
    }
}

// ---- fused hist + graph bounds ----
#define HIST_BLOCKS 1329
__global__ void hist_bounds(const int* __restrict__ ei, int* __restrict__ deg,
                            const int* __restrict__ batch, int* __restrict__ gstart) {
    int b = blockIdx.x, t = threadIdx.x;
    if (b < HIST_BLOCKS) {
        int e = b * 256 + t;
        if (e >= N_EP) return;
        int d = (e < N_EDGES) ? ei[N_EDGES + e] : e - N_EDGES;
        atomicAdd(&deg[d], 1);
        return;
    }
    int i = (b - HIST_BLOCKS) * 256 + t;
    if (i >= N_NODES) return;
    int bb = batch[i];
    if (i == 0) {
        for (int g = 0; g <= bb; ++g) gstart[g] = 0;
    } else {
        int pb = batch[i - 1];
        for (int g = pb + 1; g <= bb; ++g) gstart[g] = i;
    }
    if (i == N_NODES - 1) {
        for (int g = bb + 1; g <= N_GRAPHS; ++g) gstart[g] = N_NODES;
    }
}

__global__ __launch_bounds__(1024) void deg_scan(const int* __restrict__ deg, int* __restrict__ rowptr,
                                                 const float* __restrict__ eap, float* __restrict__ ea_acc) {
    __shared__ int part[1024];
    __shared__ float fsh[512];
    int t = threadIdx.x;
    int lo = t * 20;
    int hi = lo + 20; if (hi > N_NODES) hi = N_NODES; if (lo > N_NODES) lo = N_NODES;
    int s = 0;
    for (int i = lo; i < hi; ++i) s += deg[i];
    part[t] = s;
    __syncthreads();
    for (int off = 1; off < 1024; off <<= 1) {
        int u = (t >= off) ? part[t - off] : 0;
        __syncthreads();
        if (t >= off) part[t] += u;
        __syncthreads();
    }
    int run = part[t] - s;
    for (int i = lo; i < hi; ++i) { rowptr[i] = run; run += deg[i]; }
    if (hi == N_NODES && lo < N_NODES) rowptr[N_NODES] = run;
    if (t < 512) fsh[t] = (t < PB_EAF) ? eap[t] : 0.f;
    __syncthreads();
    for (int st = 256; st; st >>= 1) {
        if (t < st) fsh[t] += fsh[t + st];
        __syncthreads();
    }
    if (t == 0) ea_acc[0] = fsh[0];
}

__global__ void edge_scatter(const int* __restrict__ ei, const int* __restrict__ rowptr,
                             int* __restrict__ cursor, int2* __restrict__ csr_se) {
    int e = blockIdx.x * blockDim.x + threadIdx.x;
    if (e >= N_EP) return;
    int s, d;
    if (e < N_EDGES) { s = ei[e]; d = ei[N_EDGES + e]; }
    else { s = d = e - N_EDGES; }
    int pos = rowptr[d] + atomicAdd(&cursor[d], 1);
    csr_se[pos] = make_int2(s, e);
}

// ---- canonical CSR sort + eav fill ----
// n<=64: register odd-even transposition across one wave via shfl (no LDS, no barriers)
// 64<n<=128: per-wave LDS odd-even (wave-local lgkmcnt, no block barriers)
// n>128: single-lane insertion (vanishingly rare)
__global__ __launch_bounds__(256) void csr_sort_fill(const int* __restrict__ rowptr, int2* __restrict__ cs,
                                                     const float* __restrict__ eaf,
                                                     const float* __restrict__ ea_acc) {
    __shared__ int2 buf[4][128];
    int wv = threadIdx.x >> 6, lane = threadIdx.x & 63;
    int d = blockIdx.x * 4 + wv;
    int beg = rowptr[d], end = rowptr[d + 1], n = end - beg;
    float ea_mean = ea_acc[0] * (1.0f / N_EDGES);
    if (n <= 0) return;
    if (n <= 64) {
        int key = 0x7FFFFFFF, val = 0;
        if (lane < n) { int2 se = cs[beg + lane]; key = se.y; val = se.x; }
        // 64 rounds of odd-even transposition; unique keys => deterministic ascending order
        for (int r = 0; r < 64; ++r) {
            int par = r & 1;
            bool up = ((lane & 1) == par);            // left member of pair
            int partner = up ? lane + 1 : lane - 1;
            bool valid = (partner >= 0) && (partner < 64);
            int pidx = valid ? partner : lane;
            int pk = __shfl(key, pidx);
            int pv = __shfl(val, pidx);
            bool take = valid && (up ? (pk < key) : (pk > key));
            if (take) { key = pk; val = pv; }
        }
        if (lane < n) {
            float eav = (key < N_EDGES) ? eaf[key] : ea_mean;
            cs[beg + lane] = make_int2(val, __float_as_int(eav));
        }
        return;
    }
    if (n <= 128) {
        for (int i = lane; i < n; i += 64) buf[wv][i] = cs[beg + i];
        asm volatile("s_waitcnt lgkmcnt(0)" ::: "memory");
        for (int r = 0; r < n; ++r) {
            int i = 2 * lane + (r & 1);
            if (i + 1 < n) {
                int2 a = buf[wv][i], b = buf[wv][i + 1];
                if (a.y > b.y) { buf[wv][i] = b; buf[wv][i + 1] = a; }
            }
            asm volatile("s_waitcnt lgkmcnt(0)" ::: "memory");
        }
        for (int i = lane; i < n; i += 64) {
            int2 se = buf[wv][i];
            float eav = (se.y < N_EDGES) ? eaf[se.y] : ea_mean;
            se.y = __float_as_int(eav);
            cs[beg + i] = se;
        }
        return;
    }
    if (lane == 0) {
        for (int i = beg + 1; i < end; ++i) {
            int2 key = cs[i]; int j = i - 1;
            while (j >= beg && cs[j].y > key.y) { cs[j + 1] = cs[j]; --j; }
            cs[j + 1] = key;
        }
    }
    asm volatile("s_waitcnt vmcnt(0)" ::: "memory");
    for (int i = lane; i < n; i += 64) {
        int2 se = cs[beg + i];
        float eav = (se.y < N_EDGES) ? eaf[se.y] : ea_mean;
        se.y = __float_as_int(eav);
        cs[beg + i] = se;
    }
}

// ---- MFMA bf16 GEMM + al epilogue: atomicAdd into pre-zeroed als/ald ----
__global__ __launch_bounds__(256) void gemm_mfma_al(
        const short* __restrict__ A, const short* __restrict__ Bt,
        __hip_bfloat16* __restrict__ Cb, int N, int K,
        float* __restrict__ als, float* __restrict__ ald,
        const float* __restrict__ asv, const float* __restrict__ adv, int cshift) {
    __shared__ short As[128 * 40];
    __shared__ short Bs[64 * 40];
    int t = threadIdx.x;
    int wv = t >> 6, lane = t & 63, quad = lane >> 4, lr = lane & 15;
    int m0 = blockIdx.y * 128, n0 = blockIdx.x * 64;
    f4_t acc[2][4] = {};
    int ra0 = t >> 2, sa0 = t & 3;
    int ra1 = (t + 256) >> 2;
    for (int k0 = 0; k0 < K; k0 += 32) {
        *(uint4*)&As[ra0 * 40 + sa0 * 8] = *(const uint4*)&A[(size_t)(m0 + ra0) * K + k0 + sa0 * 8];
        *(uint4*)&As[ra1 * 40 + sa0 * 8] = *(const uint4*)&A[(size_t)(m0 + ra1) * K + k0 + sa0 * 8];
        *(uint4*)&Bs[ra0 * 40 + sa0 * 8] = *(const uint4*)&Bt[(size_t)(n0 + ra0) * K + k0 + sa0 * 8];
        __syncthreads();
        bf8_t a0 = *(const bf8_t*)&As[(wv * 16 + lr) * 40 + quad * 8];
        bf8_t a1 = *(const bf8_t*)&As[((wv + 4) * 16 + lr) * 40 + quad * 8];
#pragma unroll
        for (int nt = 0; nt < 4; ++nt) {
            bf8_t b = *(const bf8_t*)&Bs[(nt * 16 + lr) * 40 + quad * 8];
            acc[0][nt] = __builtin_amdgcn_mfma_f32_16x16x32_bf16(a0, b, acc[0][nt], 0, 0, 0);
            acc[1][nt] = __builtin_amdgcn_mfma_f32_16x16x32_bf16(a1, b, acc[1][nt], 0, 0, 0);
        }
        __syncthreads();
    }
#pragma unroll
    for (int si = 0; si < 2; ++si) {
        int mrow = m0 + (wv + si * 4) * 16 + quad * 4;
#pragma unroll
        for (int nt = 0; nt < 4; ++nt) {
            int col = n0 + nt * 16 + lr;
#pragma unroll
            for (int r = 0; r < 4; ++r)
                Cb[(size_t)(mrow + r) * N + col] = __float2bfloat16(acc[si][nt][r]);
        }
    }
    float asv4[4], adv4[4];
#pragma unroll
    for (int nt = 0; nt < 4; ++nt) {
        asv4[nt] = asv[n0 + nt * 16 + lr];
        adv4[nt] = adv[n0 + nt * 16 + lr];
    }
    int hsel = n0 >> cshift;
#pragma unroll
    for (int si = 0; si < 2; ++si) {
#pragma unroll
        for (int r = 0; r < 4; ++r) {
            float ps = 0.f, pd = 0.f;
#pragma unroll
            for (int nt = 0; nt < 4; ++nt) {
                ps += acc[si][nt][r] * asv4[nt];
                pd += acc[si][nt][r] * adv4[nt];
            }
#pragma unroll
            for (int m = 1; m < 16; m <<= 1) {
                ps += __shfl_xor(ps, m);
                pd += __shfl_xor(pd, m);
            }
            if (lr == 0) {
                int row = m0 + (wv + si * 4) * 16 + quad * 4 + r;
                atomicAdd(&als[row * 4 + hsel], ps);
                atomicAdd(&ald[row * 4 + hsel], pd);
            }
        }
    }
}

// ---- FUSED deterministic softmax+agg, layer 1: ONE WAVE per dst (4 dst / 256-thr block) ----
__global__ __launch_bounds__(256) void fused_agg1(
        const int* __restrict__ rowptr, const int2* __restrict__ cs,
        const float* __restrict__ als, const float* __restrict__ ald,
        const float* __restrict__ sbuf, const __hip_bfloat16* __restrict__ hb,
        __hip_bfloat16* __restrict__ outb) {
    __shared__ float lg[4][MAXDEG * 4];
    __shared__ int   ssrc[4][MAXDEG];
    int wv = threadIdx.x >> 6, t = threadIdx.x & 63;
    int d = blockIdx.x * 4 + wv;
    int beg = rowptr[d], n = rowptr[d + 1] - beg;
    bool fit = (n <= MAXDEG);
    float4 adv = *(const float4*)&ald[d * 4];
    float adh[4] = {adv.x, adv.y, adv.z, adv.w};
    float sb4[4] = {sbuf[0], sbuf[1], sbuf[2], sbuf[3]};
    float mx[4] = {-INFINITY, -INFINITY, -INFINITY, -INFINITY};
    for (int p = t; p < n; p += 64) {
        int2 se = cs[beg + p];
        float eav = __int_as_float(se.y);
        float4 as = *(const float4*)&als[se.x * 4];
        float l[4] = {as.x, as.y, as.z, as.w};
#pragma unroll
        for (int hh = 0; hh < 4; ++hh) {
            float v = l[hh] + adh[hh] + eav * sb4[hh];
            v = v > 0.f ? v : 0.2f * v;
            l[hh] = v;
            mx[hh] = fmaxf(mx[hh], v);
        }
        if (fit) {
            *(float4*)&lg[wv][p * 4] = make_float4(l[0], l[1], l[2], l[3]);
            ssrc[wv][p] = se.x;
        }
    }
#pragma unroll
    for (int m = 1; m < 64; m <<= 1)
#pragma unroll
        for (int hh = 0; hh < 4; ++hh)
            mx[hh] = fmaxf(mx[hh], __shfl_xor(mx[hh], m));
    // wave-local LDS producer/consumer: drain this wave's LDS writes only.
    asm volatile("s_waitcnt lgkmcnt(0)" ::: "memory");
    int h = t >> 4;                       // 8 channels/lane, 128 ch/head -> head = t>>4
    float mh = mx[h];
    float a[8] = {};
    float ds = 0.f;
    const __hip_bfloat16* hrow = hb + 8 * t;
#define ACC8(rr, wt) { \
    unsigned q0 = (rr).x, q1 = (rr).y, q2 = (rr).z, q3 = (rr).w; \
    a[0] += (wt) * __uint_as_float(q0 << 16); a[1] += (wt) * __uint_as_float(q0 & 0xFFFF0000u); \
    a[2] += (wt) * __uint_as_float(q1 << 16); a[3] += (wt) * __uint_as_float(q1 & 0xFFFF0000u); \
    a[4] += (wt) * __uint_as_float(q2 << 16); a[5] += (wt) * __uint_as_float(q2 & 0xFFFF0000u); \
    a[6] += (wt) * __uint_as_float(q3 << 16); a[7] += (wt) * __uint_as_float(q3 & 0xFFFF0000u); }
    if (fit) {
        int p = 0;
        for (; p + 8 <= n; p += 8) {
            int s0 = ssrc[wv][p],     s1 = ssrc[wv][p + 1], s2 = ssrc[wv][p + 2], s3 = ssrc[wv][p + 3];
            int s4 = ssrc[wv][p + 4], s5 = ssrc[wv][p + 5], s6 = ssrc[wv][p + 6], s7 = ssrc[wv][p + 7];
            uint4 r0 = *(const uint4*)&hrow[(size_t)s0 * 512];
            uint4 r1 = *(const uint4*)&hrow[(size_t)s1 * 512];
            uint4 r2 = *(const uint4*)&hrow[(size_t)s2 * 512];
            uint4 r3 = *(const uint4*)&hrow[(size_t)s3 * 512];
            uint4 r4 = *(const uint4*)&hrow[(size_t)s4 * 512];
            uint4 r5 = *(const uint4*)&hrow[(size_t)s5 * 512];
            uint4 r6 = *(const uint4*)&hrow[(size_t)s6 * 512];
            uint4 r7 = *(const uint4*)&hrow[(size_t)s7 * 512];
            float w0 = __expf(lg[wv][p * 4 + h] - mh);
            float w1 = __expf(lg[wv][p * 4 + 4 + h] - mh);
            float w2 = __expf(lg[wv][p * 4 + 8 + h] - mh);
            float w3 = __expf(lg[wv][p * 4 + 12 + h] - mh);
            float w4 = __expf(lg[wv][p * 4 + 16 + h] - mh);
            float w5 = __expf(lg[wv][p * 4 + 20 + h] - mh);
            float w6 = __expf(lg[wv][p * 4 + 24 + h] - mh);
            float w7 = __expf(lg[wv][p * 4 + 28 + h] - mh);
            ds += ((w0 + w1) + (w2 + w3)) + ((w4 + w5) + (w6 + w7));
            ACC8(r0, w0); ACC8(r1, w1); ACC8(r2, w2); ACC8(r3, w3);
            ACC8(r4, w4); ACC8(r5, w5); ACC8(r6, w6); ACC8(r7, w7);
        }
        for (; p + 4 <= n; p += 4) {
            int s0 = ssrc[wv][p], s1 = ssrc[wv][p + 1], s2 = ssrc[wv][p + 2], s3 = ssrc[wv][p + 3];
            uint4 r0 = *(const uint4*)&hrow[(size_t)s0 * 512];
            uint4 r1 = *(const uint4*)&hrow[(size_t)s1 * 512];
            uint4 r2 = *(const uint4*)&hrow[(size_t)s2 * 512];
            uint4 r3 = *(const uint4*)&hrow[(size_t)s3 * 512];
            float w0 = __expf(lg[wv][p * 4 + h] - mh);
            float w1 = __expf(lg[wv][p * 4 + 4 + h] - mh);
            float w2 = __expf(lg[wv][p * 4 + 8 + h] - mh);
            float w3 = __expf(lg[wv][p * 4 + 12 + h] - mh);
            ds += (w0 + w1) + (w2 + w3);
            ACC8(r0, w0); ACC8(r1, w1); ACC8(r2, w2); ACC8(r3, w3);
        }
        for (; p < n; ++p) {
            int s0 = ssrc[wv][p];
            uint4 r0 = *(const uint4*)&hrow[(size_t)s0 * 512];
            float w0 = __expf(lg[wv][p * 4 + h] - mh);
            ds += w0;
            ACC8(r0, w0);
        }
    } else {
        for (int p = 0; p < n; ++p) {
            int2 se = cs[beg + p];
            float eav = __int_as_float(se.y);
            float l = als[se.x * 4 + h] + adh[h] + eav * sb4[h];
            l = l > 0.f ? l : 0.2f * l;
            float w = __expf(l - mh);
            uint4 r0 = *(const uint4*)&hrow[(size_t)se.x * 512];
            ds += w;
            ACC8(r0, w);
        }
    }
#undef ACC8
    float rdn = 1.0f / (ds + 1e-16f);
    __hip_bfloat16 tmp[8];
#pragma unroll
    for (int j = 0; j < 8; ++j) tmp[j] = __float2bfloat16(a[j] * rdn);
    *(uint4*)&outb[(size_t)d * 512 + 8 * t] = *(uint4*)tmp;
}

// ---- FUSED softmax+agg+head-mean, layer 2: ONE WAVE per dst (4 dst / 256-thr block) ----
__global__ __launch_bounds__(256) void fused_agg2(
        const int* __restrict__ rowptr, const int2* __restrict__ cs,
        const float* __restrict__ als, const float* __restrict__ ald,
        const float* __restrict__ sbuf, const __hip_bfloat16* __restrict__ hb,
        float* __restrict__ out2) {
    __shared__ float lg[4][MAXDEG * 4];
    __shared__ int   ssrc[4][MAXDEG];
    int wv = threadIdx.x >> 6, t = threadIdx.x & 63;
    int d = blockIdx.x * 4 + wv;
    int beg = rowptr[d], n = rowptr[d + 1] - beg;
    bool fit = (n <= MAXDEG);
    float4 adv = *(const float4*)&ald[d * 4];
    float adh[4] = {adv.x, adv.y, adv.z, adv.w};
    float sb4[4] = {sbuf[4], sbuf[5], sbuf[6], sbuf[7]};
    float mx[4] = {-INFINITY, -INFINITY, -INFINITY, -INFINITY};
    for (int p = t; p < n; p += 64) {
        int2 se = cs[beg + p];
        float eav = __int_as_float(se.y);
        float4 as = *(const float4*)&als[se.x * 4];
        float l[4] = {as.x, as.y, as.z, as.w};
#pragma unroll
        for (int hh = 0; hh < 4; ++hh) {
            float v = l[hh] + adh[hh] + eav * sb4[hh];
            v = v > 0.f ? v : 0.2f * v;
            l[hh] = v;
            mx[hh] = fmaxf(mx[hh], v);
        }
        if (fit) {
            *(float4*)&lg[wv][p * 4] = make_float4(l[0], l[1], l[2], l[3]);
            ssrc[wv][p] = se.x;
        }
    }
#pragma unroll
    for (int m = 1; m < 64; m <<= 1)
#pragma unroll
        for (int hh = 0; hh < 4; ++hh)
            mx[hh] = fmaxf(mx[hh], __shfl_xor(mx[hh], m));
    asm volatile("s_waitcnt lgkmcnt(0)" ::: "memory");
    int h = t >> 4;
    float mh = mx[h];
    float a4[4] = {};
    float ds = 0.f;
    const __hip_bfloat16* hrow = hb + 4 * t;
#define ACC4(rr, wt) { \
    unsigned q0 = (rr).x, q1 = (rr).y; \
    a4[0] += (wt) * __uint_as_float(q0 << 16); a4[1] += (wt) * __uint_as_float(q0 & 0xFFFF0000u); \
    a4[2] += (wt) * __uint_as_float(q1 << 16); a4[3] += (wt) * __uint_as_float(q1 & 0xFFFF0000u); }
    if (fit) {
        int p = 0;
        for (; p + 8 <= n; p += 8) {
            int s0 = ssrc[wv][p],     s1 = ssrc[wv][p + 1], s2 = ssrc[wv][p + 2], s3 = ssrc[wv][p + 3];
            int s4 = ssrc[wv][p + 4], s5 = ssrc[wv][p + 5], s6 = ssrc[wv][p + 6], s7 = ssrc[wv][p + 7];
            uint2 r0 = *(const uint2*)&hrow[(size_t)s0 * 256];
            uint2 r1 = *(const uint2*)&hrow[(size_t)s1 * 256];
            uint2 r2 = *(const uint2*)&hrow[(size_t)s2 * 256];
            uint2 r3 = *(const uint2*)&hrow[(size_t)s3 * 256];
            uint2 r4 = *(const uint2*)&hrow[(size_t)s4 * 256];
            uint2 r5 = *(const uint2*)&hrow[(size_t)s5 * 256];
            uint2 r6 = *(const uint2*)&hrow[(size_t)s6 * 256];
            uint2 r7 = *(const uint2*)&hrow[(size_t)s7 * 256];
            float w0 = __expf(lg[wv][p * 4 + h] - mh);
            float w1 = __expf(lg[wv][p * 4 + 4 + h] - mh);
            float w2 = __expf(lg[wv][p * 4 + 8 + h] - mh);
            float w3 = __expf(lg[wv][p * 4 + 12 + h] - mh);
            float w4 = __expf(lg[wv][p * 4 + 16 + h] - mh);
            float w5 = __expf(lg[wv][p * 4 + 20 + h] - mh);
            float w6 = __expf(lg[wv][p * 4 + 24 + h] - mh);
            float w7 = __expf(lg[wv][p * 4 + 28 + h] - mh);
            ds += ((w0 + w1) + (w2 + w3)) + ((w4 + w5) + (w6 + w7));
            ACC4(r0, w0); ACC4(r1, w1); ACC4(r2, w2); ACC4(r3, w3);
            ACC4(r4, w4); ACC4(r5, w5); ACC4(r6, w6); ACC4(r7, w7);
        }
        for (; p + 4 <= n; p += 4) {
            int s0 = ssrc[wv][p], s1 = ssrc[wv][p + 1], s2 = ssrc[wv][p + 2], s3 = ssrc[wv][p + 3];
            uint2 r0 = *(const uint2*)&hrow[(size_t)s0 * 256];
            uint2 r1 = *(const uint2*)&hrow[(size_t)s1 * 256];
            uint2 r2 = *(const uint2*)&hrow[(size_t)s2 * 256];
            uint2 r3 = *(const uint2*)&hrow[(size_t)s3 * 256];
            float w0 = __expf(lg[wv][p * 4 + h] - mh);
            float w1 = __expf(lg[wv][p * 4 + 4 + h] - mh);
            float w2 = __expf(lg[wv][p * 4 + 8 + h] - mh);
            float w3 = __expf(lg[wv][p * 4 + 12 + h] - mh);
            ds += (w0 + w1) + (w2 + w3);
            ACC4(r0, w0); ACC4(r1, w1); ACC4(r2, w2); ACC4(r3, w3);
        }
        for (; p < n; ++p) {
            int s0 = ssrc[wv][p];
            uint2 r0 = *(const uint2*)&hrow[(size_t)s0 * 256];
            float w0 = __expf(lg[wv][p * 4 + h] - mh);
            ds += w0;
            ACC4(r0, w0);
        }
    } else {
        for (int p = 0; p < n; ++p) {
            int2 se = cs[beg + p];
            float eav = __int_as_float(se.y);
            float l = als[se.x * 4 + h] + adh[h] + eav * sb4[h];
            l = l > 0.f ? l : 0.2f * l;
            float w = __expf(l - mh);
            uint2 r0 = *(const uint2*)&hrow[(size_t)se.x * 256];
            ds += w;
            ACC4(r0, w);
        }
    }
#undef ACC4
    float rdn = 1.0f / (ds + 1e-16f);
#pragma unroll
    for (int j = 0; j < 4; ++j) {
        float v = a4[j] * rdn;
        v += __shfl_xor(v, 16);
        v += __shfl_xor(v, 32);
        a4[j] = v * 0.25f;
    }
    if (t < 16)
        *(float4*)&out2[(size_t)d * 64 + 4 * t] = make_float4(a4[0], a4[1], a4[2], a4[3]);
}

// ---- BN1 stats: per-block partials ----
__global__ __launch_bounds__(256) void bn_part_b(const __hip_bfloat16* __restrict__ x,
                                                 float* __restrict__ pmu, float* __restrict__ pm2) {
    int t = threadIdx.x, b = blockIdx.x;
    float s0 = 0.f, s20 = 0.f, s1 = 0.f, s21 = 0.f;
    for (int i = b; i < N_NODES; i += gridDim.x) {
        unsigned u = *(const unsigned*)&x[(size_t)i * 512 + 2 * t];
        float v0 = __uint_as_float(u << 16);
        float v1 = __uint_as_float(u & 0xFFFF0000u);
        s0 += v0; s20 += v0 * v0; s1 += v1; s21 += v1 * v1;
    }
    pmu[b * 512 + 2 * t] = s0;     pm2[b * 512 + 2 * t] = s20;
    pmu[b * 512 + 2 * t + 1] = s1; pm2[b * 512 + 2 * t + 1] = s21;
}

// ---- reduce partials -> affine a,b (fixed order) ----
__global__ void bn_reduce_affine(const float* __restrict__ pmu, const float* __restrict__ pm2,
                                 const float* __restrict__ smalls, int s_g, int s_be,
                                 float* __restrict__ a, float* __restrict__ b, int nch) {
    int c = blockIdx.x * blockDim.x + threadIdx.x;
    if (c >= nch) return;
    float s = 0.f, s2 = 0.f;
    for (int bk = 0; bk < 256; ++bk) { s += pmu[bk * nch + c]; s2 += pm2[bk * nch + c]; }
    float m = s * (1.0f / N_NODES);
    float var = s2 * (1.0f / N_NODES) - m * m;
    float aa = smalls[s_g + c] * rsqrtf(var + 1e-5f);
    a[c] = aa;
    b[c] = smalls[s_be + c] - m * aa;
}

// ---- BN1 apply + ELU in place on bf16 [N_NODES,512] ----
__global__ __launch_bounds__(256) void bn_apply_elu_b16(__hip_bfloat16* __restrict__ x,
                                                        const float* __restrict__ a,
                                                        const float* __restrict__ b) {
    int q = blockIdx.x * blockDim.x + threadIdx.x;
    if (q >= N_NODES * 512 / 4) return;
    int base = q * 4;
    int j = base & 511;
    uint2 raw = *(uint2*)&x[base];
    float v[4] = {__uint_as_float(raw.x << 16), __uint_as_float(raw.x & 0xFFFF0000u),
                  __uint_as_float(raw.y << 16), __uint_as_float(raw.y & 0xFFFF0000u)};
    __hip_bfloat16 tmp[4];
#pragma unroll
    for (int k = 0; k < 4; ++k) {
        float y = a[j + k] * v[k] + b[j + k];
        y = y > 0.f ? y : expm1f(y);
        tmp[k] = __float2bfloat16(y);
    }
    *(uint2*)&x[base] = *(uint2*)tmp;
}

// ---- BN2 stats: per-block partials ----
__global__ __launch_bounds__(256) void bn2_stats(const float* __restrict__ x,
                                                 float* __restrict__ pmu, float* __restrict__ pm2) {
    int t = threadIdx.x;
    int c = t & 63, j = t >> 6;
    float ls = 0.f, ls2 = 0.f;
    for (int nd = blockIdx.x * 4 + j; nd < N_NODES; nd += gridDim.x * 4) {
        float v = x[(size_t)nd * 64 + c];
        ls += v; ls2 += v * v;
    }
    __shared__ float shs[4][64], sh2[4][64];
    shs[j][c] = ls; sh2[j][c] = ls2;
    __syncthreads();
    if (j == 0) {
        pmu[blockIdx.x * 64 + c] = shs[0][c] + shs[1][c] + shs[2][c] + shs[3][c];
        pm2[blockIdx.x * 64 + c] = sh2[0][c] + sh2[1][c] + sh2[2][c] + sh2[3][c];
    }
}

// ---- pool stage 1: 8 chunks per graph, BN2 affine+ELU fused, partial sums ----
__global__ __launch_bounds__(256) void pool_part(const float* __restrict__ x, const int* __restrict__ gstart,
                                                 const float* __restrict__ a2, const float* __restrict__ b2,
                                                 float* __restrict__ pp) {
    int g = blockIdx.x >> 3, ck = blockIdx.x & 7;
    int t = threadIdx.x;
    int c = t & 63, j = t >> 6;
    int beg = gstart[g], end = gstart[g + 1], n = end - beg;
    int cb = beg + (n * ck) / 8, ce = beg + (n * (ck + 1)) / 8;
    float ac = a2[c], bc = b2[c];
    float s = 0.f;
    for (int i = cb + j; i < ce; i += 4) {
        float y = ac * x[(size_t)i * 64 + c] + bc;
        s += (y > 0.f ? y : expm1f(y));
    }
    __shared__ float sh[4][64];
    sh[j][c] = s;
    __syncthreads();
    if (j == 0)
        pp[blockIdx.x * 64 + c] = sh[0][c] + sh[1][c] + sh[2][c] + sh[3][c];
}

// ---- pool stage 2: reduce 8 chunks (fixed order) + MLP ----
__global__ __launch_bounds__(64) void pool_mlp_fin(const float* __restrict__ pp, const int* __restrict__ gstart,
                                                   const float* __restrict__ smalls, const int* __restrict__ flag,
                                                   void* __restrict__ outp) {
    int g = blockIdx.x, t = threadIdx.x;
    __shared__ float pooled[64];
    __shared__ float hsh[32];
    float s = 0.f;
    for (int k = 0; k < 8; ++k) s += pp[(g * 8 + k) * 64 + t];
    int n = gstart[g + 1] - gstart[g];
    pooled[t] = s / fmaxf((float)n, 1.0f);
    __syncthreads();
    if (t < 32) {
        float acc = smalls[S_FB1 + t];
        for (int cc = 0; cc < 64; ++cc)
            acc += pooled[cc] * smalls[S_FW1 + cc * 32 + t];
        hsh[t] = acc > 0.f ? acc : expm1f(acc);
    }
    __syncthreads();
    if (t == 0) {
        float o = smalls[S_FB2];
        for (int k = 0; k < 32; ++k) o += hsh[k] * smalls[S_FW2 + k];
        if (flag[0]) ((float*)outp)[g] = o;
        else ((__hip_bfloat16*)outp)[g] = __float2bfloat16(o);
    }
}

extern "C" void kernel_launch(void* const* d_in, const int* in_sizes, int n_in,
                              void* d_out, int out_size, void* d_ws, size_t ws_size,
                              hipStream_t stream) {
    const void* x    = d_in[0];
    const int* ei    = (const int*)d_in[1];
    const int* batch = (const int*)d_in[2];
    const void* ea   = d_in[3];
    const void* W1   = d_in[4];
    const void* as1  = d_in[5];
    const void* ad1  = d_in[6];
    const void* We1  = d_in[7];
    const void* ae1  = d_in[8];
    const void* g1   = d_in[10];
    const void* be1  = d_in[11];
    const void* W2   = d_in[12];
    const void* as2  = d_in[13];
    const void* ad2  = d_in[14];
    const void* We2  = d_in[15];
    const void* ae2  = d_in[16];
    const void* g2   = d_in[18];
    const void* be2  = d_in[19];
    const void* fw1  = d_in[20];
    const void* fb1  = d_in[21];
    const void* fw2  = d_in[22];
    const void* fb2  = d_in[23];

    char* ws = (char*)d_ws;
    __hip_bfloat16* xb   = (__hip_bfloat16*)(ws + XB_OFF);
    __hip_bfloat16* hb1  = (__hip_bfloat16*)(ws + HB1_OFF);
    __hip_bfloat16* agg1 = (__hip_bfloat16*)(ws + AGG1_OFF);
    __hip_bfloat16* hb2  = (__hip_bfloat16*)(ws + HB2_OFF);
    float* out2   = (float*)(ws + OUT2_OFF);
    float* eaf    = (float*)(ws + EAF_OFF);
    __hip_bfloat16* W1bt = (__hip_bfloat16*)(ws + W1BT_OFF);
    __hip_bfloat16* W2bt = (__hip_bfloat16*)(ws + W2BT_OFF);
    int2*  csr_se = (int2*)(ws + CSR_OFF);
    int*   rowptr = (int*)(ws + ROWPTR_OFF);
    int*   gstart = (int*)(ws + GSTART_OFF);
    float* smalls = (float*)(ws + SMALL_OFF);
    float* sbuf   = (float*)(ws + SBUF_OFF);
    float* eap    = (float*)(ws + EAP_OFF);
    float* pmu1   = (float*)(ws + PMU1_OFF);
    float* pm21   = (float*)(ws + PM21_OFF);
    float* pmu2   = (float*)(ws + PMU2_OFF);
    float* pm22   = (float*)(ws + PM22_OFF);
    float* a1     = (float*)(ws + A1_OFF);
    float* b1     = (float*)(ws + B1_OFF);
    float* a2     = (float*)(ws + A2_OFF);
    float* b2     = (float*)(ws + B2_OFF);
    float* ea_acc = (float*)(ws + EAACC_OFF);
    float* als1   = (float*)(ws + ALS1_OFF);
    float* ald1   = (float*)(ws + ALD1_OFF);
    float* als2   = (float*)(ws + ALS2_OFF);
    float* ald2   = (float*)(ws + ALD2_OFF);
    float* pp     = (float*)(ws + PP_OFF);
    int*   deg    = (int*)(ws + DEG_OFF);
    int*   cursor = (int*)(ws + CURS_OFF);
    int*   flag   = (int*)(ws + FLAGZ_OFF);

    hipMemsetAsync(ws + ZERO0_START, 0, ZERO0_SIZE, stream);

    detect_dtype<<<256, 256, 0, stream>>>((const unsigned short*)x, flag);
    prep<<<PREP_BLOCKS, 256, 0, stream>>>(flag, x, ea, W1, W2,
                                          as1, ad1, We1, ae1, g1, be1, as2, ad2,
                                          We2, ae2, g2, be2, fw1, fb1, fw2, fb2,
                                          xb, eaf, eap, W1bt, W2bt, smalls, sbuf);

    hist_bounds<<<HIST_BLOCKS + 79, 256, 0, stream>>>(ei, deg, batch, gstart);
    deg_scan<<<1, 1024, 0, stream>>>(deg, rowptr, eap, ea_acc);
    edge_scatter<<<HIST_BLOCKS, 256, 0, stream>>>(ei, rowptr, cursor, csr_se);
    csr_sort_fill<<<N_NODES / 4, 256, 0, stream>>>(rowptr, csr_se, eaf, ea_acc);

    // ---------- layer 1 ----------
    gemm_mfma_al<<<dim3(512 / 64, MPAD / 128), 256, 0, stream>>>(
        (const short*)xb, (const short*)W1bt, hb1, 512, 256,
        als1, ald1, smalls + S_AS1, smalls + S_AD1, 7);
    fused_agg1<<<N_NODES / 4, 256, 0, stream>>>(rowptr, csr_se, als1, ald1, sbuf, hb1, agg1);
    bn_part_b<<<256, 256, 0, stream>>>(agg1, pmu1, pm21);
    bn_reduce_affine<<<2, 256, 0, stream>>>(pmu1, pm21, smalls, S_G1, S_BE1, a1, b1, 512);
    bn_apply_elu_b16<<<10000, 256, 0, stream>>>(agg1, a1, b1);

    // ---------- layer 2 ----------
    gemm_mfma_al<<<dim3(256 / 64, MPAD / 128), 256, 0, stream>>>(
        (const short*)agg1, (const short*)W2bt, hb2, 256, 512,
        als2, ald2, smalls + S_AS2, smalls + S_AD2, 6);
    fused_agg2<<<N_NODES / 4, 256, 0, stream>>>(rowptr, csr_se, als2, ald2, sbuf, hb2, out2);
    bn2_stats<<<256, 256, 0, stream>>>(out2, pmu2, pm22);
    bn_reduce_affine<<<1, 64, 0, stream>>>(pmu2, pm22, smalls, S_G2, S_BE2, a2, b2, 64);

    // ---------- BN2+ELU+pool (2-stage) + MLP ----------
    pool_part<<<N_GRAPHS * 8, 256, 0, stream>>>(out2, gstart, a2, b2, pp);
    pool_mlp_fin<<<N_GRAPHS, 64, 0, stream>>>(pp, gstart, smalls, flag, d_out);
}

// Round 7
// 427.589 us; speedup vs baseline: 1.1168x; 1.0398x over previous
//
#include <hip/hip_runtime.h>
#include <hip/hip_bf16.h>

#define N_NODES  20000
#define MPAD     20096
#define N_EDGES  320000
#define N_EP     (N_EDGES + N_NODES)
#define D_IN     256
#define N_GRAPHS 32
#define HH1 4
#define CC1 128
#define HH2 4
#define CC2 64
#define MAXDEG   128

// ---- workspace layout (bytes) ----
#define XB_OFF      0ull                    // 10,289,152 : x bf16 [MPAD,256]
#define HB1_OFF     10289152ull             // 20,578,304 : h1 bf16 [MPAD,512]
#define AGG1_OFF    30867456ull             // 20,578,304 : agg1 bf16 [MPAD,512] (in-place BN)
#define HB2_OFF     51445760ull             // 10,289,152 : h2 bf16 [MPAD,256]
#define OUT2_OFF    61734912ull             //  5,120,000 : head-mean fp32 [20000,64] (pre-BN)
#define EAF_OFF     66854912ull             //  1,280,000
#define W1BT_OFF    68134912ull             //    262,144
#define W2BT_OFF    68397056ull             //    262,144
#define CSR_OFF     68659200ull             //  2,720,000 (int2: s, edge-id -> s, eav-bits)
#define ROWPTR_OFF  71379200ull             //     80,064
#define GSTART_OFF  71459264ull             //        256
#define SMALL_OFF   71459520ull             //     25,600
#define SBUF_OFF    71485120ull             //         64
#define EAP_OFF     71485184ull             //      1,280
#define ALSP_OFF    71486464ull             //    643,072 : al partials [MPAD*4][2]
#define ALDP_OFF    72129536ull             //    643,072
#define PMU1_OFF    72772608ull             //    524,288
#define PM21_OFF    73296896ull             //    524,288
#define PMU2_OFF    73821184ull             //     65,536
#define PM22_OFF    73886720ull             //     65,536
#define A1_OFF      73952256ull             //      2,048
#define B1_OFF      73954304ull             //      2,048
#define A2_OFF      73956352ull             //        256
#define B2_OFF      73956608ull             //        256
#define EAACC_OFF   73956864ull             //         64
#define ALS_OFF     73956928ull             //    321,536 : combined als [MPAD*4]
#define ALD_OFF     74278464ull             //    321,536
// ---- zeroed-at-start region ----
#define DEG_OFF     74600000ull             //     80,000
#define CURS_OFF    74680000ull             //     80,000
#define FLAGZ_OFF   74760000ull             //        128
#define ZERO0_START DEG_OFF
#define ZERO0_SIZE  160128ull
#define PP_OFF      74760128ull             //     65,536 : pool partials [256][64]

// small-region float offsets
#define S_AS1 0
#define S_AD1 512
#define S_WE1 1024
#define S_AE1 1536
#define S_G1  2048
#define S_BE1 2560
#define S_AS2 3072
#define S_AD2 3328
#define S_WE2 3584
#define S_AE2 3840
#define S_G2  4096
#define S_BE2 4160
#define S_FW1 4224
#define S_FB1 6272
#define S_FW2 6304
#define S_FB2 6336

typedef __attribute__((ext_vector_type(8))) short bf8_t;
typedef __attribute__((ext_vector_type(4))) float f4_t;

__device__ __forceinline__ float loadF(const void* p, int i, int fp32) {
    return fp32 ? ((const float*)p)[i]
                : __bfloat162float(((const __hip_bfloat16*)p)[i]);
}

// ---- fused dtype-detect + degree-hist + graph bounds ----
#define DH_DETECT 256
#define HIST_BLOCKS 1329
__global__ void detect_hist(const unsigned short* __restrict__ xr, int* __restrict__ flag,
                            const int* __restrict__ ei, int* __restrict__ deg,
                            const int* __restrict__ batch, int* __restrict__ gstart) {
    int b = blockIdx.x, t = threadIdx.x;
    if (b < DH_DETECT) {
        int i = b * 256 + t;
        unsigned short u = xr[i];
        if ((u & 0x7F80) == 0x7F80) atomicOr(flag, 1);
        return;
    }
    b -= DH_DETECT;
    if (b < HIST_BLOCKS) {
        int e = b * 256 + t;
        if (e >= N_EP) return;
        int d = (e < N_EDGES) ? ei[N_EDGES + e] : e - N_EDGES;
        atomicAdd(&deg[d], 1);
        return;
    }
    int i = (b - HIST_BLOCKS) * 256 + t;
    if (i >= N_NODES) return;
    int bb = batch[i];
    if (i == 0) {
        for (int g = 0; g <= bb; ++g) gstart[g] = 0;
    } else {
        int pb = batch[i - 1];
        for (int g = pb + 1; g <= bb; ++g) gstart[g] = i;
    }
    if (i == N_NODES - 1) {
        for (int g = bb + 1; g <= N_GRAPHS; ++g) gstart[g] = N_NODES;
    }
}

// ---- fused prep ----
#define PB_XB  5024
#define PB_EAF 313
#define PB_W   512
#define PB_SM  16
#define PREP_BLOCKS (PB_XB + PB_EAF + 2 * PB_W + PB_SM + 1)
__global__ __launch_bounds__(256) void prep(
        const int* __restrict__ flag,
        const void* x, const void* ea, const void* W1, const void* W2,
        const void* as1, const void* ad1, const void* We1, const void* ae1,
        const void* g1, const void* be1, const void* as2, const void* ad2,
        const void* We2, const void* ae2, const void* g2, const void* be2,
        const void* fw1, const void* fb1, const void* fw2, const void* fb2,
        __hip_bfloat16* __restrict__ xb, float* __restrict__ eaf, float* __restrict__ eap,
        __hip_bfloat16* __restrict__ W1bt, __hip_bfloat16* __restrict__ W2bt,
        float* __restrict__ smalls, float* __restrict__ sbuf) {
    __shared__ float shw[4];
    int b = blockIdx.x, t = threadIdx.x;
    int fp32 = flag[0];
    if (b < PB_XB) {
        int base = (b * 256 + t) * 4;
        __hip_bfloat16 tmp[4];
#pragma unroll
        for (int j = 0; j < 4; ++j) {
            int i = base + j;
            float v = (i < N_NODES * D_IN) ? loadF(x, i, fp32) : 0.f;
            tmp[j] = __float2bfloat16(v);
        }
        *(uint2*)&xb[base] = *(uint2*)tmp;
        return;
    }
    b -= PB_XB;
    if (b < PB_EAF) {
        int base = (b * 256 + t) * 4;
        float s = 0.f;
#pragma unroll
        for (int j = 0; j < 4; ++j) {
            int i = base + j;
            if (i < N_EDGES) { float v = loadF(ea, i, fp32); eaf[i] = v; s += v; }
        }
#pragma unroll
        for (int m = 1; m < 64; m <<= 1) s += __shfl_xor(s, m);
        if ((t & 63) == 0) shw[t >> 6] = s;
        __syncthreads();
        if (t == 0) eap[b] = shw[0] + shw[1] + shw[2] + shw[3];
        return;
    }
    b -= PB_EAF;
    if (b < PB_W) {
        int i = b * 256 + t;
        int k = i >> 9, n = i & 511;
        W1bt[(size_t)n * 256 + k] = __float2bfloat16(loadF(W1, i, fp32));
        return;
    }
    b -= PB_W;
    if (b < PB_W) {
        int i = b * 256 + t;
        int k = i >> 8, n = i & 255;
        W2bt[(size_t)n * 512 + k] = __float2bfloat16(loadF(W2, i, fp32));
        return;
    }
    b -= PB_W;
    if (b < PB_SM) {
        const void* srcs[16] = {as1, ad1, We1, ae1, g1, be1, as2, ad2, We2, ae2, g2, be2, fw1, fb1, fw2, fb2};
        const int cnts[16] = {512, 512, 512, 512, 512, 512, 256, 256, 256, 256, 64, 64, 2048, 32, 32, 1};
        const int offs[16] = {S_AS1, S_AD1, S_WE1, S_AE1, S_G1, S_BE1, S_AS2, S_AD2,
                              S_WE2, S_AE2, S_G2, S_BE2, S_FW1, S_FB1, S_FW2, S_FB2};
        for (int i = t; i < cnts[b]; i += 256)
            smalls[offs[b] + i] = loadF(srcs[b], i, fp32);
        return;
    }
    if (t < 4) {
        float s = 0.f;
        for (int c = 0; c < CC1; ++c) s += loadF(We1, t * CC1 + c, fp32) * loadF(ae1, t * CC1 + c, fp32);
        sbuf[t] = s;
    } else if (t < 8) {
        int h = t - 4;
        float s = 0.f;
        for (int c = 0; c < CC2; ++c) s += loadF(We2, h * CC2 + c, fp32) * loadF(ae2, h * CC2 + c, fp32);
        sbuf[4 + h] = s;
    }
}

__global__ __launch_bounds__(1024) void deg_scan(const int* __restrict__ deg, int* __restrict__ rowptr,
                                                 const float* __restrict__ eap, float* __restrict__ ea_acc) {
    __shared__ int part[1024];
    __shared__ float fsh[512];
    int t = threadIdx.x;
    int lo = t * 20;
    int hi = lo + 20; if (hi > N_NODES) hi = N_NODES; if (lo > N_NODES) lo = N_NODES;
    int s = 0;
    for (int i = lo; i < hi; ++i) s += deg[i];
    part[t] = s;
    __syncthreads();
    for (int off = 1; off < 1024; off <<= 1) {
        int u = (t >= off) ? part[t - off] : 0;
        __syncthreads();
        if (t >= off) part[t] += u;
        __syncthreads();
    }
    int run = part[t] - s;
    for (int i = lo; i < hi; ++i) { rowptr[i] = run; run += deg[i]; }
    if (hi == N_NODES && lo < N_NODES) rowptr[N_NODES] = run;
    if (t < 512) fsh[t] = (t < PB_EAF) ? eap[t] : 0.f;
    __syncthreads();
    for (int st = 256; st; st >>= 1) {
        if (t < st) fsh[t] += fsh[t + st];
        __syncthreads();
    }
    if (t == 0) ea_acc[0] = fsh[0];
}

__global__ void edge_scatter(const int* __restrict__ ei, const int* __restrict__ rowptr,
                             int* __restrict__ cursor, int2* __restrict__ csr_se) {
    int e = blockIdx.x * blockDim.x + threadIdx.x;
    if (e >= N_EP) return;
    int s, d;
    if (e < N_EDGES) { s = ei[e]; d = ei[N_EDGES + e]; }
    else { s = d = e - N_EDGES; }
    int pos = rowptr[d] + atomicAdd(&cursor[d], 1);
    csr_se[pos] = make_int2(s, e);
}

// ---- canonical CSR sort + eav fill ----
// n<=64: register odd-even transposition via shfl, n rounds (max-sentinel tail)
// 64<n<=128: LDS odd-even (64-thread block, cheap barriers)
// n>128: single-lane insertion (vanishingly rare)
__global__ __launch_bounds__(64) void csr_sort_fill(const int* __restrict__ rowptr, int2* __restrict__ cs,
                                                    const float* __restrict__ eaf,
                                                    const float* __restrict__ ea_acc) {
    __shared__ int2 buf[128];
    int d = blockIdx.x;
    int beg = rowptr[d], end = rowptr[d + 1], n = end - beg;
    int lane = threadIdx.x;
    float ea_mean = ea_acc[0] * (1.0f / N_EDGES);
    if (n <= 0) return;
    if (n <= 64) {
        int key = 0x7FFFFFFF, val = 0;
        if (lane < n) { int2 se = cs[beg + lane]; key = se.y; val = se.x; }
        for (int r = 0; r < n; ++r) {
            bool up = ((lane & 1) == (r & 1));
            int partner = up ? lane + 1 : lane - 1;
            bool valid = (partner >= 0) && (partner < 64);
            int pidx = valid ? partner : lane;
            int pk = __shfl(key, pidx);
            int pv = __shfl(val, pidx);
            if (valid && (up ? (pk < key) : (pk > key))) { key = pk; val = pv; }
        }
        if (lane < n) {
            float eav = (key < N_EDGES) ? eaf[key] : ea_mean;
            cs[beg + lane] = make_int2(val, __float_as_int(eav));
        }
        return;
    }
    if (n <= 128) {
        for (int i = lane; i < n; i += 64) buf[i] = cs[beg + i];
        __syncthreads();
        for (int r = 0; r < n; ++r) {
            int i = 2 * lane + (r & 1);
            if (i + 1 < n) {
                int2 a = buf[i], b = buf[i + 1];
                if (a.y > b.y) { buf[i] = b; buf[i + 1] = a; }
            }
            __syncthreads();
        }
        for (int i = lane; i < n; i += 64) {
            int2 se = buf[i];
            float eav = (se.y < N_EDGES) ? eaf[se.y] : ea_mean;
            se.y = __float_as_int(eav);
            cs[beg + i] = se;
        }
        return;
    }
    if (lane == 0) {
        for (int i = beg + 1; i < end; ++i) {
            int2 key = cs[i]; int j = i - 1;
            while (j >= beg && cs[j].y > key.y) { cs[j + 1] = cs[j]; --j; }
            cs[j + 1] = key;
        }
    }
    __syncthreads();
    for (int i = lane; i < n; i += 64) {
        int2 se = cs[beg + i];
        float eav = (se.y < N_EDGES) ? eaf[se.y] : ea_mean;
        se.y = __float_as_int(eav);
        cs[beg + i] = se;
    }
}

// ---- MFMA bf16 GEMM + al epilogue via deterministic partial slots ----
__global__ __launch_bounds__(256) void gemm_mfma_al(
        const short* __restrict__ A, const short* __restrict__ Bt,
        __hip_bfloat16* __restrict__ Cb, int N, int K,
        float* __restrict__ alsp, float* __restrict__ aldp,
        const float* __restrict__ asv, const float* __restrict__ adv, int cshift) {
    __shared__ short As[128 * 40];
    __shared__ short Bs[64 * 40];
    int t = threadIdx.x;
    int wv = t >> 6, lane = t & 63, quad = lane >> 4, lr = lane & 15;
    int m0 = blockIdx.y * 128, n0 = blockIdx.x * 64;
    f4_t acc[2][4] = {};
    int ra0 = t >> 2, sa0 = t & 3;
    int ra1 = (t + 256) >> 2;
    for (int k0 = 0; k0 < K; k0 += 32) {
        *(uint4*)&As[ra0 * 40 + sa0 * 8] = *(const uint4*)&A[(size_t)(m0 + ra0) * K + k0 + sa0 * 8];
        *(uint4*)&As[ra1 * 40 + sa0 * 8] = *(const uint4*)&A[(size_t)(m0 + ra1) * K + k0 + sa0 * 8];
        *(uint4*)&Bs[ra0 * 40 + sa0 * 8] = *(const uint4*)&Bt[(size_t)(n0 + ra0) * K + k0 + sa0 * 8];
        __syncthreads();
        bf8_t a0 = *(const bf8_t*)&As[(wv * 16 + lr) * 40 + quad * 8];
        bf8_t a1 = *(const bf8_t*)&As[((wv + 4) * 16 + lr) * 40 + quad * 8];
#pragma unroll
        for (int nt = 0; nt < 4; ++nt) {
            bf8_t b = *(const bf8_t*)&Bs[(nt * 16 + lr) * 40 + quad * 8];
            acc[0][nt] = __builtin_amdgcn_mfma_f32_16x16x32_bf16(a0, b, acc[0][nt], 0, 0, 0);
            acc[1][nt] = __builtin_amdgcn_mfma_f32_16x16x32_bf16(a1, b, acc[1][nt], 0, 0, 0);
        }
        __syncthreads();
    }
#pragma unroll
    for (int si = 0; si < 2; ++si) {
        int mrow = m0 + (wv + si * 4) * 16 + quad * 4;
#pragma unroll
        for (int nt = 0; nt < 4; ++nt) {
            int col = n0 + nt * 16 + lr;
#pragma unroll
            for (int r = 0; r < 4; ++r)
                Cb[(size_t)(mrow + r) * N + col] = __float2bfloat16(acc[si][nt][r]);
        }
    }
    float asv4[4], adv4[4];
#pragma unroll
    for (int nt = 0; nt < 4; ++nt) {
        asv4[nt] = asv[n0 + nt * 16 + lr];
        adv4[nt] = adv[n0 + nt * 16 + lr];
    }
    int hsel = n0 >> cshift;
    int parity = (n0 >> 6) & ((1 << (cshift - 6)) - 1);
#pragma unroll
    for (int si = 0; si < 2; ++si) {
#pragma unroll
        for (int r = 0; r < 4; ++r) {
            float ps = 0.f, pd = 0.f;
#pragma unroll
            for (int nt = 0; nt < 4; ++nt) {
                ps += acc[si][nt][r] * asv4[nt];
                pd += acc[si][nt][r] * adv4[nt];
            }
#pragma unroll
            for (int m = 1; m < 16; m <<= 1) {
                ps += __shfl_xor(ps, m);
                pd += __shfl_xor(pd, m);
            }
            if (lr == 0) {
                int row = m0 + (wv + si * 4) * 16 + quad * 4 + r;
                alsp[(row * 4 + hsel) * 2 + parity] = ps;
                aldp[(row * 4 + hsel) * 2 + parity] = pd;
            }
        }
    }
}

// ---- combine al partials in fixed order ----
__global__ void al_combine(const float* __restrict__ alsp, const float* __restrict__ aldp,
                           float* __restrict__ als, float* __restrict__ ald, int nparts) {
    int i = blockIdx.x * blockDim.x + threadIdx.x;
    if (i >= MPAD * 4) return;
    float s = alsp[2 * i], d0 = aldp[2 * i];
    if (nparts == 2) { s += alsp[2 * i + 1]; d0 += aldp[2 * i + 1]; }
    als[i] = s; ald[i] = d0;
}

// ---- FUSED deterministic softmax+agg, layer 1: ONE WAVE per dst (2 dst / block) ----
__global__ __launch_bounds__(128) void fused_agg1(
        const int* __restrict__ rowptr, const int2* __restrict__ cs,
        const float* __restrict__ als, const float* __restrict__ ald,
        const float* __restrict__ sbuf, const __hip_bfloat16* __restrict__ hb,
        __hip_bfloat16* __restrict__ outb) {
    __shared__ float lg[2][MAXDEG * 4];
    __shared__ int   ssrc[2][MAXDEG];
    int wv = threadIdx.x >> 6, t = threadIdx.x & 63;
    int d = blockIdx.x * 2 + wv;
    int beg = rowptr[d], n = rowptr[d + 1] - beg;
    bool fit = (n <= MAXDEG);
    float4 adv = *(const float4*)&ald[d * 4];
    float adh[4] = {adv.x, adv.y, adv.z, adv.w};
    float sb4[4] = {sbuf[0], sbuf[1], sbuf[2], sbuf[3]};
    float mx[4] = {-INFINITY, -INFINITY, -INFINITY, -INFINITY};
    for (int p = t; p < n; p += 64) {
        int2 se = cs[beg + p];
        float eav = __int_as_float(se.y);
        float4 as = *(const float4*)&als[se.x * 4];
        float l[4] = {as.x, as.y, as.z, as.w};
#pragma unroll
        for (int hh = 0; hh < 4; ++hh) {
            float v = l[hh] + adh[hh] + eav * sb4[hh];
            v = v > 0.f ? v : 0.2f * v;
            l[hh] = v;
            mx[hh] = fmaxf(mx[hh], v);
        }
        if (fit) {
            *(float4*)&lg[wv][p * 4] = make_float4(l[0], l[1], l[2], l[3]);
            ssrc[wv][p] = se.x;
        }
    }
#pragma unroll
    for (int m = 1; m < 64; m <<= 1)
#pragma unroll
        for (int hh = 0; hh < 4; ++hh)
            mx[hh] = fmaxf(mx[hh], __shfl_xor(mx[hh], m));
    // wave-local LDS producer/consumer: drain this wave's LDS writes only.
    asm volatile("s_waitcnt lgkmcnt(0)" ::: "memory");
    int h = t >> 4;                       // 8 channels/lane, 128 ch/head -> head = t>>4
    float mh = mx[h];
    float a[8] = {};
    float ds = 0.f;
    const __hip_bfloat16* hrow = hb + 8 * t;
#define ACC8(rr, wt) { \
    unsigned q0 = (rr).x, q1 = (rr).y, q2 = (rr).z, q3 = (rr).w; \
    a[0] += (wt) * __uint_as_float(q0 << 16); a[1] += (wt) * __uint_as_float(q0 & 0xFFFF0000u); \
    a[2] += (wt) * __uint_as_float(q1 << 16); a[3] += (wt) * __uint_as_float(q1 & 0xFFFF0000u); \
    a[4] += (wt) * __uint_as_float(q2 << 16); a[5] += (wt) * __uint_as_float(q2 & 0xFFFF0000u); \
    a[6] += (wt) * __uint_as_float(q3 << 16); a[7] += (wt) * __uint_as_float(q3 & 0xFFFF0000u); }
    if (fit) {
        int p = 0;
        for (; p + 8 <= n; p += 8) {
            int s0 = ssrc[wv][p],     s1 = ssrc[wv][p + 1], s2 = ssrc[wv][p + 2], s3 = ssrc[wv][p + 3];
            int s4 = ssrc[wv][p + 4], s5 = ssrc[wv][p + 5], s6 = ssrc[wv][p + 6], s7 = ssrc[wv][p + 7];
            uint4 r0 = *(const uint4*)&hrow[(size_t)s0 * 512];
            uint4 r1 = *(const uint4*)&hrow[(size_t)s1 * 512];
            uint4 r2 = *(const uint4*)&hrow[(size_t)s2 * 512];
            uint4 r3 = *(const uint4*)&hrow[(size_t)s3 * 512];
            uint4 r4 = *(const uint4*)&hrow[(size_t)s4 * 512];
            uint4 r5 = *(const uint4*)&hrow[(size_t)s5 * 512];
            uint4 r6 = *(const uint4*)&hrow[(size_t)s6 * 512];
            uint4 r7 = *(const uint4*)&hrow[(size_t)s7 * 512];
            float w0 = __expf(lg[wv][p * 4 + h] - mh);
            float w1 = __expf(lg[wv][p * 4 + 4 + h] - mh);
            float w2 = __expf(lg[wv][p * 4 + 8 + h] - mh);
            float w3 = __expf(lg[wv][p * 4 + 12 + h] - mh);
            float w4 = __expf(lg[wv][p * 4 + 16 + h] - mh);
            float w5 = __expf(lg[wv][p * 4 + 20 + h] - mh);
            float w6 = __expf(lg[wv][p * 4 + 24 + h] - mh);
            float w7 = __expf(lg[wv][p * 4 + 28 + h] - mh);
            ds += ((w0 + w1) + (w2 + w3)) + ((w4 + w5) + (w6 + w7));
            ACC8(r0, w0); ACC8(r1, w1); ACC8(r2, w2); ACC8(r3, w3);
            ACC8(r4, w4); ACC8(r5, w5); ACC8(r6, w6); ACC8(r7, w7);
        }
        for (; p + 4 <= n; p += 4) {
            int s0 = ssrc[wv][p], s1 = ssrc[wv][p + 1], s2 = ssrc[wv][p + 2], s3 = ssrc[wv][p + 3];
            uint4 r0 = *(const uint4*)&hrow[(size_t)s0 * 512];
            uint4 r1 = *(const uint4*)&hrow[(size_t)s1 * 512];
            uint4 r2 = *(const uint4*)&hrow[(size_t)s2 * 512];
            uint4 r3 = *(const uint4*)&hrow[(size_t)s3 * 512];
            float w0 = __expf(lg[wv][p * 4 + h] - mh);
            float w1 = __expf(lg[wv][p * 4 + 4 + h] - mh);
            float w2 = __expf(lg[wv][p * 4 + 8 + h] - mh);
            float w3 = __expf(lg[wv][p * 4 + 12 + h] - mh);
            ds += (w0 + w1) + (w2 + w3);
            ACC8(r0, w0); ACC8(r1, w1); ACC8(r2, w2); ACC8(r3, w3);
        }
        for (; p < n; ++p) {
            int s0 = ssrc[wv][p];
            uint4 r0 = *(const uint4*)&hrow[(size_t)s0 * 512];
            float w0 = __expf(lg[wv][p * 4 + h] - mh);
            ds += w0;
            ACC8(r0, w0);
        }
    } else {
        for (int p = 0; p < n; ++p) {
            int2 se = cs[beg + p];
            float eav = __int_as_float(se.y);
            float l = als[se.x * 4 + h] + adh[h] + eav * sb4[h];
            l = l > 0.f ? l : 0.2f * l;
            float w = __expf(l - mh);
            uint4 r0 = *(const uint4*)&hrow[(size_t)se.x * 512];
            ds += w;
            ACC8(r0, w);
        }
    }
#undef ACC8
    float rdn = 1.0f / (ds + 1e-16f);
    __hip_bfloat16 tmp[8];
#pragma unroll
    for (int j = 0; j < 8; ++j) tmp[j] = __float2bfloat16(a[j] * rdn);
    *(uint4*)&outb[(size_t)d * 512 + 8 * t] = *(uint4*)tmp;
}

// ---- FUSED softmax+agg+head-mean, layer 2: ONE WAVE per dst (2 dst / block) ----
__global__ __launch_bounds__(128) void fused_agg2(
        const int* __restrict__ rowptr, const int2* __restrict__ cs,
        const float* __restrict__ als, const float* __restrict__ ald,
        const float* __restrict__ sbuf, const __hip_bfloat16* __restrict__ hb,
        float* __restrict__ out2) {
    __shared__ float lg[2][MAXDEG * 4];
    __shared__ int   ssrc[2][MAXDEG];
    int wv = threadIdx.x >> 6, t = threadIdx.x & 63;
    int d = blockIdx.x * 2 + wv;
    int beg = rowptr[d], n = rowptr[d + 1] - beg;
    bool fit = (n <= MAXDEG);
    float4 adv = *(const float4*)&ald[d * 4];
    float adh[4] = {adv.x, adv.y, adv.z, adv.w};
    float sb4[4] = {sbuf[4], sbuf[5], sbuf[6], sbuf[7]};
    float mx[4] = {-INFINITY, -INFINITY, -INFINITY, -INFINITY};
    for (int p = t; p < n; p += 64) {
        int2 se = cs[beg + p];
        float eav = __int_as_float(se.y);
        float4 as = *(const float4*)&als[se.x * 4];
        float l[4] = {as.x, as.y, as.z, as.w};
#pragma unroll
        for (int hh = 0; hh < 4; ++hh) {
            float v = l[hh] + adh[hh] + eav * sb4[hh];
            v = v > 0.f ? v : 0.2f * v;
            l[hh] = v;
            mx[hh] = fmaxf(mx[hh], v);
        }
        if (fit) {
            *(float4*)&lg[wv][p * 4] = make_float4(l[0], l[1], l[2], l[3]);
            ssrc[wv][p] = se.x;
        }
    }
#pragma unroll
    for (int m = 1; m < 64; m <<= 1)
#pragma unroll
        for (int hh = 0; hh < 4; ++hh)
            mx[hh] = fmaxf(mx[hh], __shfl_xor(mx[hh], m));
    asm volatile("s_waitcnt lgkmcnt(0)" ::: "memory");
    int h = t >> 4;                       // 4 channels/lane, 64 ch/head -> head = t>>4
    float mh = mx[h];
    float a4[4] = {};
    float ds = 0.f;
    const __hip_bfloat16* hrow = hb + 4 * t;
#define ACC4(rr, wt) { \
    unsigned q0 = (rr).x, q1 = (rr).y; \
    a4[0] += (wt) * __uint_as_float(q0 << 16); a4[1] += (wt) * __uint_as_float(q0 & 0xFFFF0000u); \
    a4[2] += (wt) * __uint_as_float(q1 << 16); a4[3] += (wt) * __uint_as_float(q1 & 0xFFFF0000u); }
    if (fit) {
        int p = 0;
        for (; p + 8 <= n; p += 8) {
            int s0 = ssrc[wv][p],     s1 = ssrc[wv][p + 1], s2 = ssrc[wv][p + 2], s3 = ssrc[wv][p + 3];
            int s4 = ssrc[wv][p + 4], s5 = ssrc[wv][p + 5], s6 = ssrc[wv][p + 6], s7 = ssrc[wv][p + 7];
            uint2 r0 = *(const uint2*)&hrow[(size_t)s0 * 256];
            uint2 r1 = *(const uint2*)&hrow[(size_t)s1 * 256];
            uint2 r2 = *(const uint2*)&hrow[(size_t)s2 * 256];
            uint2 r3 = *(const uint2*)&hrow[(size_t)s3 * 256];
            uint2 r4 = *(const uint2*)&hrow[(size_t)s4 * 256];
            uint2 r5 = *(const uint2*)&hrow[(size_t)s5 * 256];
            uint2 r6 = *(const uint2*)&hrow[(size_t)s6 * 256];
            uint2 r7 = *(const uint2*)&hrow[(size_t)s7 * 256];
            float w0 = __expf(lg[wv][p * 4 + h] - mh);
            float w1 = __expf(lg[wv][p * 4 + 4 + h] - mh);
            float w2 = __expf(lg[wv][p * 4 + 8 + h] - mh);
            float w3 = __expf(lg[wv][p * 4 + 12 + h] - mh);
            float w4 = __expf(lg[wv][p * 4 + 16 + h] - mh);
            float w5 = __expf(lg[wv][p * 4 + 20 + h] - mh);
            float w6 = __expf(lg[wv][p * 4 + 24 + h] - mh);
            float w7 = __expf(lg[wv][p * 4 + 28 + h] - mh);
            ds += ((w0 + w1) + (w2 + w3)) + ((w4 + w5) + (w6 + w7));
            ACC4(r0, w0); ACC4(r1, w1); ACC4(r2, w2); ACC4(r3, w3);
            ACC4(r4, w4); ACC4(r5, w5); ACC4(r6, w6); ACC4(r7, w7);
        }
        for (; p + 4 <= n; p += 4) {
            int s0 = ssrc[wv][p], s1 = ssrc[wv][p + 1], s2 = ssrc[wv][p + 2], s3 = ssrc[wv][p + 3];
            uint2 r0 = *(const uint2*)&hrow[(size_t)s0 * 256];
            uint2 r1 = *(const uint2*)&hrow[(size_t)s1 * 256];
            uint2 r2 = *(const uint2*)&hrow[(size_t)s2 * 256];
            uint2 r3 = *(const uint2*)&hrow[(size_t)s3 * 256];
            float w0 = __expf(lg[wv][p * 4 + h] - mh);
            float w1 = __expf(lg[wv][p * 4 + 4 + h] - mh);
            float w2 = __expf(lg[wv][p * 4 + 8 + h] - mh);
            float w3 = __expf(lg[wv][p * 4 + 12 + h] - mh);
            ds += (w0 + w1) + (w2 + w3);
            ACC4(r0, w0); ACC4(r1, w1); ACC4(r2, w2); ACC4(r3, w3);
        }
        for (; p < n; ++p) {
            int s0 = ssrc[wv][p];
            uint2 r0 = *(const uint2*)&hrow[(size_t)s0 * 256];
            float w0 = __expf(lg[wv][p * 4 + h] - mh);
            ds += w0;
            ACC4(r0, w0);
        }
    } else {
        for (int p = 0; p < n; ++p) {
            int2 se = cs[beg + p];
            float eav = __int_as_float(se.y);
            float l = als[se.x * 4 + h] + adh[h] + eav * sb4[h];
            l = l > 0.f ? l : 0.2f * l;
            float w = __expf(l - mh);
            uint2 r0 = *(const uint2*)&hrow[(size_t)se.x * 256];
            ds += w;
            ACC4(r0, w);
        }
    }
#undef ACC4
    float rdn = 1.0f / (ds + 1e-16f);
#pragma unroll
    for (int j = 0; j < 4; ++j) {
        float v = a4[j] * rdn;
        v += __shfl_xor(v, 16);
        v += __shfl_xor(v, 32);
        a4[j] = v * 0.25f;
    }
    if (t < 16)
        *(float4*)&out2[(size_t)d * 64 + 4 * t] = make_float4(a4[0], a4[1], a4[2], a4[3]);
}

// ---- BN1 stats: per-block partials ----
__global__ __launch_bounds__(256) void bn_part_b(const __hip_bfloat16* __restrict__ x,
                                                 float* __restrict__ pmu, float* __restrict__ pm2) {
    int t = threadIdx.x, b = blockIdx.x;
    float s0 = 0.f, s20 = 0.f, s1 = 0.f, s21 = 0.f;
    for (int i = b; i < N_NODES; i += gridDim.x) {
        unsigned u = *(const unsigned*)&x[(size_t)i * 512 + 2 * t];
        float v0 = __uint_as_float(u << 16);
        float v1 = __uint_as_float(u & 0xFFFF0000u);
        s0 += v0; s20 += v0 * v0; s1 += v1; s21 += v1 * v1;
    }
    pmu[b * 512 + 2 * t] = s0;     pm2[b * 512 + 2 * t] = s20;
    pmu[b * 512 + 2 * t + 1] = s1; pm2[b * 512 + 2 * t + 1] = s21;
}

// ---- reduce partials -> affine a,b : parallel (4 splits/channel, fixed-order combine) ----
// grid = nch/64 blocks x 256 thr; thread (c = blk*64 + t&63, j = t>>6) sums bk in [j*64,(j+1)*64)
__global__ __launch_bounds__(256) void bn_reduce_affine(const float* __restrict__ pmu, const float* __restrict__ pm2,
                                 const float* __restrict__ smalls, int s_g, int s_be,
                                 float* __restrict__ a, float* __restrict__ b, int nch) {
    __shared__ float shs[4][64], sh2[4][64];
    int t = threadIdx.x;
    int cl = t & 63, j = t >> 6;
    int c = blockIdx.x * 64 + cl;
    float s = 0.f, s2 = 0.f;
    for (int bk = j * 64; bk < (j + 1) * 64; ++bk) { s += pmu[bk * nch + c]; s2 += pm2[bk * nch + c]; }
    shs[j][cl] = s; sh2[j][cl] = s2;
    __syncthreads();
    if (j == 0) {
        float st  = ((shs[0][cl] + shs[1][cl]) + (shs[2][cl] + shs[3][cl]));
        float st2 = ((sh2[0][cl] + sh2[1][cl]) + (sh2[2][cl] + sh2[3][cl]));
        float m = st * (1.0f / N_NODES);
        float var = st2 * (1.0f / N_NODES) - m * m;
        float aa = smalls[s_g + c] * rsqrtf(var + 1e-5f);
        a[c] = aa;
        b[c] = smalls[s_be + c] - m * aa;
    }
}

// ---- BN1 apply + ELU in place on bf16 [N_NODES,512] ----
__global__ __launch_bounds__(256) void bn_apply_elu_b16(__hip_bfloat16* __restrict__ x,
                                                        const float* __restrict__ a,
                                                        const float* __restrict__ b) {
    int q = blockIdx.x * blockDim.x + threadIdx.x;
    if (q >= N_NODES * 512 / 4) return;
    int base = q * 4;
    int j = base & 511;
    uint2 raw = *(uint2*)&x[base];
    float v[4] = {__uint_as_float(raw.x << 16), __uint_as_float(raw.x & 0xFFFF0000u),
                  __uint_as_float(raw.y << 16), __uint_as_float(raw.y & 0xFFFF0000u)};
    __hip_bfloat16 tmp[4];
#pragma unroll
    for (int k = 0; k < 4; ++k) {
        float y = a[j + k] * v[k] + b[j + k];
        y = y > 0.f ? y : expm1f(y);
        tmp[k] = __float2bfloat16(y);
    }
    *(uint2*)&x[base] = *(uint2*)tmp;
}

// ---- BN2 stats: per-block partials (64 blocks for the 64-ch reduce kernel's 256 bk layout) ----
__global__ __launch_bounds__(256) void bn2_stats(const float* __restrict__ x,
                                                 float* __restrict__ pmu, float* __restrict__ pm2) {
    int t = threadIdx.x;
    int c = t & 63, j = t >> 6;
    float ls = 0.f, ls2 = 0.f;
    for (int nd = blockIdx.x * 4 + j; nd < N_NODES; nd += gridDim.x * 4) {
        float v = x[(size_t)nd * 64 + c];
        ls += v; ls2 += v * v;
    }
    __shared__ float shs[4][64], sh2[4][64];
    shs[j][c] = ls; sh2[j][c] = ls2;
    __syncthreads();
    if (j == 0) {
        pmu[blockIdx.x * 64 + c] = shs[0][c] + shs[1][c] + shs[2][c] + shs[3][c];
        pm2[blockIdx.x * 64 + c] = sh2[0][c] + sh2[1][c] + sh2[2][c] + sh2[3][c];
    }
}

// ---- pool stage 1: 8 chunks per graph, BN2 affine+ELU fused, partial sums ----
__global__ __launch_bounds__(256) void pool_part(const float* __restrict__ x, const int* __restrict__ gstart,
                                                 const float* __restrict__ a2, const float* __restrict__ b2,
                                                 float* __restrict__ pp) {
    int g = blockIdx.x >> 3, ck = blockIdx.x & 7;
    int t = threadIdx.x;
    int c = t & 63, j = t >> 6;
    int beg = gstart[g], end = gstart[g + 1], n = end - beg;
    int cb = beg + (n * ck) / 8, ce = beg + (n * (ck + 1)) / 8;
    float ac = a2[c], bc = b2[c];
    float s = 0.f;
    for (int i = cb + j; i < ce; i += 4) {
        float y = ac * x[(size_t)i * 64 + c] + bc;
        s += (y > 0.f ? y : expm1f(y));
    }
    __shared__ float sh[4][64];
    sh[j][c] = s;
    __syncthreads();
    if (j == 0)
        pp[blockIdx.x * 64 + c] = sh[0][c] + sh[1][c] + sh[2][c] + sh[3][c];
}

// ---- pool stage 2: reduce 8 chunks (fixed order) + MLP ----
__global__ __launch_bounds__(64) void pool_mlp_fin(const float* __restrict__ pp, const int* __restrict__ gstart,
                                                   const float* __restrict__ smalls, const int* __restrict__ flag,
                                                   void* __restrict__ outp) {
    int g = blockIdx.x, t = threadIdx.x;
    __shared__ float pooled[64];
    __shared__ float hsh[32];
    float s = 0.f;
    for (int k = 0; k < 8; ++k) s += pp[(g * 8 + k) * 64 + t];
    int n = gstart[g + 1] - gstart[g];
    pooled[t] = s / fmaxf((float)n, 1.0f);
    __syncthreads();
    if (t < 32) {
        float acc = smalls[S_FB1 + t];
        for (int cc = 0; cc < 64; ++cc)
            acc += pooled[cc] * smalls[S_FW1 + cc * 32 + t];
        hsh[t] = acc > 0.f ? acc : expm1f(acc);
    }
    __syncthreads();
    if (t == 0) {
        float o = smalls[S_FB2];
        for (int k = 0; k < 32; ++k) o += hsh[k] * smalls[S_FW2 + k];
        if (flag[0]) ((float*)outp)[g] = o;
        else ((__hip_bfloat16*)outp)[g] = __float2bfloat16(o);
    }
}

extern "C" void kernel_launch(void* const* d_in, const int* in_sizes, int n_in,
                              void* d_out, int out_size, void* d_ws, size_t ws_size,
                              hipStream_t stream) {
    const void* x    = d_in[0];
    const int* ei    = (const int*)d_in[1];
    const int* batch = (const int*)d_in[2];
    const void* ea   = d_in[3];
    const void* W1   = d_in[4];
    const void* as1  = d_in[5];
    const void* ad1  = d_in[6];
    const void* We1  = d_in[7];
    const void* ae1  = d_in[8];
    const void* g1   = d_in[10];
    const void* be1  = d_in[11];
    const void* W2   = d_in[12];
    const void* as2  = d_in[13];
    const void* ad2  = d_in[14];
    const void* We2  = d_in[15];
    const void* ae2  = d_in[16];
    const void* g2   = d_in[18];
    const void* be2  = d_in[19];
    const void* fw1  = d_in[20];
    const void* fb1  = d_in[21];
    const void* fw2  = d_in[22];
    const void* fb2  = d_in[23];

    char* ws = (char*)d_ws;
    __hip_bfloat16* xb   = (__hip_bfloat16*)(ws + XB_OFF);
    __hip_bfloat16* hb1  = (__hip_bfloat16*)(ws + HB1_OFF);
    __hip_bfloat16* agg1 = (__hip_bfloat16*)(ws + AGG1_OFF);
    __hip_bfloat16* hb2  = (__hip_bfloat16*)(ws + HB2_OFF);
    float* out2   = (float*)(ws + OUT2_OFF);
    float* eaf    = (float*)(ws + EAF_OFF);
    __hip_bfloat16* W1bt = (__hip_bfloat16*)(ws + W1BT_OFF);
    __hip_bfloat16* W2bt = (__hip_bfloat16*)(ws + W2BT_OFF);
    int2*  csr_se = (int2*)(ws + CSR_OFF);
    int*   rowptr = (int*)(ws + ROWPTR_OFF);
    int*   gstart = (int*)(ws + GSTART_OFF);
    float* smalls = (float*)(ws + SMALL_OFF);
    float* sbuf   = (float*)(ws + SBUF_OFF);
    float* eap    = (float*)(ws + EAP_OFF);
    float* alsp   = (float*)(ws + ALSP_OFF);
    float* aldp   = (float*)(ws + ALDP_OFF);
    float* pmu1   = (float*)(ws + PMU1_OFF);
    float* pm21   = (float*)(ws + PM21_OFF);
    float* pmu2   = (float*)(ws + PMU2_OFF);
    float* pm22   = (float*)(ws + PM22_OFF);
    float* a1     = (float*)(ws + A1_OFF);
    float* b1     = (float*)(ws + B1_OFF);
    float* a2     = (float*)(ws + A2_OFF);
    float* b2     = (float*)(ws + B2_OFF);
    float* ea_acc = (float*)(ws + EAACC_OFF);
    float* als    = (float*)(ws + ALS_OFF);
    float* ald    = (float*)(ws + ALD_OFF);
    float* pp     = (float*)(ws + PP_OFF);
    int*   deg    = (int*)(ws + DEG_OFF);
    int*   cursor = (int*)(ws + CURS_OFF);
    int*   flag   = (int*)(ws + FLAGZ_OFF);

    hipMemsetAsync(ws + ZERO0_START, 0, ZERO0_SIZE, stream);

    detect_hist<<<DH_DETECT + HIST_BLOCKS + 79, 256, 0, stream>>>(
        (const unsigned short*)x, flag, ei, deg, batch, gstart);
    prep<<<PREP_BLOCKS, 256, 0, stream>>>(flag, x, ea, W1, W2,
                                          as1, ad1, We1, ae1, g1, be1, as2, ad2,
                                          We2, ae2, g2, be2, fw1, fb1, fw2, fb2,
                                          xb, eaf, eap, W1bt, W2bt, smalls, sbuf);

    deg_scan<<<1, 1024, 0, stream>>>(deg, rowptr, eap, ea_acc);
    edge_scatter<<<HIST_BLOCKS, 256, 0, stream>>>(ei, rowptr, cursor, csr_se);
    csr_sort_fill<<<N_NODES, 64, 0, stream>>>(rowptr, csr_se, eaf, ea_acc);

    // ---------- layer 1 ----------
    gemm_mfma_al<<<dim3(512 / 64, MPAD / 128), 256, 0, stream>>>(
        (const short*)xb, (const short*)W1bt, hb1, 512, 256,
        alsp, aldp, smalls + S_AS1, smalls + S_AD1, 7);
    al_combine<<<(MPAD * 4 + 255) / 256, 256, 0, stream>>>(alsp, aldp, als, ald, 2);
    fused_agg1<<<N_NODES / 2, 128, 0, stream>>>(rowptr, csr_se, als, ald, sbuf, hb1, agg1);
    bn_part_b<<<256, 256, 0, stream>>>(agg1, pmu1, pm21);
    bn_reduce_affine<<<8, 256, 0, stream>>>(pmu1, pm21, smalls, S_G1, S_BE1, a1, b1, 512);
    bn_apply_elu_b16<<<10000, 256, 0, stream>>>(agg1, a1, b1);

    // ---------- layer 2 ----------
    gemm_mfma_al<<<dim3(256 / 64, MPAD / 128), 256, 0, stream>>>(
        (const short*)agg1, (const short*)W2bt, hb2, 256, 512,
        alsp, aldp, smalls + S_AS2, smalls + S_AD2, 6);
    al_combine<<<(MPAD * 4 + 255) / 256, 256, 0, stream>>>(alsp, aldp, als, ald, 1);
    fused_agg2<<<N_NODES / 2, 128, 0, stream>>>(rowptr, csr_se, als, ald, sbuf, hb2, out2);
    bn2_stats<<<256, 256, 0, stream>>>(out2, pmu2, pm22);
    bn_reduce_affine<<<1, 256, 0, stream>>>(pmu2, pm22, smalls, S_G2, S_BE2, a2, b2, 64);

    // ---------- BN2+ELU+pool (2-stage) + MLP ----------
    pool_part<<<N_GRAPHS * 8, 256, 0, stream>>>(out2, gstart, a2, b2, pp);
    pool_mlp_fin<<<N_GRAPHS, 64, 0, stream>>>(pp, gstart, smalls, flag, d_out);
}

// Round 8
// 418.230 us; speedup vs baseline: 1.1417x; 1.0224x over previous
//
#include <hip/hip_runtime.h>
#include <hip/hip_bf16.h>

#define N_NODES  20000
#define MPAD     20096
#define N_EDGES  320000
#define N_EP     (N_EDGES + N_NODES)
#define D_IN     256
#define N_GRAPHS 32
#define HH1 4
#define CC1 128
#define HH2 4
#define CC2 64
#define MAXDEG   128

// ---- workspace layout (bytes) ----
#define XB_OFF      0ull                    // 10,289,152 : x bf16 [MPAD,256]
#define HB1_OFF     10289152ull             // 20,578,304 : h1 bf16 [MPAD,512]
#define AGG1_OFF    30867456ull             // 20,578,304 : agg1 bf16 [MPAD,512] (raw, pre-BN)
#define HB2_OFF     51445760ull             // 10,289,152 : h2 bf16 [MPAD,256]
#define OUT2_OFF    61734912ull             //  5,120,000 : head-mean fp32 [20000,64] (pre-BN)
#define EAF_OFF     66854912ull             //  1,280,000
#define W1BT_OFF    68134912ull             //    262,144
#define W2BT_OFF    68397056ull             //    262,144
#define CSR_OFF     68659200ull             //  2,720,000 (int2: s, edge-id -> s, eav-bits)
#define ROWPTR_OFF  71379200ull             //     80,064
#define GSTART_OFF  71459264ull             //        256
#define SMALL_OFF   71459520ull             //     25,600
#define SBUF_OFF    71485120ull             //         64
#define EAP_OFF     71485184ull             //      1,280
#define ALSP_OFF    71486464ull             //    643,072 : al partials [MPAD*4][2]
#define ALDP_OFF    72129536ull             //    643,072
#define PMU1_OFF    72772608ull             //    524,288
#define PM21_OFF    73296896ull             //    524,288
#define PMU2_OFF    73821184ull             //     65,536
#define PM22_OFF    73886720ull             //     65,536
#define A1_OFF      73952256ull             //      2,048
#define B1_OFF      73954304ull             //      2,048
#define A2_OFF      73956352ull             //        256
#define B2_OFF      73956608ull             //        256
#define EAACC_OFF   73956864ull             //         64
// ---- zeroed-at-start region ----
#define DEG_OFF     74600000ull             //     80,000
#define CURS_OFF    74680000ull             //     80,000
#define FLAGZ_OFF   74760000ull             //        128
#define ZERO0_START DEG_OFF
#define ZERO0_SIZE  160128ull
#define PP_OFF      74760128ull             //     65,536 : pool partials [256][64]

// small-region float offsets
#define S_AS1 0
#define S_AD1 512
#define S_WE1 1024
#define S_AE1 1536
#define S_G1  2048
#define S_BE1 2560
#define S_AS2 3072
#define S_AD2 3328
#define S_WE2 3584
#define S_AE2 3840
#define S_G2  4096
#define S_BE2 4160
#define S_FW1 4224
#define S_FB1 6272
#define S_FW2 6304
#define S_FB2 6336

typedef __attribute__((ext_vector_type(8))) short bf8_t;
typedef __attribute__((ext_vector_type(4))) float f4_t;

__device__ __forceinline__ float loadF(const void* p, int i, int fp32) {
    return fp32 ? ((const float*)p)[i]
                : __bfloat162float(((const __hip_bfloat16*)p)[i]);
}

// ---- fused dtype-detect + degree-hist + graph bounds ----
#define DH_DETECT 256
#define HIST_BLOCKS 1329
__global__ void detect_hist(const unsigned short* __restrict__ xr, int* __restrict__ flag,
                            const int* __restrict__ ei, int* __restrict__ deg,
                            const int* __restrict__ batch, int* __restrict__ gstart) {
    int b = blockIdx.x, t = threadIdx.x;
    if (b < DH_DETECT) {
        int i = b * 256 + t;
        unsigned short u = xr[i];
        if ((u & 0x7F80) == 0x7F80) atomicOr(flag, 1);
        return;
    }
    b -= DH_DETECT;
    if (b < HIST_BLOCKS) {
        int e = b * 256 + t;
        if (e >= N_EP) return;
        int d = (e < N_EDGES) ? ei[N_EDGES + e] : e - N_EDGES;
        atomicAdd(&deg[d], 1);
        return;
    }
    int i = (b - HIST_BLOCKS) * 256 + t;
    if (i >= N_NODES) return;
    int bb = batch[i];
    if (i == 0) {
        for (int g = 0; g <= bb; ++g) gstart[g] = 0;
    } else {
        int pb = batch[i - 1];
        for (int g = pb + 1; g <= bb; ++g) gstart[g] = i;
    }
    if (i == N_NODES - 1) {
        for (int g = bb + 1; g <= N_GRAPHS; ++g) gstart[g] = N_NODES;
    }
}

// ---- fused prep ----
#define PB_XB  5024
#define PB_EAF 313
#define PB_W   512
#define PB_SM  16
#define PREP_BLOCKS (PB_XB + PB_EAF + 2 * PB_W + PB_SM + 1)
__global__ __launch_bounds__(256) void prep(
        const int* __restrict__ flag,
        const void* x, const void* ea, const void* W1, const void* W2,
        const void* as1, const void* ad1, const void* We1, const void* ae1,
        const void* g1, const void* be1, const void* as2, const void* ad2,
        const void* We2, const void* ae2, const void* g2, const void* be2,
        const void* fw1, const void* fb1, const void* fw2, const void* fb2,
        __hip_bfloat16* __restrict__ xb, float* __restrict__ eaf, float* __restrict__ eap,
        __hip_bfloat16* __restrict__ W1bt, __hip_bfloat16* __restrict__ W2bt,
        float* __restrict__ smalls, float* __restrict__ sbuf) {
    __shared__ float shw[4];
    int b = blockIdx.x, t = threadIdx.x;
    int fp32 = flag[0];
    if (b < PB_XB) {
        int base = (b * 256 + t) * 4;
        __hip_bfloat16 tmp[4];
#pragma unroll
        for (int j = 0; j < 4; ++j) {
            int i = base + j;
            float v = (i < N_NODES * D_IN) ? loadF(x, i, fp32) : 0.f;
            tmp[j] = __float2bfloat16(v);
        }
        *(uint2*)&xb[base] = *(uint2*)tmp;
        return;
    }
    b -= PB_XB;
    if (b < PB_EAF) {
        int base = (b * 256 + t) * 4;
        float s = 0.f;
#pragma unroll
        for (int j = 0; j < 4; ++j) {
            int i = base + j;
            if (i < N_EDGES) { float v = loadF(ea, i, fp32); eaf[i] = v; s += v; }
        }
#pragma unroll
        for (int m = 1; m < 64; m <<= 1) s += __shfl_xor(s, m);
        if ((t & 63) == 0) shw[t >> 6] = s;
        __syncthreads();
        if (t == 0) eap[b] = shw[0] + shw[1] + shw[2] + shw[3];
        return;
    }
    b -= PB_EAF;
    if (b < PB_W) {
        int i = b * 256 + t;
        int k = i >> 9, n = i & 511;
        W1bt[(size_t)n * 256 + k] = __float2bfloat16(loadF(W1, i, fp32));
        return;
    }
    b -= PB_W;
    if (b < PB_W) {
        int i = b * 256 + t;
        int k = i >> 8, n = i & 255;
        W2bt[(size_t)n * 512 + k] = __float2bfloat16(loadF(W2, i, fp32));
        return;
    }
    b -= PB_W;
    if (b < PB_SM) {
        const void* srcs[16] = {as1, ad1, We1, ae1, g1, be1, as2, ad2, We2, ae2, g2, be2, fw1, fb1, fw2, fb2};
        const int cnts[16] = {512, 512, 512, 512, 512, 512, 256, 256, 256, 256, 64, 64, 2048, 32, 32, 1};
        const int offs[16] = {S_AS1, S_AD1, S_WE1, S_AE1, S_G1, S_BE1, S_AS2, S_AD2,
                              S_WE2, S_AE2, S_G2, S_BE2, S_FW1, S_FB1, S_FW2, S_FB2};
        for (int i = t; i < cnts[b]; i += 256)
            smalls[offs[b] + i] = loadF(srcs[b], i, fp32);
        return;
    }
    if (t < 4) {
        float s = 0.f;
        for (int c = 0; c < CC1; ++c) s += loadF(We1, t * CC1 + c, fp32) * loadF(ae1, t * CC1 + c, fp32);
        sbuf[t] = s;
    } else if (t < 8) {
        int h = t - 4;
        float s = 0.f;
        for (int c = 0; c < CC2; ++c) s += loadF(We2, h * CC2 + c, fp32) * loadF(ae2, h * CC2 + c, fp32);
        sbuf[4 + h] = s;
    }
}

__global__ __launch_bounds__(1024) void deg_scan(const int* __restrict__ deg, int* __restrict__ rowptr,
                                                 const float* __restrict__ eap, float* __restrict__ ea_acc) {
    __shared__ int part[1024];
    __shared__ float fsh[512];
    int t = threadIdx.x;
    int lo = t * 20;
    int hi = lo + 20; if (hi > N_NODES) hi = N_NODES; if (lo > N_NODES) lo = N_NODES;
    int s = 0;
    for (int i = lo; i < hi; ++i) s += deg[i];
    part[t] = s;
    __syncthreads();
    for (int off = 1; off < 1024; off <<= 1) {
        int u = (t >= off) ? part[t - off] : 0;
        __syncthreads();
        if (t >= off) part[t] += u;
        __syncthreads();
    }
    int run = part[t] - s;
    for (int i = lo; i < hi; ++i) { rowptr[i] = run; run += deg[i]; }
    if (hi == N_NODES && lo < N_NODES) rowptr[N_NODES] = run;
    if (t < 512) fsh[t] = (t < PB_EAF) ? eap[t] : 0.f;
    __syncthreads();
    for (int st = 256; st; st >>= 1) {
        if (t < st) fsh[t] += fsh[t + st];
        __syncthreads();
    }
    if (t == 0) ea_acc[0] = fsh[0];
}

__global__ void edge_scatter(const int* __restrict__ ei, const int* __restrict__ rowptr,
                             int* __restrict__ cursor, int2* __restrict__ csr_se) {
    int e = blockIdx.x * blockDim.x + threadIdx.x;
    if (e >= N_EP) return;
    int s, d;
    if (e < N_EDGES) { s = ei[e]; d = ei[N_EDGES + e]; }
    else { s = d = e - N_EDGES; }
    int pos = rowptr[d] + atomicAdd(&cursor[d], 1);
    csr_se[pos] = make_int2(s, e);
}

// ---- canonical CSR sort + eav fill ----
__global__ __launch_bounds__(64) void csr_sort_fill(const int* __restrict__ rowptr, int2* __restrict__ cs,
                                                    const float* __restrict__ eaf,
                                                    const float* __restrict__ ea_acc) {
    __shared__ int2 buf[128];
    int d = blockIdx.x;
    int beg = rowptr[d], end = rowptr[d + 1], n = end - beg;
    int lane = threadIdx.x;
    float ea_mean = ea_acc[0] * (1.0f / N_EDGES);
    if (n <= 0) return;
    if (n <= 64) {
        int key = 0x7FFFFFFF, val = 0;
        if (lane < n) { int2 se = cs[beg + lane]; key = se.y; val = se.x; }
        for (int r = 0; r < n; ++r) {
            bool up = ((lane & 1) == (r & 1));
            int partner = up ? lane + 1 : lane - 1;
            bool valid = (partner >= 0) && (partner < 64);
            int pidx = valid ? partner : lane;
            int pk = __shfl(key, pidx);
            int pv = __shfl(val, pidx);
            if (valid && (up ? (pk < key) : (pk > key))) { key = pk; val = pv; }
        }
        if (lane < n) {
            float eav = (key < N_EDGES) ? eaf[key] : ea_mean;
            cs[beg + lane] = make_int2(val, __float_as_int(eav));
        }
        return;
    }
    if (n <= 128) {
        for (int i = lane; i < n; i += 64) buf[i] = cs[beg + i];
        __syncthreads();
        for (int r = 0; r < n; ++r) {
            int i = 2 * lane + (r & 1);
            if (i + 1 < n) {
                int2 a = buf[i], b = buf[i + 1];
                if (a.y > b.y) { buf[i] = b; buf[i + 1] = a; }
            }
            __syncthreads();
        }
        for (int i = lane; i < n; i += 64) {
            int2 se = buf[i];
            float eav = (se.y < N_EDGES) ? eaf[se.y] : ea_mean;
            se.y = __float_as_int(eav);
            cs[beg + i] = se;
        }
        return;
    }
    if (lane == 0) {
        for (int i = beg + 1; i < end; ++i) {
            int2 key = cs[i]; int j = i - 1;
            while (j >= beg && cs[j].y > key.y) { cs[j + 1] = cs[j]; --j; }
            cs[j + 1] = key;
        }
    }
    __syncthreads();
    for (int i = lane; i < n; i += 64) {
        int2 se = cs[beg + i];
        float eav = (se.y < N_EDGES) ? eaf[se.y] : ea_mean;
        se.y = __float_as_int(eav);
        cs[beg + i] = se;
    }
}

// ---- BN1-affine + ELU + bf16 repack for 8 contiguous channels (bit-identical to the old
//      standalone bn_apply_elu pass: same fp32 affine, same expm1, same bf16 rounding) ----
__device__ __forceinline__ uint4 bn_elu_pack(uint4 v, const float* __restrict__ a8,
                                             const float* __restrict__ b8) {
    unsigned q[4] = {v.x, v.y, v.z, v.w};
    float4 a0 = *(const float4*)a8, a1 = *(const float4*)(a8 + 4);
    float4 b0 = *(const float4*)b8, b1 = *(const float4*)(b8 + 4);
    float av[8] = {a0.x, a0.y, a0.z, a0.w, a1.x, a1.y, a1.z, a1.w};
    float bv[8] = {b0.x, b0.y, b0.z, b0.w, b1.x, b1.y, b1.z, b1.w};
    __hip_bfloat16 t[8];
#pragma unroll
    for (int k = 0; k < 8; ++k) {
        unsigned u = (k & 1) ? (q[k >> 1] & 0xFFFF0000u) : (q[k >> 1] << 16);
        float y = av[k] * __uint_as_float(u) + bv[k];
        y = y > 0.f ? y : expm1f(y);
        t[k] = __float2bfloat16(y);
    }
    return *(uint4*)t;
}

// ---- MFMA bf16 GEMM + al epilogue via deterministic partial slots ----
// optional BN1+ELU fold on the A operand (bna/bnb non-null => layer-2 path)
__global__ __launch_bounds__(256) void gemm_mfma_al(
        const short* __restrict__ A, const short* __restrict__ Bt,
        __hip_bfloat16* __restrict__ Cb, int N, int K,
        float* __restrict__ alsp, float* __restrict__ aldp,
        const float* __restrict__ asv, const float* __restrict__ adv, int cshift,
        const float* __restrict__ bna, const float* __restrict__ bnb) {
    __shared__ short As[128 * 40];
    __shared__ short Bs[64 * 40];
    int t = threadIdx.x;
    int wv = t >> 6, lane = t & 63, quad = lane >> 4, lr = lane & 15;
    int m0 = blockIdx.y * 128, n0 = blockIdx.x * 64;
    f4_t acc[2][4] = {};
    int ra0 = t >> 2, sa0 = t & 3;
    int ra1 = (t + 256) >> 2;
    for (int k0 = 0; k0 < K; k0 += 32) {
        uint4 va0 = *(const uint4*)&A[(size_t)(m0 + ra0) * K + k0 + sa0 * 8];
        uint4 va1 = *(const uint4*)&A[(size_t)(m0 + ra1) * K + k0 + sa0 * 8];
        uint4 vb  = *(const uint4*)&Bt[(size_t)(n0 + ra0) * K + k0 + sa0 * 8];
        if (bna) {
            int j = k0 + sa0 * 8;
            va0 = bn_elu_pack(va0, bna + j, bnb + j);
            va1 = bn_elu_pack(va1, bna + j, bnb + j);
        }
        *(uint4*)&As[ra0 * 40 + sa0 * 8] = va0;
        *(uint4*)&As[ra1 * 40 + sa0 * 8] = va1;
        *(uint4*)&Bs[ra0 * 40 + sa0 * 8] = vb;
        __syncthreads();
        bf8_t a0 = *(const bf8_t*)&As[(wv * 16 + lr) * 40 + quad * 8];
        bf8_t a1 = *(const bf8_t*)&As[((wv + 4) * 16 + lr) * 40 + quad * 8];
#pragma unroll
        for (int nt = 0; nt < 4; ++nt) {
            bf8_t b = *(const bf8_t*)&Bs[(nt * 16 + lr) * 40 + quad * 8];
            acc[0][nt] = __builtin_amdgcn_mfma_f32_16x16x32_bf16(a0, b, acc[0][nt], 0, 0, 0);
            acc[1][nt] = __builtin_amdgcn_mfma_f32_16x16x32_bf16(a1, b, acc[1][nt], 0, 0, 0);
        }
        __syncthreads();
    }
#pragma unroll
    for (int si = 0; si < 2; ++si) {
        int mrow = m0 + (wv + si * 4) * 16 + quad * 4;
#pragma unroll
        for (int nt = 0; nt < 4; ++nt) {
            int col = n0 + nt * 16 + lr;
#pragma unroll
            for (int r = 0; r < 4; ++r)
                Cb[(size_t)(mrow + r) * N + col] = __float2bfloat16(acc[si][nt][r]);
        }
    }
    float asv4[4], adv4[4];
#pragma unroll
    for (int nt = 0; nt < 4; ++nt) {
        asv4[nt] = asv[n0 + nt * 16 + lr];
        adv4[nt] = adv[n0 + nt * 16 + lr];
    }
    int hsel = n0 >> cshift;
    int parity = (n0 >> 6) & ((1 << (cshift - 6)) - 1);
#pragma unroll
    for (int si = 0; si < 2; ++si) {
#pragma unroll
        for (int r = 0; r < 4; ++r) {
            float ps = 0.f, pd = 0.f;
#pragma unroll
            for (int nt = 0; nt < 4; ++nt) {
                ps += acc[si][nt][r] * asv4[nt];
                pd += acc[si][nt][r] * adv4[nt];
            }
#pragma unroll
            for (int m = 1; m < 16; m <<= 1) {
                ps += __shfl_xor(ps, m);
                pd += __shfl_xor(pd, m);
            }
            if (lr == 0) {
                int row = m0 + (wv + si * 4) * 16 + quad * 4 + r;
                alsp[(row * 4 + hsel) * 2 + parity] = ps;
                aldp[(row * 4 + hsel) * 2 + parity] = pd;
            }
        }
    }
}

// ---- inline slot-combine: slots (row*4+h)*2+parity -> row*8 + 2h + p ----
__device__ __forceinline__ void load_al4(const float* __restrict__ alp, int row, bool np2, float out[4]) {
    const float4* ap = (const float4*)(alp + (size_t)row * 8);
    float4 e0 = ap[0], e1 = ap[1];
    out[0] = e0.x; out[1] = e0.z; out[2] = e1.x; out[3] = e1.z;
    if (np2) { out[0] += e0.y; out[1] += e0.w; out[2] += e1.y; out[3] += e1.w; }
}

// ---- FUSED deterministic softmax+agg, layer 1: ONE WAVE per dst (2 dst / block) ----
__global__ __launch_bounds__(128) void fused_agg1(
        const int* __restrict__ rowptr, const int2* __restrict__ cs,
        const float* __restrict__ alsp, const float* __restrict__ aldp,
        const float* __restrict__ sbuf, const __hip_bfloat16* __restrict__ hb,
        __hip_bfloat16* __restrict__ outb, int nparts) {
    __shared__ float lg[2][MAXDEG * 4];
    __shared__ int   ssrc[2][MAXDEG];
    int wv = threadIdx.x >> 6, t = threadIdx.x & 63;
    int d = blockIdx.x * 2 + wv;
    int beg = rowptr[d], n = rowptr[d + 1] - beg;
    bool fit = (n <= MAXDEG);
    bool np2 = (nparts == 2);
    float adh[4];
    load_al4(aldp, d, np2, adh);
    float sb4[4] = {sbuf[0], sbuf[1], sbuf[2], sbuf[3]};
    float mx[4] = {-INFINITY, -INFINITY, -INFINITY, -INFINITY};
    for (int p = t; p < n; p += 64) {
        int2 se = cs[beg + p];
        float eav = __int_as_float(se.y);
        float l[4];
        load_al4(alsp, se.x, np2, l);
#pragma unroll
        for (int hh = 0; hh < 4; ++hh) {
            float v = l[hh] + adh[hh] + eav * sb4[hh];
            v = v > 0.f ? v : 0.2f * v;
            l[hh] = v;
            mx[hh] = fmaxf(mx[hh], v);
        }
        if (fit) {
            *(float4*)&lg[wv][p * 4] = make_float4(l[0], l[1], l[2], l[3]);
            ssrc[wv][p] = se.x;
        }
    }
#pragma unroll
    for (int m = 1; m < 64; m <<= 1)
#pragma unroll
        for (int hh = 0; hh < 4; ++hh)
            mx[hh] = fmaxf(mx[hh], __shfl_xor(mx[hh], m));
    // wave-local LDS producer/consumer: drain this wave's LDS writes only.
    asm volatile("s_waitcnt lgkmcnt(0)" ::: "memory");
    int h = t >> 4;                       // 8 channels/lane, 128 ch/head -> head = t>>4
    float mh = mx[h];
    float a[8] = {};
    float ds = 0.f;
    const __hip_bfloat16* hrow = hb + 8 * t;
#define ACC8(rr, wt) { \
    unsigned q0 = (rr).x, q1 = (rr).y, q2 = (rr).z, q3 = (rr).w; \
    a[0] += (wt) * __uint_as_float(q0 << 16); a[1] += (wt) * __uint_as_float(q0 & 0xFFFF0000u); \
    a[2] += (wt) * __uint_as_float(q1 << 16); a[3] += (wt) * __uint_as_float(q1 & 0xFFFF0000u); \
    a[4] += (wt) * __uint_as_float(q2 << 16); a[5] += (wt) * __uint_as_float(q2 & 0xFFFF0000u); \
    a[6] += (wt) * __uint_as_float(q3 << 16); a[7] += (wt) * __uint_as_float(q3 & 0xFFFF0000u); }
    if (fit) {
        int p = 0;
        for (; p + 8 <= n; p += 8) {
            int s0 = ssrc[wv][p],     s1 = ssrc[wv][p + 1], s2 = ssrc[wv][p + 2], s3 = ssrc[wv][p + 3];
            int s4 = ssrc[wv][p + 4], s5 = ssrc[wv][p + 5], s6 = ssrc[wv][p + 6], s7 = ssrc[wv][p + 7];
            uint4 r0 = *(const uint4*)&hrow[(size_t)s0 * 512];
            uint4 r1 = *(const uint4*)&hrow[(size_t)s1 * 512];
            uint4 r2 = *(const uint4*)&hrow[(size_t)s2 * 512];
            uint4 r3 = *(const uint4*)&hrow[(size_t)s3 * 512];
            uint4 r4 = *(const uint4*)&hrow[(size_t)s4 * 512];
            uint4 r5 = *(const uint4*)&hrow[(size_t)s5 * 512];
            uint4 r6 = *(const uint4*)&hrow[(size_t)s6 * 512];
            uint4 r7 = *(const uint4*)&hrow[(size_t)s7 * 512];
            float w0 = __expf(lg[wv][p * 4 + h] - mh);
            float w1 = __expf(lg[wv][p * 4 + 4 + h] - mh);
            float w2 = __expf(lg[wv][p * 4 + 8 + h] - mh);
            float w3 = __expf(lg[wv][p * 4 + 12 + h] - mh);
            float w4 = __expf(lg[wv][p * 4 + 16 + h] - mh);
            float w5 = __expf(lg[wv][p * 4 + 20 + h] - mh);
            float w6 = __expf(lg[wv][p * 4 + 24 + h] - mh);
            float w7 = __expf(lg[wv][p * 4 + 28 + h] - mh);
            ds += ((w0 + w1) + (w2 + w3)) + ((w4 + w5) + (w6 + w7));
            ACC8(r0, w0); ACC8(r1, w1); ACC8(r2, w2); ACC8(r3, w3);
            ACC8(r4, w4); ACC8(r5, w5); ACC8(r6, w6); ACC8(r7, w7);
        }
        for (; p + 4 <= n; p += 4) {
            int s0 = ssrc[wv][p], s1 = ssrc[wv][p + 1], s2 = ssrc[wv][p + 2], s3 = ssrc[wv][p + 3];
            uint4 r0 = *(const uint4*)&hrow[(size_t)s0 * 512];
            uint4 r1 = *(const uint4*)&hrow[(size_t)s1 * 512];
            uint4 r2 = *(const uint4*)&hrow[(size_t)s2 * 512];
            uint4 r3 = *(const uint4*)&hrow[(size_t)s3 * 512];
            float w0 = __expf(lg[wv][p * 4 + h] - mh);
            float w1 = __expf(lg[wv][p * 4 + 4 + h] - mh);
            float w2 = __expf(lg[wv][p * 4 + 8 + h] - mh);
            float w3 = __expf(lg[wv][p * 4 + 12 + h] - mh);
            ds += (w0 + w1) + (w2 + w3);
            ACC8(r0, w0); ACC8(r1, w1); ACC8(r2, w2); ACC8(r3, w3);
        }
        for (; p < n; ++p) {
            int s0 = ssrc[wv][p];
            uint4 r0 = *(const uint4*)&hrow[(size_t)s0 * 512];
            float w0 = __expf(lg[wv][p * 4 + h] - mh);
            ds += w0;
            ACC8(r0, w0);
        }
    } else {
        for (int p = 0; p < n; ++p) {
            int2 se = cs[beg + p];
            float eav = __int_as_float(se.y);
            float l4[4];
            load_al4(alsp, se.x, np2, l4);
            float l = l4[h] + adh[h] + eav * sb4[h];
            l = l > 0.f ? l : 0.2f * l;
            float w = __expf(l - mh);
            uint4 r0 = *(const uint4*)&hrow[(size_t)se.x * 512];
            ds += w;
            ACC8(r0, w);
        }
    }
#undef ACC8
    float rdn = 1.0f / (ds + 1e-16f);
    __hip_bfloat16 tmp[8];
#pragma unroll
    for (int j = 0; j < 8; ++j) tmp[j] = __float2bfloat16(a[j] * rdn);
    *(uint4*)&outb[(size_t)d * 512 + 8 * t] = *(uint4*)tmp;
}

// ---- FUSED softmax+agg+head-mean, layer 2: ONE WAVE per dst (2 dst / block) ----
__global__ __launch_bounds__(128) void fused_agg2(
        const int* __restrict__ rowptr, const int2* __restrict__ cs,
        const float* __restrict__ alsp, const float* __restrict__ aldp,
        const float* __restrict__ sbuf, const __hip_bfloat16* __restrict__ hb,
        float* __restrict__ out2, int nparts) {
    __shared__ float lg[2][MAXDEG * 4];
    __shared__ int   ssrc[2][MAXDEG];
    int wv = threadIdx.x >> 6, t = threadIdx.x & 63;
    int d = blockIdx.x * 2 + wv;
    int beg = rowptr[d], n = rowptr[d + 1] - beg;
    bool fit = (n <= MAXDEG);
    bool np2 = (nparts == 2);
    float adh[4];
    load_al4(aldp, d, np2, adh);
    float sb4[4] = {sbuf[4], sbuf[5], sbuf[6], sbuf[7]};
    float mx[4] = {-INFINITY, -INFINITY, -INFINITY, -INFINITY};
    for (int p = t; p < n; p += 64) {
        int2 se = cs[beg + p];
        float eav = __int_as_float(se.y);
        float l[4];
        load_al4(alsp, se.x, np2, l);
#pragma unroll
        for (int hh = 0; hh < 4; ++hh) {
            float v = l[hh] + adh[hh] + eav * sb4[hh];
            v = v > 0.f ? v : 0.2f * v;
            l[hh] = v;
            mx[hh] = fmaxf(mx[hh], v);
        }
        if (fit) {
            *(float4*)&lg[wv][p * 4] = make_float4(l[0], l[1], l[2], l[3]);
            ssrc[wv][p] = se.x;
        }
    }
#pragma unroll
    for (int m = 1; m < 64; m <<= 1)
#pragma unroll
        for (int hh = 0; hh < 4; ++hh)
            mx[hh] = fmaxf(mx[hh], __shfl_xor(mx[hh], m));
    asm volatile("s_waitcnt lgkmcnt(0)" ::: "memory");
    int h = t >> 4;                       // 4 channels/lane, 64 ch/head -> head = t>>4
    float mh = mx[h];
    float a4[4] = {};
    float ds = 0.f;
    const __hip_bfloat16* hrow = hb + 4 * t;
#define ACC4(rr, wt) { \
    unsigned q0 = (rr).x, q1 = (rr).y; \
    a4[0] += (wt) * __uint_as_float(q0 << 16); a4[1] += (wt) * __uint_as_float(q0 & 0xFFFF0000u); \
    a4[2] += (wt) * __uint_as_float(q1 << 16); a4[3] += (wt) * __uint_as_float(q1 & 0xFFFF0000u); }
    if (fit) {
        int p = 0;
        for (; p + 8 <= n; p += 8) {
            int s0 = ssrc[wv][p],     s1 = ssrc[wv][p + 1], s2 = ssrc[wv][p + 2], s3 = ssrc[wv][p + 3];
            int s4 = ssrc[wv][p + 4], s5 = ssrc[wv][p + 5], s6 = ssrc[wv][p + 6], s7 = ssrc[wv][p + 7];
            uint2 r0 = *(const uint2*)&hrow[(size_t)s0 * 256];
            uint2 r1 = *(const uint2*)&hrow[(size_t)s1 * 256];
            uint2 r2 = *(const uint2*)&hrow[(size_t)s2 * 256];
            uint2 r3 = *(const uint2*)&hrow[(size_t)s3 * 256];
            uint2 r4 = *(const uint2*)&hrow[(size_t)s4 * 256];
            uint2 r5 = *(const uint2*)&hrow[(size_t)s5 * 256];
            uint2 r6 = *(const uint2*)&hrow[(size_t)s6 * 256];
            uint2 r7 = *(const uint2*)&hrow[(size_t)s7 * 256];
            float w0 = __expf(lg[wv][p * 4 + h] - mh);
            float w1 = __expf(lg[wv][p * 4 + 4 + h] - mh);
            float w2 = __expf(lg[wv][p * 4 + 8 + h] - mh);
            float w3 = __expf(lg[wv][p * 4 + 12 + h] - mh);
            float w4 = __expf(lg[wv][p * 4 + 16 + h] - mh);
            float w5 = __expf(lg[wv][p * 4 + 20 + h] - mh);
            float w6 = __expf(lg[wv][p * 4 + 24 + h] - mh);
            float w7 = __expf(lg[wv][p * 4 + 28 + h] - mh);
            ds += ((w0 + w1) + (w2 + w3)) + ((w4 + w5) + (w6 + w7));
            ACC4(r0, w0); ACC4(r1, w1); ACC4(r2, w2); ACC4(r3, w3);
            ACC4(r4, w4); ACC4(r5, w5); ACC4(r6, w6); ACC4(r7, w7);
        }
        for (; p + 4 <= n; p += 4) {
            int s0 = ssrc[wv][p], s1 = ssrc[wv][p + 1], s2 = ssrc[wv][p + 2], s3 = ssrc[wv][p + 3];
            uint2 r0 = *(const uint2*)&hrow[(size_t)s0 * 256];
            uint2 r1 = *(const uint2*)&hrow[(size_t)s1 * 256];
            uint2 r2 = *(const uint2*)&hrow[(size_t)s2 * 256];
            uint2 r3 = *(const uint2*)&hrow[(size_t)s3 * 256];
            float w0 = __expf(lg[wv][p * 4 + h] - mh);
            float w1 = __expf(lg[wv][p * 4 + 4 + h] - mh);
            float w2 = __expf(lg[wv][p * 4 + 8 + h] - mh);
            float w3 = __expf(lg[wv][p * 4 + 12 + h] - mh);
            ds += (w0 + w1) + (w2 + w3);
            ACC4(r0, w0); ACC4(r1, w1); ACC4(r2, w2); ACC4(r3, w3);
        }
        for (; p < n; ++p) {
            int s0 = ssrc[wv][p];
            uint2 r0 = *(const uint2*)&hrow[(size_t)s0 * 256];
            float w0 = __expf(lg[wv][p * 4 + h] - mh);
            ds += w0;
            ACC4(r0, w0);
        }
    } else {
        for (int p = 0; p < n; ++p) {
            int2 se = cs[beg + p];
            float eav = __int_as_float(se.y);
            float l4[4];
            load_al4(alsp, se.x, np2, l4);
            float l = l4[h] + adh[h] + eav * sb4[h];
            l = l > 0.f ? l : 0.2f * l;
            float w = __expf(l - mh);
            uint2 r0 = *(const uint2*)&hrow[(size_t)se.x * 256];
            ds += w;
            ACC4(r0, w);
        }
    }
#undef ACC4
    float rdn = 1.0f / (ds + 1e-16f);
#pragma unroll
    for (int j = 0; j < 4; ++j) {
        float v = a4[j] * rdn;
        v += __shfl_xor(v, 16);
        v += __shfl_xor(v, 32);
        a4[j] = v * 0.25f;
    }
    if (t < 16)
        *(float4*)&out2[(size_t)d * 64 + 4 * t] = make_float4(a4[0], a4[1], a4[2], a4[3]);
}

// ---- BN1 stats: per-block partials ----
__global__ __launch_bounds__(256) void bn_part_b(const __hip_bfloat16* __restrict__ x,
                                                 float* __restrict__ pmu, float* __restrict__ pm2) {
    int t = threadIdx.x, b = blockIdx.x;
    float s0 = 0.f, s20 = 0.f, s1 = 0.f, s21 = 0.f;
    for (int i = b; i < N_NODES; i += gridDim.x) {
        unsigned u = *(const unsigned*)&x[(size_t)i * 512 + 2 * t];
        float v0 = __uint_as_float(u << 16);
        float v1 = __uint_as_float(u & 0xFFFF0000u);
        s0 += v0; s20 += v0 * v0; s1 += v1; s21 += v1 * v1;
    }
    pmu[b * 512 + 2 * t] = s0;     pm2[b * 512 + 2 * t] = s20;
    pmu[b * 512 + 2 * t + 1] = s1; pm2[b * 512 + 2 * t + 1] = s21;
}

// ---- reduce partials -> affine a,b : parallel (4 splits/channel, fixed-order combine) ----
__global__ __launch_bounds__(256) void bn_reduce_affine(const float* __restrict__ pmu, const float* __restrict__ pm2,
                                 const float* __restrict__ smalls, int s_g, int s_be,
                                 float* __restrict__ a, float* __restrict__ b, int nch) {
    __shared__ float shs[4][64], sh2[4][64];
    int t = threadIdx.x;
    int cl = t & 63, j = t >> 6;
    int c = blockIdx.x * 64 + cl;
    float s = 0.f, s2 = 0.f;
    for (int bk = j * 64; bk < (j + 1) * 64; ++bk) { s += pmu[bk * nch + c]; s2 += pm2[bk * nch + c]; }
    shs[j][cl] = s; sh2[j][cl] = s2;
    __syncthreads();
    if (j == 0) {
        float st  = ((shs[0][cl] + shs[1][cl]) + (shs[2][cl] + shs[3][cl]));
        float st2 = ((sh2[0][cl] + sh2[1][cl]) + (sh2[2][cl] + sh2[3][cl]));
        float m = st * (1.0f / N_NODES);
        float var = st2 * (1.0f / N_NODES) - m * m;
        float aa = smalls[s_g + c] * rsqrtf(var + 1e-5f);
        a[c] = aa;
        b[c] = smalls[s_be + c] - m * aa;
    }
}

// ---- BN2 stats: per-block partials ----
__global__ __launch_bounds__(256) void bn2_stats(const float* __restrict__ x,
                                                 float* __restrict__ pmu, float* __restrict__ pm2) {
    int t = threadIdx.x;
    int c = t & 63, j = t >> 6;
    float ls = 0.f, ls2 = 0.f;
    for (int nd = blockIdx.x * 4 + j; nd < N_NODES; nd += gridDim.x * 4) {
        float v = x[(size_t)nd * 64 + c];
        ls += v; ls2 += v * v;
    }
    __shared__ float shs[4][64], sh2[4][64];
    shs[j][c] = ls; sh2[j][c] = ls2;
    __syncthreads();
    if (j == 0) {
        pmu[blockIdx.x * 64 + c] = shs[0][c] + shs[1][c] + shs[2][c] + shs[3][c];
        pm2[blockIdx.x * 64 + c] = sh2[0][c] + sh2[1][c] + sh2[2][c] + sh2[3][c];
    }
}

// ---- pool stage 1: 8 chunks per graph, BN2 affine+ELU fused, partial sums ----
__global__ __launch_bounds__(256) void pool_part(const float* __restrict__ x, const int* __restrict__ gstart,
                                                 const float* __restrict__ a2, const float* __restrict__ b2,
                                                 float* __restrict__ pp) {
    int g = blockIdx.x >> 3, ck = blockIdx.x & 7;
    int t = threadIdx.x;
    int c = t & 63, j = t >> 6;
    int beg = gstart[g], end = gstart[g + 1], n = end - beg;
    int cb = beg + (n * ck) / 8, ce = beg + (n * (ck + 1)) / 8;
    float ac = a2[c], bc = b2[c];
    float s = 0.f;
    for (int i = cb + j; i < ce; i += 4) {
        float y = ac * x[(size_t)i * 64 + c] + bc;
        s += (y > 0.f ? y : expm1f(y));
    }
    __shared__ float sh[4][64];
    sh[j][c] = s;
    __syncthreads();
    if (j == 0)
        pp[blockIdx.x * 64 + c] = sh[0][c] + sh[1][c] + sh[2][c] + sh[3][c];
}

// ---- pool stage 2: reduce 8 chunks (fixed order) + MLP ----
__global__ __launch_bounds__(64) void pool_mlp_fin(const float* __restrict__ pp, const int* __restrict__ gstart,
                                                   const float* __restrict__ smalls, const int* __restrict__ flag,
                                                   void* __restrict__ outp) {
    int g = blockIdx.x, t = threadIdx.x;
    __shared__ float pooled[64];
    __shared__ float hsh[32];
    float s = 0.f;
    for (int k = 0; k < 8; ++k) s += pp[(g * 8 + k) * 64 + t];
    int n = gstart[g + 1] - gstart[g];
    pooled[t] = s / fmaxf((float)n, 1.0f);
    __syncthreads();
    if (t < 32) {
        float acc = smalls[S_FB1 + t];
        for (int cc = 0; cc < 64; ++cc)
            acc += pooled[cc] * smalls[S_FW1 + cc * 32 + t];
        hsh[t] = acc > 0.f ? acc : expm1f(acc);
    }
    __syncthreads();
    if (t == 0) {
        float o = smalls[S_FB2];
        for (int k = 0; k < 32; ++k) o += hsh[k] * smalls[S_FW2 + k];
        if (flag[0]) ((float*)outp)[g] = o;
        else ((__hip_bfloat16*)outp)[g] = __float2bfloat16(o);
    }
}

extern "C" void kernel_launch(void* const* d_in, const int* in_sizes, int n_in,
                              void* d_out, int out_size, void* d_ws, size_t ws_size,
                              hipStream_t stream) {
    const void* x    = d_in[0];
    const int* ei    = (const int*)d_in[1];
    const int* batch = (const int*)d_in[2];
    const void* ea   = d_in[3];
    const void* W1   = d_in[4];
    const void* as1  = d_in[5];
    const void* ad1  = d_in[6];
    const void* We1  = d_in[7];
    const void* ae1  = d_in[8];
    const void* g1   = d_in[10];
    const void* be1  = d_in[11];
    const void* W2   = d_in[12];
    const void* as2  = d_in[13];
    const void* ad2  = d_in[14];
    const void* We2  = d_in[15];
    const void* ae2  = d_in[16];
    const void* g2   = d_in[18];
    const void* be2  = d_in[19];
    const void* fw1  = d_in[20];
    const void* fb1  = d_in[21];
    const void* fw2  = d_in[22];
    const void* fb2  = d_in[23];

    char* ws = (char*)d_ws;
    __hip_bfloat16* xb   = (__hip_bfloat16*)(ws + XB_OFF);
    __hip_bfloat16* hb1  = (__hip_bfloat16*)(ws + HB1_OFF);
    __hip_bfloat16* agg1 = (__hip_bfloat16*)(ws + AGG1_OFF);
    __hip_bfloat16* hb2  = (__hip_bfloat16*)(ws + HB2_OFF);
    float* out2   = (float*)(ws + OUT2_OFF);
    float* eaf    = (float*)(ws + EAF_OFF);
    __hip_bfloat16* W1bt = (__hip_bfloat16*)(ws + W1BT_OFF);
    __hip_bfloat16* W2bt = (__hip_bfloat16*)(ws + W2BT_OFF);
    int2*  csr_se = (int2*)(ws + CSR_OFF);
    int*   rowptr = (int*)(ws + ROWPTR_OFF);
    int*   gstart = (int*)(ws + GSTART_OFF);
    float* smalls = (float*)(ws + SMALL_OFF);
    float* sbuf   = (float*)(ws + SBUF_OFF);
    float* eap    = (float*)(ws + EAP_OFF);
    float* alsp   = (float*)(ws + ALSP_OFF);
    float* aldp   = (float*)(ws + ALDP_OFF);
    float* pmu1   = (float*)(ws + PMU1_OFF);
    float* pm21   = (float*)(ws + PM21_OFF);
    float* pmu2   = (float*)(ws + PMU2_OFF);
    float* pm22   = (float*)(ws + PM22_OFF);
    float* a1     = (float*)(ws + A1_OFF);
    float* b1     = (float*)(ws + B1_OFF);
    float* a2     = (float*)(ws + A2_OFF);
    float* b2     = (float*)(ws + B2_OFF);
    float* ea_acc = (float*)(ws + EAACC_OFF);
    float* pp     = (float*)(ws + PP_OFF);
    int*   deg    = (int*)(ws + DEG_OFF);
    int*   cursor = (int*)(ws + CURS_OFF);
    int*   flag   = (int*)(ws + FLAGZ_OFF);

    hipMemsetAsync(ws + ZERO0_START, 0, ZERO0_SIZE, stream);

    detect_hist<<<DH_DETECT + HIST_BLOCKS + 79, 256, 0, stream>>>(
        (const unsigned short*)x, flag, ei, deg, batch, gstart);
    prep<<<PREP_BLOCKS, 256, 0, stream>>>(flag, x, ea, W1, W2,
                                          as1, ad1, We1, ae1, g1, be1, as2, ad2,
                                          We2, ae2, g2, be2, fw1, fb1, fw2, fb2,
                                          xb, eaf, eap, W1bt, W2bt, smalls, sbuf);

    deg_scan<<<1, 1024, 0, stream>>>(deg, rowptr, eap, ea_acc);
    edge_scatter<<<HIST_BLOCKS, 256, 0, stream>>>(ei, rowptr, cursor, csr_se);
    csr_sort_fill<<<N_NODES, 64, 0, stream>>>(rowptr, csr_se, eaf, ea_acc);

    // ---------- layer 1 ----------
    gemm_mfma_al<<<dim3(512 / 64, MPAD / 128), 256, 0, stream>>>(
        (const short*)xb, (const short*)W1bt, hb1, 512, 256,
        alsp, aldp, smalls + S_AS1, smalls + S_AD1, 7, nullptr, nullptr);
    fused_agg1<<<N_NODES / 2, 128, 0, stream>>>(rowptr, csr_se, alsp, aldp, sbuf, hb1, agg1, 2);
    bn_part_b<<<256, 256, 0, stream>>>(agg1, pmu1, pm21);
    bn_reduce_affine<<<8, 256, 0, stream>>>(pmu1, pm21, smalls, S_G1, S_BE1, a1, b1, 512);

    // ---------- layer 2 (BN1+ELU folded into A-staging) ----------
    gemm_mfma_al<<<dim3(256 / 64, MPAD / 128), 256, 0, stream>>>(
        (const short*)agg1, (const short*)W2bt, hb2, 256, 512,
        alsp, aldp, smalls + S_AS2, smalls + S_AD2, 6, a1, b1);
    fused_agg2<<<N_NODES / 2, 128, 0, stream>>>(rowptr, csr_se, alsp, aldp, sbuf, hb2, out2, 1);
    bn2_stats<<<256, 256, 0, stream>>>(out2, pmu2, pm22);
    bn_reduce_affine<<<1, 256, 0, stream>>>(pmu2, pm22, smalls, S_G2, S_BE2, a2, b2, 64);

    // ---------- BN2+ELU+pool (2-stage) + MLP ----------
    pool_part<<<N_GRAPHS * 8, 256, 0, stream>>>(out2, gstart, a2, b2, pp);
    pool_mlp_fin<<<N_GRAPHS, 64, 0, stream>>>(pp, gstart, smalls, flag, d_out);
}

// Round 9
// 417.540 us; speedup vs baseline: 1.1436x; 1.0017x over previous
//
#include <hip/hip_runtime.h>
#include <hip/hip_bf16.h>

#define N_NODES  20000
#define MPAD     20096
#define N_EDGES  320000
#define N_EP     (N_EDGES + N_NODES)
#define D_IN     256
#define N_GRAPHS 32
#define HH1 4
#define CC1 128
#define HH2 4
#define CC2 64
#define MAXDEG   128

// ---- workspace layout (bytes) ----
#define XB_OFF      0ull                    // 10,289,152 : x bf16 [MPAD,256]
#define HB1_OFF     10289152ull             // 20,578,304 : h1 bf16 [MPAD,512]
#define AGG1_OFF    30867456ull             // 20,578,304 : agg1 bf16 [MPAD,512] (raw, pre-BN)
#define HB2_OFF     51445760ull             // 10,289,152 : h2 bf16 [MPAD,256]
#define OUT2_OFF    61734912ull             //  5,120,000 : head-mean fp32 [20000,64] (pre-BN)
#define EAF_OFF     66854912ull             //  1,280,000
#define W1BT_OFF    68134912ull             //    262,144
#define W2BT_OFF    68397056ull             //    262,144
#define CSR_OFF     68659200ull             //  2,720,000 (int2: s, edge-id)
#define ROWPTR_OFF  71379200ull             //     80,064
#define GSTART_OFF  71459264ull             //        256
#define SMALL_OFF   71459520ull             //     25,600
#define SBUF_OFF    71485120ull             //         64
#define EAP_OFF     71485184ull             //      1,280
#define ALSP_OFF    71486464ull             //    643,072 : al partials [MPAD*4][2]
#define ALDP_OFF    72129536ull             //    643,072
#define PMU1_OFF    72772608ull             //    524,288
#define PM21_OFF    73296896ull             //    524,288
#define PMU2_OFF    73821184ull             //     65,536
#define PM22_OFF    73886720ull             //     65,536
#define A1_OFF      73952256ull             //      2,048
#define B1_OFF      73954304ull             //      2,048
#define A2_OFF      73956352ull             //        256
#define B2_OFF      73956608ull             //        256
#define EAACC_OFF   73956864ull             //         64
// ---- zeroed-at-start region ----
#define DEG_OFF     74600000ull             //     80,000
#define CURS_OFF    74680000ull             //     80,000
#define FLAGZ_OFF   74760000ull             //        128
#define ZERO0_START DEG_OFF
#define ZERO0_SIZE  160128ull
#define PP_OFF      74760128ull             //     65,536 : pool partials [256][64]

// small-region float offsets
#define S_AS1 0
#define S_AD1 512
#define S_WE1 1024
#define S_AE1 1536
#define S_G1  2048
#define S_BE1 2560
#define S_AS2 3072
#define S_AD2 3328
#define S_WE2 3584
#define S_AE2 3840
#define S_G2  4096
#define S_BE2 4160
#define S_FW1 4224
#define S_FB1 6272
#define S_FW2 6304
#define S_FB2 6336

typedef __attribute__((ext_vector_type(8))) short bf8_t;
typedef __attribute__((ext_vector_type(4))) float f4_t;

__device__ __forceinline__ float loadF(const void* p, int i, int fp32) {
    return fp32 ? ((const float*)p)[i]
                : __bfloat162float(((const __hip_bfloat16*)p)[i]);
}

// ---- fused dtype-detect + degree-hist + graph bounds ----
#define DH_DETECT 256
#define HIST_BLOCKS 1329
__global__ void detect_hist(const unsigned short* __restrict__ xr, int* __restrict__ flag,
                            const int* __restrict__ ei, int* __restrict__ deg,
                            const int* __restrict__ batch, int* __restrict__ gstart) {
    int b = blockIdx.x, t = threadIdx.x;
    if (b < DH_DETECT) {
        int i = b * 256 + t;
        unsigned short u = xr[i];
        if ((u & 0x7F80) == 0x7F80) atomicOr(flag, 1);
        return;
    }
    b -= DH_DETECT;
    if (b < HIST_BLOCKS) {
        int e = b * 256 + t;
        if (e >= N_EP) return;
        int d = (e < N_EDGES) ? ei[N_EDGES + e] : e - N_EDGES;
        atomicAdd(&deg[d], 1);
        return;
    }
    int i = (b - HIST_BLOCKS) * 256 + t;
    if (i >= N_NODES) return;
    int bb = batch[i];
    if (i == 0) {
        for (int g = 0; g <= bb; ++g) gstart[g] = 0;
    } else {
        int pb = batch[i - 1];
        for (int g = pb + 1; g <= bb; ++g) gstart[g] = i;
    }
    if (i == N_NODES - 1) {
        for (int g = bb + 1; g <= N_GRAPHS; ++g) gstart[g] = N_NODES;
    }
}

// ---- fused prep ----
#define PB_XB  5024
#define PB_EAF 313
#define PB_W   512
#define PB_SM  16
#define PREP_BLOCKS (PB_XB + PB_EAF + 2 * PB_W + PB_SM + 1)
__global__ __launch_bounds__(256) void prep(
        const int* __restrict__ flag,
        const void* x, const void* ea, const void* W1, const void* W2,
        const void* as1, const void* ad1, const void* We1, const void* ae1,
        const void* g1, const void* be1, const void* as2, const void* ad2,
        const void* We2, const void* ae2, const void* g2, const void* be2,
        const void* fw1, const void* fb1, const void* fw2, const void* fb2,
        __hip_bfloat16* __restrict__ xb, float* __restrict__ eaf, float* __restrict__ eap,
        __hip_bfloat16* __restrict__ W1bt, __hip_bfloat16* __restrict__ W2bt,
        float* __restrict__ smalls, float* __restrict__ sbuf) {
    __shared__ float shw[4];
    int b = blockIdx.x, t = threadIdx.x;
    int fp32 = flag[0];
    if (b < PB_XB) {
        int base = (b * 256 + t) * 4;
        __hip_bfloat16 tmp[4];
#pragma unroll
        for (int j = 0; j < 4; ++j) {
            int i = base + j;
            float v = (i < N_NODES * D_IN) ? loadF(x, i, fp32) : 0.f;
            tmp[j] = __float2bfloat16(v);
        }
        *(uint2*)&xb[base] = *(uint2*)tmp;
        return;
    }
    b -= PB_XB;
    if (b < PB_EAF) {
        int base = (b * 256 + t) * 4;
        float s = 0.f;
#pragma unroll
        for (int j = 0; j < 4; ++j) {
            int i = base + j;
            if (i < N_EDGES) { float v = loadF(ea, i, fp32); eaf[i] = v; s += v; }
        }
#pragma unroll
        for (int m = 1; m < 64; m <<= 1) s += __shfl_xor(s, m);
        if ((t & 63) == 0) shw[t >> 6] = s;
        __syncthreads();
        if (t == 0) eap[b] = shw[0] + shw[1] + shw[2] + shw[3];
        return;
    }
    b -= PB_EAF;
    if (b < PB_W) {
        int i = b * 256 + t;
        int k = i >> 9, n = i & 511;
        W1bt[(size_t)n * 256 + k] = __float2bfloat16(loadF(W1, i, fp32));
        return;
    }
    b -= PB_W;
    if (b < PB_W) {
        int i = b * 256 + t;
        int k = i >> 8, n = i & 255;
        W2bt[(size_t)n * 512 + k] = __float2bfloat16(loadF(W2, i, fp32));
        return;
    }
    b -= PB_W;
    if (b < PB_SM) {
        const void* srcs[16] = {as1, ad1, We1, ae1, g1, be1, as2, ad2, We2, ae2, g2, be2, fw1, fb1, fw2, fb2};
        const int cnts[16] = {512, 512, 512, 512, 512, 512, 256, 256, 256, 256, 64, 64, 2048, 32, 32, 1};
        const int offs[16] = {S_AS1, S_AD1, S_WE1, S_AE1, S_G1, S_BE1, S_AS2, S_AD2,
                              S_WE2, S_AE2, S_G2, S_BE2, S_FW1, S_FB1, S_FW2, S_FB2};
        for (int i = t; i < cnts[b]; i += 256)
            smalls[offs[b] + i] = loadF(srcs[b], i, fp32);
        return;
    }
    if (t < 4) {
        float s = 0.f;
        for (int c = 0; c < CC1; ++c) s += loadF(We1, t * CC1 + c, fp32) * loadF(ae1, t * CC1 + c, fp32);
        sbuf[t] = s;
    } else if (t < 8) {
        int h = t - 4;
        float s = 0.f;
        for (int c = 0; c < CC2; ++c) s += loadF(We2, h * CC2 + c, fp32) * loadF(ae2, h * CC2 + c, fp32);
        sbuf[4 + h] = s;
    }
}

__global__ __launch_bounds__(1024) void deg_scan(const int* __restrict__ deg, int* __restrict__ rowptr,
                                                 const float* __restrict__ eap, float* __restrict__ ea_acc) {
    __shared__ int part[1024];
    __shared__ float fsh[512];
    int t = threadIdx.x;
    int lo = t * 20;
    int hi = lo + 20; if (hi > N_NODES) hi = N_NODES; if (lo > N_NODES) lo = N_NODES;
    int s = 0;
    for (int i = lo; i < hi; ++i) s += deg[i];
    part[t] = s;
    __syncthreads();
    for (int off = 1; off < 1024; off <<= 1) {
        int u = (t >= off) ? part[t - off] : 0;
        __syncthreads();
        if (t >= off) part[t] += u;
        __syncthreads();
    }
    int run = part[t] - s;
    for (int i = lo; i < hi; ++i) { rowptr[i] = run; run += deg[i]; }
    if (hi == N_NODES && lo < N_NODES) rowptr[N_NODES] = run;
    if (t < 512) fsh[t] = (t < PB_EAF) ? eap[t] : 0.f;
    __syncthreads();
    for (int st = 256; st; st >>= 1) {
        if (t < st) fsh[t] += fsh[t + st];
        __syncthreads();
    }
    if (t == 0) ea_acc[0] = fsh[0];
}

// ---- BN1-affine + ELU + bf16 repack for 8 contiguous channels (bit-identical math) ----
__device__ __forceinline__ uint4 bn_elu_pack(uint4 v, const float* __restrict__ a8,
                                             const float* __restrict__ b8) {
    unsigned q[4] = {v.x, v.y, v.z, v.w};
    float4 a0 = *(const float4*)a8, a1 = *(const float4*)(a8 + 4);
    float4 b0 = *(const float4*)b8, b1 = *(const float4*)(b8 + 4);
    float av[8] = {a0.x, a0.y, a0.z, a0.w, a1.x, a1.y, a1.z, a1.w};
    float bv[8] = {b0.x, b0.y, b0.z, b0.w, b1.x, b1.y, b1.z, b1.w};
    __hip_bfloat16 t[8];
#pragma unroll
    for (int k = 0; k < 8; ++k) {
        unsigned u = (k & 1) ? (q[k >> 1] & 0xFFFF0000u) : (q[k >> 1] << 16);
        float y = av[k] * __uint_as_float(u) + bv[k];
        y = y > 0.f ? y : expm1f(y);
        t[k] = __float2bfloat16(y);
    }
    return *(uint4*)t;
}

// ---- MFMA bf16 GEMM body + al epilogue via deterministic partial slots ----
__device__ __forceinline__ void gemm_body(
        const short* __restrict__ A, const short* __restrict__ Bt,
        __hip_bfloat16* __restrict__ Cb, int N, int K,
        float* __restrict__ alsp, float* __restrict__ aldp,
        const float* __restrict__ asv, const float* __restrict__ adv, int cshift,
        const float* __restrict__ bna, const float* __restrict__ bnb,
        int bx, int by) {
    __shared__ short As[128 * 40];
    __shared__ short Bs[64 * 40];
    int t = threadIdx.x;
    int wv = t >> 6, lane = t & 63, quad = lane >> 4, lr = lane & 15;
    int m0 = by * 128, n0 = bx * 64;
    f4_t acc[2][4] = {};
    int ra0 = t >> 2, sa0 = t & 3;
    int ra1 = (t + 256) >> 2;
    for (int k0 = 0; k0 < K; k0 += 32) {
        uint4 va0 = *(const uint4*)&A[(size_t)(m0 + ra0) * K + k0 + sa0 * 8];
        uint4 va1 = *(const uint4*)&A[(size_t)(m0 + ra1) * K + k0 + sa0 * 8];
        uint4 vb  = *(const uint4*)&Bt[(size_t)(n0 + ra0) * K + k0 + sa0 * 8];
        if (bna) {
            int j = k0 + sa0 * 8;
            va0 = bn_elu_pack(va0, bna + j, bnb + j);
            va1 = bn_elu_pack(va1, bna + j, bnb + j);
        }
        *(uint4*)&As[ra0 * 40 + sa0 * 8] = va0;
        *(uint4*)&As[ra1 * 40 + sa0 * 8] = va1;
        *(uint4*)&Bs[ra0 * 40 + sa0 * 8] = vb;
        __syncthreads();
        bf8_t a0 = *(const bf8_t*)&As[(wv * 16 + lr) * 40 + quad * 8];
        bf8_t a1 = *(const bf8_t*)&As[((wv + 4) * 16 + lr) * 40 + quad * 8];
#pragma unroll
        for (int nt = 0; nt < 4; ++nt) {
            bf8_t b = *(const bf8_t*)&Bs[(nt * 16 + lr) * 40 + quad * 8];
            acc[0][nt] = __builtin_amdgcn_mfma_f32_16x16x32_bf16(a0, b, acc[0][nt], 0, 0, 0);
            acc[1][nt] = __builtin_amdgcn_mfma_f32_16x16x32_bf16(a1, b, acc[1][nt], 0, 0, 0);
        }
        __syncthreads();
    }
#pragma unroll
    for (int si = 0; si < 2; ++si) {
        int mrow = m0 + (wv + si * 4) * 16 + quad * 4;
#pragma unroll
        for (int nt = 0; nt < 4; ++nt) {
            int col = n0 + nt * 16 + lr;
#pragma unroll
            for (int r = 0; r < 4; ++r)
                Cb[(size_t)(mrow + r) * N + col] = __float2bfloat16(acc[si][nt][r]);
        }
    }
    float asv4[4], adv4[4];
#pragma unroll
    for (int nt = 0; nt < 4; ++nt) {
        asv4[nt] = asv[n0 + nt * 16 + lr];
        adv4[nt] = adv[n0 + nt * 16 + lr];
    }
    int hsel = n0 >> cshift;
    int parity = (n0 >> 6) & ((1 << (cshift - 6)) - 1);
#pragma unroll
    for (int si = 0; si < 2; ++si) {
#pragma unroll
        for (int r = 0; r < 4; ++r) {
            float ps = 0.f, pd = 0.f;
#pragma unroll
            for (int nt = 0; nt < 4; ++nt) {
                ps += acc[si][nt][r] * asv4[nt];
                pd += acc[si][nt][r] * adv4[nt];
            }
#pragma unroll
            for (int m = 1; m < 16; m <<= 1) {
                ps += __shfl_xor(ps, m);
                pd += __shfl_xor(pd, m);
            }
            if (lr == 0) {
                int row = m0 + (wv + si * 4) * 16 + quad * 4 + r;
                alsp[(row * 4 + hsel) * 2 + parity] = ps;
                aldp[(row * 4 + hsel) * 2 + parity] = pd;
            }
        }
    }
}

// ---- layer-1 GEMM merged with edge_scatter (independent work, overlapped) ----
#define G1_BLOCKS 1256          // (512/64) x (MPAD/128) = 8 x 157
__global__ __launch_bounds__(256) void gemm1_scatter(
        const short* __restrict__ A, const short* __restrict__ Bt,
        __hip_bfloat16* __restrict__ Cb,
        float* __restrict__ alsp, float* __restrict__ aldp,
        const float* __restrict__ asv, const float* __restrict__ adv,
        const int* __restrict__ ei, const int* __restrict__ rowptr,
        int* __restrict__ cursor, int2* __restrict__ csr_se) {
    int blk = blockIdx.x;
    if (blk >= G1_BLOCKS) {
        int e = (blk - G1_BLOCKS) * 256 + threadIdx.x;
        if (e >= N_EP) return;
        int s, dd;
        if (e < N_EDGES) { s = ei[e]; dd = ei[N_EDGES + e]; }
        else { s = dd = e - N_EDGES; }
        int pos = rowptr[dd] + atomicAdd(&cursor[dd], 1);
        csr_se[pos] = make_int2(s, e);
        return;
    }
    gemm_body(A, Bt, Cb, 512, 256, alsp, aldp, asv, adv, 7, nullptr, nullptr,
              blk & 7, blk >> 3);
}

// ---- layer-2 GEMM (BN1+ELU folded on A operand) ----
__global__ __launch_bounds__(256) void gemm_mfma_al(
        const short* __restrict__ A, const short* __restrict__ Bt,
        __hip_bfloat16* __restrict__ Cb, int N, int K,
        float* __restrict__ alsp, float* __restrict__ aldp,
        const float* __restrict__ asv, const float* __restrict__ adv, int cshift,
        const float* __restrict__ bna, const float* __restrict__ bnb) {
    gemm_body(A, Bt, Cb, N, K, alsp, aldp, asv, adv, cshift, bna, bnb,
              blockIdx.x, blockIdx.y);
}

// ---- inline slot-combine: slots (row*4+h)*2+parity ----
__device__ __forceinline__ void load_al4(const float* __restrict__ alp, int row, bool np2, float out[4]) {
    const float4* ap = (const float4*)(alp + (size_t)row * 8);
    float4 e0 = ap[0], e1 = ap[1];
    out[0] = e0.x; out[1] = e0.z; out[2] = e1.x; out[3] = e1.z;
    if (np2) { out[0] += e0.y; out[1] += e0.w; out[2] += e1.y; out[3] += e1.w; }
}

// ---- in-wave canonical sort of one CSR row (by edge id; unique keys => deterministic) ----
// n<=64: register odd-even via shfl, n rounds, result -> sbl[0..n)
// 64<n<=128: LDS odd-even in sbl (wave-local lgkmcnt drains)
// returns false for n>128 (caller uses lane-0 global insertion sort)
__device__ __forceinline__ bool wave_sort_row(int2* __restrict__ cs, int beg, int n, int t,
                                              int2* __restrict__ sbl) {
    if (n <= 64) {
        int key = 0x7FFFFFFF, val = 0;
        if (t < n) { int2 se = cs[beg + t]; key = se.y; val = se.x; }
        for (int r = 0; r < n; ++r) {
            bool up = ((t & 1) == (r & 1));
            int partner = up ? t + 1 : t - 1;
            bool valid = (partner >= 0) && (partner < 64);
            int pidx = valid ? partner : t;
            int pk = __shfl(key, pidx);
            int pv = __shfl(val, pidx);
            if (valid && (up ? (pk < key) : (pk > key))) { key = pk; val = pv; }
        }
        if (t < n) sbl[t] = make_int2(val, key);
        asm volatile("s_waitcnt lgkmcnt(0)" ::: "memory");
        return true;
    }
    if (n <= 128) {
        for (int i = t; i < n; i += 64) sbl[i] = cs[beg + i];
        asm volatile("s_waitcnt lgkmcnt(0)" ::: "memory");
        for (int r = 0; r < n; ++r) {
            int i = 2 * t + (r & 1);
            if (i + 1 < n) {
                int2 a = sbl[i], b = sbl[i + 1];
                if (a.y > b.y) { sbl[i] = b; sbl[i + 1] = a; }
            }
            asm volatile("s_waitcnt lgkmcnt(0)" ::: "memory");
        }
        return true;
    }
    // n > 128: lane-0 insertion sort of the global row, then drain
    if (t == 0) {
        for (int i = beg + 1; i < beg + n; ++i) {
            int2 key2 = cs[i]; int j = i - 1;
            while (j >= beg && cs[j].y > key2.y) { cs[j + 1] = cs[j]; --j; }
            cs[j + 1] = key2;
        }
    }
    asm volatile("s_waitcnt vmcnt(0)" ::: "memory");
    return false;
}

// ---- FUSED sort+softmax+agg, layer 1: ONE WAVE per dst (2 dst / block) ----
__global__ __launch_bounds__(128) void fused_agg1(
        const int* __restrict__ rowptr, int2* __restrict__ cs,
        const float* __restrict__ alsp, const float* __restrict__ aldp,
        const float* __restrict__ sbuf, const float* __restrict__ eaf,
        const float* __restrict__ ea_acc, const __hip_bfloat16* __restrict__ hb,
        __hip_bfloat16* __restrict__ outb, int nparts) {
    __shared__ float lg[2][MAXDEG * 4];
    __shared__ int   ssrc[2][MAXDEG];
    __shared__ int2  sbl[2][MAXDEG];
    int wv = threadIdx.x >> 6, t = threadIdx.x & 63;
    int d = blockIdx.x * 2 + wv;
    int beg = rowptr[d], n = rowptr[d + 1] - beg;
    bool fit = (n <= MAXDEG);
    bool np2 = (nparts == 2);
    float ea_mean = ea_acc[0] * (1.0f / N_EDGES);
    float adh[4];
    load_al4(aldp, d, np2, adh);
    float sb4[4] = {sbuf[0], sbuf[1], sbuf[2], sbuf[3]};
    float mx[4] = {-INFINITY, -INFINITY, -INFINITY, -INFINITY};
    wave_sort_row(cs, beg, n, t, sbl[wv]);
    if (fit) {
        for (int p = t; p < n; p += 64) {
            int2 se = sbl[wv][p];
            float eav = (se.y < N_EDGES) ? eaf[se.y] : ea_mean;
            float l[4];
            load_al4(alsp, se.x, np2, l);
#pragma unroll
            for (int hh = 0; hh < 4; ++hh) {
                float v = l[hh] + adh[hh] + eav * sb4[hh];
                v = v > 0.f ? v : 0.2f * v;
                l[hh] = v;
                mx[hh] = fmaxf(mx[hh], v);
            }
            *(float4*)&lg[wv][p * 4] = make_float4(l[0], l[1], l[2], l[3]);
            ssrc[wv][p] = se.x;
        }
    } else {
        for (int p = t; p < n; p += 64) {
            int2 se = cs[beg + p];
            float eav = (se.y < N_EDGES) ? eaf[se.y] : ea_mean;
            float l[4];
            load_al4(alsp, se.x, np2, l);
#pragma unroll
            for (int hh = 0; hh < 4; ++hh) {
                float v = l[hh] + adh[hh] + eav * sb4[hh];
                v = v > 0.f ? v : 0.2f * v;
                mx[hh] = fmaxf(mx[hh], v);
            }
        }
    }
#pragma unroll
    for (int m = 1; m < 64; m <<= 1)
#pragma unroll
        for (int hh = 0; hh < 4; ++hh)
            mx[hh] = fmaxf(mx[hh], __shfl_xor(mx[hh], m));
    asm volatile("s_waitcnt lgkmcnt(0)" ::: "memory");
    int h = t >> 4;                       // 8 channels/lane, 128 ch/head -> head = t>>4
    float mh = mx[h];
    float a[8] = {};
    float ds = 0.f;
    const __hip_bfloat16* hrow = hb + 8 * t;
#define ACC8(rr, wt) { \
    unsigned q0 = (rr).x, q1 = (rr).y, q2 = (rr).z, q3 = (rr).w; \
    a[0] += (wt) * __uint_as_float(q0 << 16); a[1] += (wt) * __uint_as_float(q0 & 0xFFFF0000u); \
    a[2] += (wt) * __uint_as_float(q1 << 16); a[3] += (wt) * __uint_as_float(q1 & 0xFFFF0000u); \
    a[4] += (wt) * __uint_as_float(q2 << 16); a[5] += (wt) * __uint_as_float(q2 & 0xFFFF0000u); \
    a[6] += (wt) * __uint_as_float(q3 << 16); a[7] += (wt) * __uint_as_float(q3 & 0xFFFF0000u); }
    if (fit) {
        int p = 0;
        for (; p + 8 <= n; p += 8) {
            int s0 = ssrc[wv][p],     s1 = ssrc[wv][p + 1], s2 = ssrc[wv][p + 2], s3 = ssrc[wv][p + 3];
            int s4 = ssrc[wv][p + 4], s5 = ssrc[wv][p + 5], s6 = ssrc[wv][p + 6], s7 = ssrc[wv][p + 7];
            uint4 r0 = *(const uint4*)&hrow[(size_t)s0 * 512];
            uint4 r1 = *(const uint4*)&hrow[(size_t)s1 * 512];
            uint4 r2 = *(const uint4*)&hrow[(size_t)s2 * 512];
            uint4 r3 = *(const uint4*)&hrow[(size_t)s3 * 512];
            uint4 r4 = *(const uint4*)&hrow[(size_t)s4 * 512];
            uint4 r5 = *(const uint4*)&hrow[(size_t)s5 * 512];
            uint4 r6 = *(const uint4*)&hrow[(size_t)s6 * 512];
            uint4 r7 = *(const uint4*)&hrow[(size_t)s7 * 512];
            float w0 = __expf(lg[wv][p * 4 + h] - mh);
            float w1 = __expf(lg[wv][p * 4 + 4 + h] - mh);
            float w2 = __expf(lg[wv][p * 4 + 8 + h] - mh);
            float w3 = __expf(lg[wv][p * 4 + 12 + h] - mh);
            float w4 = __expf(lg[wv][p * 4 + 16 + h] - mh);
            float w5 = __expf(lg[wv][p * 4 + 20 + h] - mh);
            float w6 = __expf(lg[wv][p * 4 + 24 + h] - mh);
            float w7 = __expf(lg[wv][p * 4 + 28 + h] - mh);
            ds += ((w0 + w1) + (w2 + w3)) + ((w4 + w5) + (w6 + w7));
            ACC8(r0, w0); ACC8(r1, w1); ACC8(r2, w2); ACC8(r3, w3);
            ACC8(r4, w4); ACC8(r5, w5); ACC8(r6, w6); ACC8(r7, w7);
        }
        for (; p + 4 <= n; p += 4) {
            int s0 = ssrc[wv][p], s1 = ssrc[wv][p + 1], s2 = ssrc[wv][p + 2], s3 = ssrc[wv][p + 3];
            uint4 r0 = *(const uint4*)&hrow[(size_t)s0 * 512];
            uint4 r1 = *(const uint4*)&hrow[(size_t)s1 * 512];
            uint4 r2 = *(const uint4*)&hrow[(size_t)s2 * 512];
            uint4 r3 = *(const uint4*)&hrow[(size_t)s3 * 512];
            float w0 = __expf(lg[wv][p * 4 + h] - mh);
            float w1 = __expf(lg[wv][p * 4 + 4 + h] - mh);
            float w2 = __expf(lg[wv][p * 4 + 8 + h] - mh);
            float w3 = __expf(lg[wv][p * 4 + 12 + h] - mh);
            ds += (w0 + w1) + (w2 + w3);
            ACC8(r0, w0); ACC8(r1, w1); ACC8(r2, w2); ACC8(r3, w3);
        }
        for (; p < n; ++p) {
            int s0 = ssrc[wv][p];
            uint4 r0 = *(const uint4*)&hrow[(size_t)s0 * 512];
            float w0 = __expf(lg[wv][p * 4 + h] - mh);
            ds += w0;
            ACC8(r0, w0);
        }
    } else {
        for (int p = 0; p < n; ++p) {
            int2 se = cs[beg + p];
            float eav = (se.y < N_EDGES) ? eaf[se.y] : ea_mean;
            float l4[4];
            load_al4(alsp, se.x, np2, l4);
            float l = l4[h] + adh[h] + eav * sb4[h];
            l = l > 0.f ? l : 0.2f * l;
            float w = __expf(l - mh);
            uint4 r0 = *(const uint4*)&hrow[(size_t)se.x * 512];
            ds += w;
            ACC8(r0, w);
        }
    }
#undef ACC8
    float rdn = 1.0f / (ds + 1e-16f);
    __hip_bfloat16 tmp[8];
#pragma unroll
    for (int j = 0; j < 8; ++j) tmp[j] = __float2bfloat16(a[j] * rdn);
    *(uint4*)&outb[(size_t)d * 512 + 8 * t] = *(uint4*)tmp;
}

// ---- FUSED sort+softmax+agg+head-mean, layer 2: ONE WAVE per dst (2 dst / block) ----
__global__ __launch_bounds__(128) void fused_agg2(
        const int* __restrict__ rowptr, int2* __restrict__ cs,
        const float* __restrict__ alsp, const float* __restrict__ aldp,
        const float* __restrict__ sbuf, const float* __restrict__ eaf,
        const float* __restrict__ ea_acc, const __hip_bfloat16* __restrict__ hb,
        float* __restrict__ out2, int nparts) {
    __shared__ float lg[2][MAXDEG * 4];
    __shared__ int   ssrc[2][MAXDEG];
    __shared__ int2  sbl[2][MAXDEG];
    int wv = threadIdx.x >> 6, t = threadIdx.x & 63;
    int d = blockIdx.x * 2 + wv;
    int beg = rowptr[d], n = rowptr[d + 1] - beg;
    bool fit = (n <= MAXDEG);
    bool np2 = (nparts == 2);
    float ea_mean = ea_acc[0] * (1.0f / N_EDGES);
    float adh[4];
    load_al4(aldp, d, np2, adh);
    float sb4[4] = {sbuf[4], sbuf[5], sbuf[6], sbuf[7]};
    float mx[4] = {-INFINITY, -INFINITY, -INFINITY, -INFINITY};
    wave_sort_row(cs, beg, n, t, sbl[wv]);
    if (fit) {
        for (int p = t; p < n; p += 64) {
            int2 se = sbl[wv][p];
            float eav = (se.y < N_EDGES) ? eaf[se.y] : ea_mean;
            float l[4];
            load_al4(alsp, se.x, np2, l);
#pragma unroll
            for (int hh = 0; hh < 4; ++hh) {
                float v = l[hh] + adh[hh] + eav * sb4[hh];
                v = v > 0.f ? v : 0.2f * v;
                l[hh] = v;
                mx[hh] = fmaxf(mx[hh], v);
            }
            *(float4*)&lg[wv][p * 4] = make_float4(l[0], l[1], l[2], l[3]);
            ssrc[wv][p] = se.x;
        }
    } else {
        for (int p = t; p < n; p += 64) {
            int2 se = cs[beg + p];
            float eav = (se.y < N_EDGES) ? eaf[se.y] : ea_mean;
            float l[4];
            load_al4(alsp, se.x, np2, l);
#pragma unroll
            for (int hh = 0; hh < 4; ++hh) {
                float v = l[hh] + adh[hh] + eav * sb4[hh];
                v = v > 0.f ? v : 0.2f * v;
                mx[hh] = fmaxf(mx[hh], v);
            }
        }
    }
#pragma unroll
    for (int m = 1; m < 64; m <<= 1)
#pragma unroll
        for (int hh = 0; hh < 4; ++hh)
            mx[hh] = fmaxf(mx[hh], __shfl_xor(mx[hh], m));
    asm volatile("s_waitcnt lgkmcnt(0)" ::: "memory");
    int h = t >> 4;                       // 4 channels/lane, 64 ch/head -> head = t>>4
    float mh = mx[h];
    float a4[4] = {};
    float ds = 0.f;
    const __hip_bfloat16* hrow = hb + 4 * t;
#define ACC4(rr, wt) { \
    unsigned q0 = (rr).x, q1 = (rr).y; \
    a4[0] += (wt) * __uint_as_float(q0 << 16); a4[1] += (wt) * __uint_as_float(q0 & 0xFFFF0000u); \
    a4[2] += (wt) * __uint_as_float(q1 << 16); a4[3] += (wt) * __uint_as_float(q1 & 0xFFFF0000u); }
    if (fit) {
        int p = 0;
        for (; p + 8 <= n; p += 8) {
            int s0 = ssrc[wv][p],     s1 = ssrc[wv][p + 1], s2 = ssrc[wv][p + 2], s3 = ssrc[wv][p + 3];
            int s4 = ssrc[wv][p + 4], s5 = ssrc[wv][p + 5], s6 = ssrc[wv][p + 6], s7 = ssrc[wv][p + 7];
            uint2 r0 = *(const uint2*)&hrow[(size_t)s0 * 256];
            uint2 r1 = *(const uint2*)&hrow[(size_t)s1 * 256];
            uint2 r2 = *(const uint2*)&hrow[(size_t)s2 * 256];
            uint2 r3 = *(const uint2*)&hrow[(size_t)s3 * 256];
            uint2 r4 = *(const uint2*)&hrow[(size_t)s4 * 256];
            uint2 r5 = *(const uint2*)&hrow[(size_t)s5 * 256];
            uint2 r6 = *(const uint2*)&hrow[(size_t)s6 * 256];
            uint2 r7 = *(const uint2*)&hrow[(size_t)s7 * 256];
            float w0 = __expf(lg[wv][p * 4 + h] - mh);
            float w1 = __expf(lg[wv][p * 4 + 4 + h] - mh);
            float w2 = __expf(lg[wv][p * 4 + 8 + h] - mh);
            float w3 = __expf(lg[wv][p * 4 + 12 + h] - mh);
            float w4 = __expf(lg[wv][p * 4 + 16 + h] - mh);
            float w5 = __expf(lg[wv][p * 4 + 20 + h] - mh);
            float w6 = __expf(lg[wv][p * 4 + 24 + h] - mh);
            float w7 = __expf(lg[wv][p * 4 + 28 + h] - mh);
            ds += ((w0 + w1) + (w2 + w3)) + ((w4 + w5) + (w6 + w7));
            ACC4(r0, w0); ACC4(r1, w1); ACC4(r2, w2); ACC4(r3, w3);
            ACC4(r4, w4); ACC4(r5, w5); ACC4(r6, w6); ACC4(r7, w7);
        }
        for (; p + 4 <= n; p += 4) {
            int s0 = ssrc[wv][p], s1 = ssrc[wv][p + 1], s2 = ssrc[wv][p + 2], s3 = ssrc[wv][p + 3];
            uint2 r0 = *(const uint2*)&hrow[(size_t)s0 * 256];
            uint2 r1 = *(const uint2*)&hrow[(size_t)s1 * 256];
            uint2 r2 = *(const uint2*)&hrow[(size_t)s2 * 256];
            uint2 r3 = *(const uint2*)&hrow[(size_t)s3 * 256];
            float w0 = __expf(lg[wv][p * 4 + h] - mh);
            float w1 = __expf(lg[wv][p * 4 + 4 + h] - mh);
            float w2 = __expf(lg[wv][p * 4 + 8 + h] - mh);
            float w3 = __expf(lg[wv][p * 4 + 12 + h] - mh);
            ds += (w0 + w1) + (w2 + w3);
            ACC4(r0, w0); ACC4(r1, w1); ACC4(r2, w2); ACC4(r3, w3);
        }
        for (; p < n; ++p) {
            int s0 = ssrc[wv][p];
            uint2 r0 = *(const uint2*)&hrow[(size_t)s0 * 256];
            float w0 = __expf(lg[wv][p * 4 + h] - mh);
            ds += w0;
            ACC4(r0, w0);
        }
    } else {
        for (int p = 0; p < n; ++p) {
            int2 se = cs[beg + p];
            float eav = (se.y < N_EDGES) ? eaf[se.y] : ea_mean;
            float l4[4];
            load_al4(alsp, se.x, np2, l4);
            float l = l4[h] + adh[h] + eav * sb4[h];
            l = l > 0.f ? l : 0.2f * l;
            float w = __expf(l - mh);
            uint2 r0 = *(const uint2*)&hrow[(size_t)se.x * 256];
            ds += w;
            ACC4(r0, w);
        }
    }
#undef ACC4
    float rdn = 1.0f / (ds + 1e-16f);
#pragma unroll
    for (int j = 0; j < 4; ++j) {
        float v = a4[j] * rdn;
        v += __shfl_xor(v, 16);
        v += __shfl_xor(v, 32);
        a4[j] = v * 0.25f;
    }
    if (t < 16)
        *(float4*)&out2[(size_t)d * 64 + 4 * t] = make_float4(a4[0], a4[1], a4[2], a4[3]);
}

// ---- BN1 stats: per-block partials ----
__global__ __launch_bounds__(256) void bn_part_b(const __hip_bfloat16* __restrict__ x,
                                                 float* __restrict__ pmu, float* __restrict__ pm2) {
    int t = threadIdx.x, b = blockIdx.x;
    float s0 = 0.f, s20 = 0.f, s1 = 0.f, s21 = 0.f;
    for (int i = b; i < N_NODES; i += gridDim.x) {
        unsigned u = *(const unsigned*)&x[(size_t)i * 512 + 2 * t];
        float v0 = __uint_as_float(u << 16);
        float v1 = __uint_as_float(u & 0xFFFF0000u);
        s0 += v0; s20 += v0 * v0; s1 += v1; s21 += v1 * v1;
    }
    pmu[b * 512 + 2 * t] = s0;     pm2[b * 512 + 2 * t] = s20;
    pmu[b * 512 + 2 * t + 1] = s1; pm2[b * 512 + 2 * t + 1] = s21;
}

// ---- reduce partials -> affine a,b : parallel (4 splits/channel, fixed-order combine) ----
__global__ __launch_bounds__(256) void bn_reduce_affine(const float* __restrict__ pmu, const float* __restrict__ pm2,
                                 const float* __restrict__ smalls, int s_g, int s_be,
                                 float* __restrict__ a, float* __restrict__ b, int nch) {
    __shared__ float shs[4][64], sh2[4][64];
    int t = threadIdx.x;
    int cl = t & 63, j = t >> 6;
    int c = blockIdx.x * 64 + cl;
    float s = 0.f, s2 = 0.f;
    for (int bk = j * 64; bk < (j + 1) * 64; ++bk) { s += pmu[bk * nch + c]; s2 += pm2[bk * nch + c]; }
    shs[j][cl] = s; sh2[j][cl] = s2;
    __syncthreads();
    if (j == 0) {
        float st  = ((shs[0][cl] + shs[1][cl]) + (shs[2][cl] + shs[3][cl]));
        float st2 = ((sh2[0][cl] + sh2[1][cl]) + (sh2[2][cl] + sh2[3][cl]));
        float m = st * (1.0f / N_NODES);
        float var = st2 * (1.0f / N_NODES) - m * m;
        float aa = smalls[s_g + c] * rsqrtf(var + 1e-5f);
        a[c] = aa;
        b[c] = smalls[s_be + c] - m * aa;
    }
}

// ---- BN2 stats: per-block partials ----
__global__ __launch_bounds__(256) void bn2_stats(const float* __restrict__ x,
                                                 float* __restrict__ pmu, float* __restrict__ pm2) {
    int t = threadIdx.x;
    int c = t & 63, j = t >> 6;
    float ls = 0.f, ls2 = 0.f;
    for (int nd = blockIdx.x * 4 + j; nd < N_NODES; nd += gridDim.x * 4) {
        float v = x[(size_t)nd * 64 + c];
        ls += v; ls2 += v * v;
    }
    __shared__ float shs[4][64], sh2[4][64];
    shs[j][c] = ls; sh2[j][c] = ls2;
    __syncthreads();
    if (j == 0) {
        pmu[blockIdx.x * 64 + c] = shs[0][c] + shs[1][c] + shs[2][c] + shs[3][c];
        pm2[blockIdx.x * 64 + c] = sh2[0][c] + sh2[1][c] + sh2[2][c] + sh2[3][c];
    }
}

// ---- pool stage 1: 8 chunks per graph, BN2 affine+ELU fused, partial sums ----
__global__ __launch_bounds__(256) void pool_part(const float* __restrict__ x, const int* __restrict__ gstart,
                                                 const float* __restrict__ a2, const float* __restrict__ b2,
                                                 float* __restrict__ pp) {
    int g = blockIdx.x >> 3, ck = blockIdx.x & 7;
    int t = threadIdx.x;
    int c = t & 63, j = t >> 6;
    int beg = gstart[g], end = gstart[g + 1], n = end - beg;
    int cb = beg + (n * ck) / 8, ce = beg + (n * (ck + 1)) / 8;
    float ac = a2[c], bc = b2[c];
    float s = 0.f;
    for (int i = cb + j; i < ce; i += 4) {
        float y = ac * x[(size_t)i * 64 + c] + bc;
        s += (y > 0.f ? y : expm1f(y));
    }
    __shared__ float sh[4][64];
    sh[j][c] = s;
    __syncthreads();
    if (j == 0)
        pp[blockIdx.x * 64 + c] = sh[0][c] + sh[1][c] + sh[2][c] + sh[3][c];
}

// ---- pool stage 2: reduce 8 chunks (fixed order) + MLP ----
__global__ __launch_bounds__(64) void pool_mlp_fin(const float* __restrict__ pp, const int* __restrict__ gstart,
                                                   const float* __restrict__ smalls, const int* __restrict__ flag,
                                                   void* __restrict__ outp) {
    int g = blockIdx.x, t = threadIdx.x;
    __shared__ float pooled[64];
    __shared__ float hsh[32];
    float s = 0.f;
    for (int k = 0; k < 8; ++k) s += pp[(g * 8 + k) * 64 + t];
    int n = gstart[g + 1] - gstart[g];
    pooled[t] = s / fmaxf((float)n, 1.0f);
    __syncthreads();
    if (t < 32) {
        float acc = smalls[S_FB1 + t];
        for (int cc = 0; cc < 64; ++cc)
            acc += pooled[cc] * smalls[S_FW1 + cc * 32 + t];
        hsh[t] = acc > 0.f ? acc : expm1f(acc);
    }
    __syncthreads();
    if (t == 0) {
        float o = smalls[S_FB2];
        for (int k = 0; k < 32; ++k) o += hsh[k] * smalls[S_FW2 + k];
        if (flag[0]) ((float*)outp)[g] = o;
        else ((__hip_bfloat16*)outp)[g] = __float2bfloat16(o);
    }
}

extern "C" void kernel_launch(void* const* d_in, const int* in_sizes, int n_in,
                              void* d_out, int out_size, void* d_ws, size_t ws_size,
                              hipStream_t stream) {
    const void* x    = d_in[0];
    const int* ei    = (const int*)d_in[1];
    const int* batch = (const int*)d_in[2];
    const void* ea   = d_in[3];
    const void* W1   = d_in[4];
    const void* as1  = d_in[5];
    const void* ad1  = d_in[6];
    const void* We1  = d_in[7];
    const void* ae1  = d_in[8];
    const void* g1   = d_in[10];
    const void* be1  = d_in[11];
    const void* W2   = d_in[12];
    const void* as2  = d_in[13];
    const void* ad2  = d_in[14];
    const void* We2  = d_in[15];
    const void* ae2  = d_in[16];
    const void* g2   = d_in[18];
    const void* be2  = d_in[19];
    const void* fw1  = d_in[20];
    const void* fb1  = d_in[21];
    const void* fw2  = d_in[22];
    const void* fb2  = d_in[23];

    char* ws = (char*)d_ws;
    __hip_bfloat16* xb   = (__hip_bfloat16*)(ws + XB_OFF);
    __hip_bfloat16* hb1  = (__hip_bfloat16*)(ws + HB1_OFF);
    __hip_bfloat16* agg1 = (__hip_bfloat16*)(ws + AGG1_OFF);
    __hip_bfloat16* hb2  = (__hip_bfloat16*)(ws + HB2_OFF);
    float* out2   = (float*)(ws + OUT2_OFF);
    float* eaf    = (float*)(ws + EAF_OFF);
    __hip_bfloat16* W1bt = (__hip_bfloat16*)(ws + W1BT_OFF);
    __hip_bfloat16* W2bt = (__hip_bfloat16*)(ws + W2BT_OFF);
    int2*  csr_se = (int2*)(ws + CSR_OFF);
    int*   rowptr = (int*)(ws + ROWPTR_OFF);
    int*   gstart = (int*)(ws + GSTART_OFF);
    float* smalls = (float*)(ws + SMALL_OFF);
    float* sbuf   = (float*)(ws + SBUF_OFF);
    float* eap    = (float*)(ws + EAP_OFF);
    float* alsp   = (float*)(ws + ALSP_OFF);
    float* aldp   = (float*)(ws + ALDP_OFF);
    float* pmu1   = (float*)(ws + PMU1_OFF);
    float* pm21   = (float*)(ws + PM21_OFF);
    float* pmu2   = (float*)(ws + PMU2_OFF);
    float* pm22   = (float*)(ws + PM22_OFF);
    float* a1     = (float*)(ws + A1_OFF);
    float* b1     = (float*)(ws + B1_OFF);
    float* a2     = (float*)(ws + A2_OFF);
    float* b2     = (float*)(ws + B2_OFF);
    float* ea_acc = (float*)(ws + EAACC_OFF);
    float* pp     = (float*)(ws + PP_OFF);
    int*   deg    = (int*)(ws + DEG_OFF);
    int*   cursor = (int*)(ws + CURS_OFF);
    int*   flag   = (int*)(ws + FLAGZ_OFF);

    hipMemsetAsync(ws + ZERO0_START, 0, ZERO0_SIZE, stream);

    detect_hist<<<DH_DETECT + HIST_BLOCKS + 79, 256, 0, stream>>>(
        (const unsigned short*)x, flag, ei, deg, batch, gstart);
    prep<<<PREP_BLOCKS, 256, 0, stream>>>(flag, x, ea, W1, W2,
                                          as1, ad1, We1, ae1, g1, be1, as2, ad2,
                                          We2, ae2, g2, be2, fw1, fb1, fw2, fb2,
                                          xb, eaf, eap, W1bt, W2bt, smalls, sbuf);
    deg_scan<<<1, 1024, 0, stream>>>(deg, rowptr, eap, ea_acc);

    // ---------- layer 1 (GEMM overlapped with edge_scatter) ----------
    gemm1_scatter<<<G1_BLOCKS + HIST_BLOCKS, 256, 0, stream>>>(
        (const short*)xb, (const short*)W1bt, hb1,
        alsp, aldp, smalls + S_AS1, smalls + S_AD1,
        ei, rowptr, cursor, csr_se);
    fused_agg1<<<N_NODES / 2, 128, 0, stream>>>(rowptr, csr_se, alsp, aldp, sbuf,
                                                eaf, ea_acc, hb1, agg1, 2);
    bn_part_b<<<256, 256, 0, stream>>>(agg1, pmu1, pm21);
    bn_reduce_affine<<<8, 256, 0, stream>>>(pmu1, pm21, smalls, S_G1, S_BE1, a1, b1, 512);

    // ---------- layer 2 (BN1+ELU folded into A-staging) ----------
    gemm_mfma_al<<<dim3(256 / 64, MPAD / 128), 256, 0, stream>>>(
        (const short*)agg1, (const short*)W2bt, hb2, 256, 512,
        alsp, aldp, smalls + S_AS2, smalls + S_AD2, 6, a1, b1);
    fused_agg2<<<N_NODES / 2, 128, 0, stream>>>(rowptr, csr_se, alsp, aldp, sbuf,
                                                eaf, ea_acc, hb2, out2, 1);
    bn2_stats<<<256, 256, 0, stream>>>(out2, pmu2, pm22);
    bn_reduce_affine<<<1, 256, 0, stream>>>(pmu2, pm22, smalls, S_G2, S_BE2, a2, b2, 64);

    // ---------- BN2+ELU+pool (2-stage) + MLP ----------
    pool_part<<<N_GRAPHS * 8, 256, 0, stream>>>(out2, gstart, a2, b2, pp);
    pool_mlp_fin<<<N_GRAPHS, 64, 0, stream>>>(pp, gstart, smalls, flag, d_out);
}

// Round 10
// 417.503 us; speedup vs baseline: 1.1437x; 1.0001x over previous
//
#include <hip/hip_runtime.h>
#include <hip/hip_bf16.h>

#define N_NODES  20000
#define MPAD     20096
#define N_EDGES  320000
#define N_EP     (N_EDGES + N_NODES)
#define D_IN     256
#define N_GRAPHS 32
#define HH1 4
#define CC1 128
#define HH2 4
#define CC2 64
#define MAXDEG   128

// ---- workspace layout (bytes) ----
#define XB_OFF      0ull                    // 10,289,152 : x bf16 [MPAD,256]
#define HB1_OFF     10289152ull             // 20,578,304 : h1 bf16 [MPAD,512]
#define AGG1_OFF    30867456ull             // 20,578,304 : agg1 bf16 [MPAD,512] (raw, pre-BN)
#define HB2_OFF     51445760ull             // 10,289,152 : h2 bf16 [MPAD,256]
#define OUT2_OFF    61734912ull             //  5,120,000 : head-mean fp32 [20000,64] (pre-BN)
#define EAF_OFF     66854912ull             //  1,280,000
#define W1BT_OFF    68134912ull             //    262,144
#define W2BT_OFF    68397056ull             //    262,144
#define CSR_OFF     68659200ull             //  2,720,000 (int2: s, edge-id -> s, eav-bits)
#define ROWPTR_OFF  71379200ull             //     80,064
#define GSTART_OFF  71459264ull             //        256
#define SMALL_OFF   71459520ull             //     25,600
#define SBUF_OFF    71485120ull             //         64
#define EAP_OFF     71485184ull             //      1,280
#define ALSP_OFF    71486464ull             //    643,072 : al partials [MPAD*4][2]
#define ALDP_OFF    72129536ull             //    643,072
#define PMU1_OFF    72772608ull             //    524,288
#define PM21_OFF    73296896ull             //    524,288
#define PMU2_OFF    73821184ull             //     65,536
#define PM22_OFF    73886720ull             //     65,536
#define A1_OFF      73952256ull             //      2,048
#define B1_OFF      73954304ull             //      2,048
#define A2_OFF      73956352ull             //        256
#define B2_OFF      73956608ull             //        256
#define EAACC_OFF   73956864ull             //         64
// ---- zeroed-at-start region ----
#define DEG_OFF     74600000ull             //     80,000
#define CURS_OFF    74680000ull             //     80,000
#define FLAGZ_OFF   74760000ull             //        128
#define ZERO0_START DEG_OFF
#define ZERO0_SIZE  160128ull
#define PP_OFF      74760128ull             //     65,536 : pool partials [256][64]

// small-region float offsets
#define S_AS1 0
#define S_AD1 512
#define S_WE1 1024
#define S_AE1 1536
#define S_G1  2048
#define S_BE1 2560
#define S_AS2 3072
#define S_AD2 3328
#define S_WE2 3584
#define S_AE2 3840
#define S_G2  4096
#define S_BE2 4160
#define S_FW1 4224
#define S_FB1 6272
#define S_FW2 6304
#define S_FB2 6336

typedef __attribute__((ext_vector_type(8))) short bf8_t;
typedef __attribute__((ext_vector_type(4))) float f4_t;

__device__ __forceinline__ float loadF(const void* p, int i, int fp32) {
    return fp32 ? ((const float*)p)[i]
                : __bfloat162float(((const __hip_bfloat16*)p)[i]);
}

// ---- fused dtype-detect + degree-hist + graph bounds ----
#define DH_DETECT 256
#define HIST_BLOCKS 1329
__global__ void detect_hist(const unsigned short* __restrict__ xr, int* __restrict__ flag,
                            const int* __restrict__ ei, int* __restrict__ deg,
                            const int* __restrict__ batch, int* __restrict__ gstart) {
    int b = blockIdx.x, t = threadIdx.x;
    if (b < DH_DETECT) {
        int i = b * 256 + t;
        unsigned short u = xr[i];
        if ((u & 0x7F80) == 0x7F80) atomicOr(flag, 1);
        return;
    }
    b -= DH_DETECT;
    if (b < HIST_BLOCKS) {
        int e = b * 256 + t;
        if (e >= N_EP) return;
        int d = (e < N_EDGES) ? ei[N_EDGES + e] : e - N_EDGES;
        atomicAdd(&deg[d], 1);
        return;
    }
    int i = (b - HIST_BLOCKS) * 256 + t;
    if (i >= N_NODES) return;
    int bb = batch[i];
    if (i == 0) {
        for (int g = 0; g <= bb; ++g) gstart[g] = 0;
    } else {
        int pb = batch[i - 1];
        for (int g = pb + 1; g <= bb; ++g) gstart[g] = i;
    }
    if (i == N_NODES - 1) {
        for (int g = bb + 1; g <= N_GRAPHS; ++g) gstart[g] = N_NODES;
    }
}

// ---- fused prep ----
#define PB_XB  5024
#define PB_EAF 313
#define PB_W   512
#define PB_SM  16
#define PREP_BLOCKS (PB_XB + PB_EAF + 2 * PB_W + PB_SM + 1)
__global__ __launch_bounds__(256) void prep(
        const int* __restrict__ flag,
        const void* x, const void* ea, const void* W1, const void* W2,
        const void* as1, const void* ad1, const void* We1, const void* ae1,
        const void* g1, const void* be1, const void* as2, const void* ad2,
        const void* We2, const void* ae2, const void* g2, const void* be2,
        const void* fw1, const void* fb1, const void* fw2, const void* fb2,
        __hip_bfloat16* __restrict__ xb, float* __restrict__ eaf, float* __restrict__ eap,
        __hip_bfloat16* __restrict__ W1bt, __hip_bfloat16* __restrict__ W2bt,
        float* __restrict__ smalls, float* __restrict__ sbuf) {
    __shared__ float shw[4];
    int b = blockIdx.x, t = threadIdx.x;
    int fp32 = flag[0];
    if (b < PB_XB) {
        int base = (b * 256 + t) * 4;
        __hip_bfloat16 tmp[4];
#pragma unroll
        for (int j = 0; j < 4; ++j) {
            int i = base + j;
            float v = (i < N_NODES * D_IN) ? loadF(x, i, fp32) : 0.f;
            tmp[j] = __float2bfloat16(v);
        }
        *(uint2*)&xb[base] = *(uint2*)tmp;
        return;
    }
    b -= PB_XB;
    if (b < PB_EAF) {
        int base = (b * 256 + t) * 4;
        float s = 0.f;
#pragma unroll
        for (int j = 0; j < 4; ++j) {
            int i = base + j;
            if (i < N_EDGES) { float v = loadF(ea, i, fp32); eaf[i] = v; s += v; }
        }
#pragma unroll
        for (int m = 1; m < 64; m <<= 1) s += __shfl_xor(s, m);
        if ((t & 63) == 0) shw[t >> 6] = s;
        __syncthreads();
        if (t == 0) eap[b] = shw[0] + shw[1] + shw[2] + shw[3];
        return;
    }
    b -= PB_EAF;
    if (b < PB_W) {
        int i = b * 256 + t;
        int k = i >> 9, n = i & 511;
        W1bt[(size_t)n * 256 + k] = __float2bfloat16(loadF(W1, i, fp32));
        return;
    }
    b -= PB_W;
    if (b < PB_W) {
        int i = b * 256 + t;
        int k = i >> 8, n = i & 255;
        W2bt[(size_t)n * 512 + k] = __float2bfloat16(loadF(W2, i, fp32));
        return;
    }
    b -= PB_W;
    if (b < PB_SM) {
        const void* srcs[16] = {as1, ad1, We1, ae1, g1, be1, as2, ad2, We2, ae2, g2, be2, fw1, fb1, fw2, fb2};
        const int cnts[16] = {512, 512, 512, 512, 512, 512, 256, 256, 256, 256, 64, 64, 2048, 32, 32, 1};
        const int offs[16] = {S_AS1, S_AD1, S_WE1, S_AE1, S_G1, S_BE1, S_AS2, S_AD2,
                              S_WE2, S_AE2, S_G2, S_BE2, S_FW1, S_FB1, S_FW2, S_FB2};
        for (int i = t; i < cnts[b]; i += 256)
            smalls[offs[b] + i] = loadF(srcs[b], i, fp32);
        return;
    }
    if (t < 4) {
        float s = 0.f;
        for (int c = 0; c < CC1; ++c) s += loadF(We1, t * CC1 + c, fp32) * loadF(ae1, t * CC1 + c, fp32);
        sbuf[t] = s;
    } else if (t < 8) {
        int h = t - 4;
        float s = 0.f;
        for (int c = 0; c < CC2; ++c) s += loadF(We2, h * CC2 + c, fp32) * loadF(ae2, h * CC2 + c, fp32);
        sbuf[4 + h] = s;
    }
}

__global__ __launch_bounds__(1024) void deg_scan(const int* __restrict__ deg, int* __restrict__ rowptr,
                                                 const float* __restrict__ eap, float* __restrict__ ea_acc) {
    __shared__ int part[1024];
    __shared__ float fsh[512];
    int t = threadIdx.x;
    int lo = t * 20;
    int hi = lo + 20; if (hi > N_NODES) hi = N_NODES; if (lo > N_NODES) lo = N_NODES;
    int s = 0;
    for (int i = lo; i < hi; ++i) s += deg[i];
    part[t] = s;
    __syncthreads();
    for (int off = 1; off < 1024; off <<= 1) {
        int u = (t >= off) ? part[t - off] : 0;
        __syncthreads();
        if (t >= off) part[t] += u;
        __syncthreads();
    }
    int run = part[t] - s;
    for (int i = lo; i < hi; ++i) { rowptr[i] = run; run += deg[i]; }
    if (hi == N_NODES && lo < N_NODES) rowptr[N_NODES] = run;
    if (t < 512) fsh[t] = (t < PB_EAF) ? eap[t] : 0.f;
    __syncthreads();
    for (int st = 256; st; st >>= 1) {
        if (t < st) fsh[t] += fsh[t + st];
        __syncthreads();
    }
    if (t == 0) ea_acc[0] = fsh[0];
}

// ---- canonical CSR sort + eav fill (standalone; n-round shfl for n<=64) ----
__global__ __launch_bounds__(64) void csr_sort_fill(const int* __restrict__ rowptr, int2* __restrict__ cs,
                                                    const float* __restrict__ eaf,
                                                    const float* __restrict__ ea_acc) {
    __shared__ int2 buf[128];
    int d = blockIdx.x;
    int beg = rowptr[d], end = rowptr[d + 1], n = end - beg;
    int lane = threadIdx.x;
    float ea_mean = ea_acc[0] * (1.0f / N_EDGES);
    if (n <= 0) return;
    if (n <= 64) {
        int key = 0x7FFFFFFF, val = 0;
        if (lane < n) { int2 se = cs[beg + lane]; key = se.y; val = se.x; }
        for (int r = 0; r < n; ++r) {
            bool up = ((lane & 1) == (r & 1));
            int partner = up ? lane + 1 : lane - 1;
            bool valid = (partner >= 0) && (partner < 64);
            int pidx = valid ? partner : lane;
            int pk = __shfl(key, pidx);
            int pv = __shfl(val, pidx);
            if (valid && (up ? (pk < key) : (pk > key))) { key = pk; val = pv; }
        }
        if (lane < n) {
            float eav = (key < N_EDGES) ? eaf[key] : ea_mean;
            cs[beg + lane] = make_int2(val, __float_as_int(eav));
        }
        return;
    }
    if (n <= 128) {
        for (int i = lane; i < n; i += 64) buf[i] = cs[beg + i];
        __syncthreads();
        for (int r = 0; r < n; ++r) {
            int i = 2 * lane + (r & 1);
            if (i + 1 < n) {
                int2 a = buf[i], b = buf[i + 1];
                if (a.y > b.y) { buf[i] = b; buf[i + 1] = a; }
            }
            __syncthreads();
        }
        for (int i = lane; i < n; i += 64) {
            int2 se = buf[i];
            float eav = (se.y < N_EDGES) ? eaf[se.y] : ea_mean;
            se.y = __float_as_int(eav);
            cs[beg + i] = se;
        }
        return;
    }
    if (lane == 0) {
        for (int i = beg + 1; i < end; ++i) {
            int2 key = cs[i]; int j = i - 1;
            while (j >= beg && cs[j].y > key.y) { cs[j + 1] = cs[j]; --j; }
            cs[j + 1] = key;
        }
    }
    __syncthreads();
    for (int i = lane; i < n; i += 64) {
        int2 se = cs[beg + i];
        float eav = (se.y < N_EDGES) ? eaf[se.y] : ea_mean;
        se.y = __float_as_int(eav);
        cs[beg + i] = se;
    }
}

// ---- BN1-affine + ELU + bf16 repack for 8 contiguous channels (bit-identical math) ----
__device__ __forceinline__ uint4 bn_elu_pack(uint4 v, const float* __restrict__ a8,
                                             const float* __restrict__ b8) {
    unsigned q[4] = {v.x, v.y, v.z, v.w};
    float4 a0 = *(const float4*)a8, a1 = *(const float4*)(a8 + 4);
    float4 b0 = *(const float4*)b8, b1 = *(const float4*)(b8 + 4);
    float av[8] = {a0.x, a0.y, a0.z, a0.w, a1.x, a1.y, a1.z, a1.w};
    float bv[8] = {b0.x, b0.y, b0.z, b0.w, b1.x, b1.y, b1.z, b1.w};
    __hip_bfloat16 t[8];
#pragma unroll
    for (int k = 0; k < 8; ++k) {
        unsigned u = (k & 1) ? (q[k >> 1] & 0xFFFF0000u) : (q[k >> 1] << 16);
        float y = av[k] * __uint_as_float(u) + bv[k];
        y = y > 0.f ? y : expm1f(y);
        t[k] = __float2bfloat16(y);
    }
    return *(uint4*)t;
}

// ---- MFMA bf16 GEMM body + al epilogue via deterministic partial slots ----
__device__ __forceinline__ void gemm_body(
        const short* __restrict__ A, const short* __restrict__ Bt,
        __hip_bfloat16* __restrict__ Cb, int N, int K,
        float* __restrict__ alsp, float* __restrict__ aldp,
        const float* __restrict__ asv, const float* __restrict__ adv, int cshift,
        const float* __restrict__ bna, const float* __restrict__ bnb,
        int bx, int by) {
    __shared__ short As[128 * 40];
    __shared__ short Bs[64 * 40];
    int t = threadIdx.x;
    int wv = t >> 6, lane = t & 63, quad = lane >> 4, lr = lane & 15;
    int m0 = by * 128, n0 = bx * 64;
    f4_t acc[2][4] = {};
    int ra0 = t >> 2, sa0 = t & 3;
    int ra1 = (t + 256) >> 2;
    for (int k0 = 0; k0 < K; k0 += 32) {
        uint4 va0 = *(const uint4*)&A[(size_t)(m0 + ra0) * K + k0 + sa0 * 8];
        uint4 va1 = *(const uint4*)&A[(size_t)(m0 + ra1) * K + k0 + sa0 * 8];
        uint4 vb  = *(const uint4*)&Bt[(size_t)(n0 + ra0) * K + k0 + sa0 * 8];
        if (bna) {
            int j = k0 + sa0 * 8;
            va0 = bn_elu_pack(va0, bna + j, bnb + j);
            va1 = bn_elu_pack(va1, bna + j, bnb + j);
        }
        *(uint4*)&As[ra0 * 40 + sa0 * 8] = va0;
        *(uint4*)&As[ra1 * 40 + sa0 * 8] = va1;
        *(uint4*)&Bs[ra0 * 40 + sa0 * 8] = vb;
        __syncthreads();
        bf8_t a0 = *(const bf8_t*)&As[(wv * 16 + lr) * 40 + quad * 8];
        bf8_t a1 = *(const bf8_t*)&As[((wv + 4) * 16 + lr) * 40 + quad * 8];
#pragma unroll
        for (int nt = 0; nt < 4; ++nt) {
            bf8_t b = *(const bf8_t*)&Bs[(nt * 16 + lr) * 40 + quad * 8];
            acc[0][nt] = __builtin_amdgcn_mfma_f32_16x16x32_bf16(a0, b, acc[0][nt], 0, 0, 0);
            acc[1][nt] = __builtin_amdgcn_mfma_f32_16x16x32_bf16(a1, b, acc[1][nt], 0, 0, 0);
        }
        __syncthreads();
    }
#pragma unroll
    for (int si = 0; si < 2; ++si) {
        int mrow = m0 + (wv + si * 4) * 16 + quad * 4;
#pragma unroll
        for (int nt = 0; nt < 4; ++nt) {
            int col = n0 + nt * 16 + lr;
#pragma unroll
            for (int r = 0; r < 4; ++r)
                Cb[(size_t)(mrow + r) * N + col] = __float2bfloat16(acc[si][nt][r]);
        }
    }
    float asv4[4], adv4[4];
#pragma unroll
    for (int nt = 0; nt < 4; ++nt) {
        asv4[nt] = asv[n0 + nt * 16 + lr];
        adv4[nt] = adv[n0 + nt * 16 + lr];
    }
    int hsel = n0 >> cshift;
    int parity = (n0 >> 6) & ((1 << (cshift - 6)) - 1);
#pragma unroll
    for (int si = 0; si < 2; ++si) {
#pragma unroll
        for (int r = 0; r < 4; ++r) {
            float ps = 0.f, pd = 0.f;
#pragma unroll
            for (int nt = 0; nt < 4; ++nt) {
                ps += acc[si][nt][r] * asv4[nt];
                pd += acc[si][nt][r] * adv4[nt];
            }
#pragma unroll
            for (int m = 1; m < 16; m <<= 1) {
                ps += __shfl_xor(ps, m);
                pd += __shfl_xor(pd, m);
            }
            if (lr == 0) {
                int row = m0 + (wv + si * 4) * 16 + quad * 4 + r;
                alsp[(row * 4 + hsel) * 2 + parity] = ps;
                aldp[(row * 4 + hsel) * 2 + parity] = pd;
            }
        }
    }
}

// ---- layer-1 GEMM merged with edge_scatter (independent work, overlapped) ----
#define G1_BLOCKS 1256          // (512/64) x (MPAD/128) = 8 x 157
__global__ __launch_bounds__(256) void gemm1_scatter(
        const short* __restrict__ A, const short* __restrict__ Bt,
        __hip_bfloat16* __restrict__ Cb,
        float* __restrict__ alsp, float* __restrict__ aldp,
        const float* __restrict__ asv, const float* __restrict__ adv,
        const int* __restrict__ ei, const int* __restrict__ rowptr,
        int* __restrict__ cursor, int2* __restrict__ csr_se) {
    int blk = blockIdx.x;
    if (blk >= G1_BLOCKS) {
        int e = (blk - G1_BLOCKS) * 256 + threadIdx.x;
        if (e >= N_EP) return;
        int s, dd;
        if (e < N_EDGES) { s = ei[e]; dd = ei[N_EDGES + e]; }
        else { s = dd = e - N_EDGES; }
        int pos = rowptr[dd] + atomicAdd(&cursor[dd], 1);
        csr_se[pos] = make_int2(s, e);
        return;
    }
    gemm_body(A, Bt, Cb, 512, 256, alsp, aldp, asv, adv, 7, nullptr, nullptr,
              blk & 7, blk >> 3);
}

// ---- layer-2 GEMM (BN1+ELU folded on A operand) ----
__global__ __launch_bounds__(256) void gemm_mfma_al(
        const short* __restrict__ A, const short* __restrict__ Bt,
        __hip_bfloat16* __restrict__ Cb, int N, int K,
        float* __restrict__ alsp, float* __restrict__ aldp,
        const float* __restrict__ asv, const float* __restrict__ adv, int cshift,
        const float* __restrict__ bna, const float* __restrict__ bnb) {
    gemm_body(A, Bt, Cb, N, K, alsp, aldp, asv, adv, cshift, bna, bnb,
              blockIdx.x, blockIdx.y);
}

// ---- inline slot-combine: slots (row*4+h)*2+parity ----
__device__ __forceinline__ void load_al4(const float* __restrict__ alp, int row, bool np2, float out[4]) {
    const float4* ap = (const float4*)(alp + (size_t)row * 8);
    float4 e0 = ap[0], e1 = ap[1];
    out[0] = e0.x; out[1] = e0.z; out[2] = e1.x; out[3] = e1.z;
    if (np2) { out[0] += e0.y; out[1] += e0.w; out[2] += e1.y; out[3] += e1.w; }
}

// ---- FUSED deterministic softmax+agg, layer 1: ONE WAVE per dst (2 dst / block) ----
__global__ __launch_bounds__(128) void fused_agg1(
        const int* __restrict__ rowptr, const int2* __restrict__ cs,
        const float* __restrict__ alsp, const float* __restrict__ aldp,
        const float* __restrict__ sbuf, const __hip_bfloat16* __restrict__ hb,
        __hip_bfloat16* __restrict__ outb, int nparts) {
    __shared__ float lg[2][MAXDEG * 4];
    __shared__ int   ssrc[2][MAXDEG];
    int wv = threadIdx.x >> 6, t = threadIdx.x & 63;
    int d = blockIdx.x * 2 + wv;
    int beg = rowptr[d], n = rowptr[d + 1] - beg;
    bool fit = (n <= MAXDEG);
    bool np2 = (nparts == 2);
    float adh[4];
    load_al4(aldp, d, np2, adh);
    float sb4[4] = {sbuf[0], sbuf[1], sbuf[2], sbuf[3]};
    float mx[4] = {-INFINITY, -INFINITY, -INFINITY, -INFINITY};
    for (int p = t; p < n; p += 64) {
        int2 se = cs[beg + p];
        float eav = __int_as_float(se.y);
        float l[4];
        load_al4(alsp, se.x, np2, l);
#pragma unroll
        for (int hh = 0; hh < 4; ++hh) {
            float v = l[hh] + adh[hh] + eav * sb4[hh];
            v = v > 0.f ? v : 0.2f * v;
            l[hh] = v;
            mx[hh] = fmaxf(mx[hh], v);
        }
        if (fit) {
            *(float4*)&lg[wv][p * 4] = make_float4(l[0], l[1], l[2], l[3]);
            ssrc[wv][p] = se.x;
        }
    }
#pragma unroll
    for (int m = 1; m < 64; m <<= 1)
#pragma unroll
        for (int hh = 0; hh < 4; ++hh)
            mx[hh] = fmaxf(mx[hh], __shfl_xor(mx[hh], m));
    asm volatile("s_waitcnt lgkmcnt(0)" ::: "memory");
    int h = t >> 4;                       // 8 channels/lane, 128 ch/head -> head = t>>4
    float mh = mx[h];
    float a[8] = {};
    float ds = 0.f;
    const __hip_bfloat16* hrow = hb + 8 * t;
#define ACC8(rr, wt) { \
    unsigned q0 = (rr).x, q1 = (rr).y, q2 = (rr).z, q3 = (rr).w; \
    a[0] += (wt) * __uint_as_float(q0 << 16); a[1] += (wt) * __uint_as_float(q0 & 0xFFFF0000u); \
    a[2] += (wt) * __uint_as_float(q1 << 16); a[3] += (wt) * __uint_as_float(q1 & 0xFFFF0000u); \
    a[4] += (wt) * __uint_as_float(q2 << 16); a[5] += (wt) * __uint_as_float(q2 & 0xFFFF0000u); \
    a[6] += (wt) * __uint_as_float(q3 << 16); a[7] += (wt) * __uint_as_float(q3 & 0xFFFF0000u); }
    if (fit) {
        int p = 0;
        for (; p + 8 <= n; p += 8) {
            int s0 = ssrc[wv][p],     s1 = ssrc[wv][p + 1], s2 = ssrc[wv][p + 2], s3 = ssrc[wv][p + 3];
            int s4 = ssrc[wv][p + 4], s5 = ssrc[wv][p + 5], s6 = ssrc[wv][p + 6], s7 = ssrc[wv][p + 7];
            uint4 r0 = *(const uint4*)&hrow[(size_t)s0 * 512];
            uint4 r1 = *(const uint4*)&hrow[(size_t)s1 * 512];
            uint4 r2 = *(const uint4*)&hrow[(size_t)s2 * 512];
            uint4 r3 = *(const uint4*)&hrow[(size_t)s3 * 512];
            uint4 r4 = *(const uint4*)&hrow[(size_t)s4 * 512];
            uint4 r5 = *(const uint4*)&hrow[(size_t)s5 * 512];
            uint4 r6 = *(const uint4*)&hrow[(size_t)s6 * 512];
            uint4 r7 = *(const uint4*)&hrow[(size_t)s7 * 512];
            float w0 = __expf(lg[wv][p * 4 + h] - mh);
            float w1 = __expf(lg[wv][p * 4 + 4 + h] - mh);
            float w2 = __expf(lg[wv][p * 4 + 8 + h] - mh);
            float w3 = __expf(lg[wv][p * 4 + 12 + h] - mh);
            float w4 = __expf(lg[wv][p * 4 + 16 + h] - mh);
            float w5 = __expf(lg[wv][p * 4 + 20 + h] - mh);
            float w6 = __expf(lg[wv][p * 4 + 24 + h] - mh);
            float w7 = __expf(lg[wv][p * 4 + 28 + h] - mh);
            ds += ((w0 + w1) + (w2 + w3)) + ((w4 + w5) + (w6 + w7));
            ACC8(r0, w0); ACC8(r1, w1); ACC8(r2, w2); ACC8(r3, w3);
            ACC8(r4, w4); ACC8(r5, w5); ACC8(r6, w6); ACC8(r7, w7);
        }
        for (; p + 4 <= n; p += 4) {
            int s0 = ssrc[wv][p], s1 = ssrc[wv][p + 1], s2 = ssrc[wv][p + 2], s3 = ssrc[wv][p + 3];
            uint4 r0 = *(const uint4*)&hrow[(size_t)s0 * 512];
            uint4 r1 = *(const uint4*)&hrow[(size_t)s1 * 512];
            uint4 r2 = *(const uint4*)&hrow[(size_t)s2 * 512];
            uint4 r3 = *(const uint4*)&hrow[(size_t)s3 * 512];
            float w0 = __expf(lg[wv][p * 4 + h] - mh);
            float w1 = __expf(lg[wv][p * 4 + 4 + h] - mh);
            float w2 = __expf(lg[wv][p * 4 + 8 + h] - mh);
            float w3 = __expf(lg[wv][p * 4 + 12 + h] - mh);
            ds += (w0 + w1) + (w2 + w3);
            ACC8(r0, w0); ACC8(r1, w1); ACC8(r2, w2); ACC8(r3, w3);
        }
        for (; p < n; ++p) {
            int s0 = ssrc[wv][p];
            uint4 r0 = *(const uint4*)&hrow[(size_t)s0 * 512];
            float w0 = __expf(lg[wv][p * 4 + h] - mh);
            ds += w0;
            ACC8(r0, w0);
        }
    } else {
        for (int p = 0; p < n; ++p) {
            int2 se = cs[beg + p];
            float eav = __int_as_float(se.y);
            float l4[4];
            load_al4(alsp, se.x, np2, l4);
            float l = l4[h] + adh[h] + eav * sb4[h];
            l = l > 0.f ? l : 0.2f * l;
            float w = __expf(l - mh);
            uint4 r0 = *(const uint4*)&hrow[(size_t)se.x * 512];
            ds += w;
            ACC8(r0, w);
        }
    }
#undef ACC8
    float rdn = 1.0f / (ds + 1e-16f);
    __hip_bfloat16 tmp[8];
#pragma unroll
    for (int j = 0; j < 8; ++j) tmp[j] = __float2bfloat16(a[j] * rdn);
    *(uint4*)&outb[(size_t)d * 512 + 8 * t] = *(uint4*)tmp;
}

// ---- FUSED softmax+agg+head-mean, layer 2: ONE WAVE per dst (2 dst / block) ----
__global__ __launch_bounds__(128) void fused_agg2(
        const int* __restrict__ rowptr, const int2* __restrict__ cs,
        const float* __restrict__ alsp, const float* __restrict__ aldp,
        const float* __restrict__ sbuf, const __hip_bfloat16* __restrict__ hb,
        float* __restrict__ out2, int nparts) {
    __shared__ float lg[2][MAXDEG * 4];
    __shared__ int   ssrc[2][MAXDEG];
    int wv = threadIdx.x >> 6, t = threadIdx.x & 63;
    int d = blockIdx.x * 2 + wv;
    int beg = rowptr[d], n = rowptr[d + 1] - beg;
    bool fit = (n <= MAXDEG);
    bool np2 = (nparts == 2);
    float adh[4];
    load_al4(aldp, d, np2, adh);
    float sb4[4] = {sbuf[4], sbuf[5], sbuf[6], sbuf[7]};
    float mx[4] = {-INFINITY, -INFINITY, -INFINITY, -INFINITY};
    for (int p = t; p < n; p += 64) {
        int2 se = cs[beg + p];
        float eav = __int_as_float(se.y);
        float l[4];
        load_al4(alsp, se.x, np2, l);
#pragma unroll
        for (int hh = 0; hh < 4; ++hh) {
            float v = l[hh] + adh[hh] + eav * sb4[hh];
            v = v > 0.f ? v : 0.2f * v;
            l[hh] = v;
            mx[hh] = fmaxf(mx[hh], v);
        }
        if (fit) {
            *(float4*)&lg[wv][p * 4] = make_float4(l[0], l[1], l[2], l[3]);
            ssrc[wv][p] = se.x;
        }
    }
#pragma unroll
    for (int m = 1; m < 64; m <<= 1)
#pragma unroll
        for (int hh = 0; hh < 4; ++hh)
            mx[hh] = fmaxf(mx[hh], __shfl_xor(mx[hh], m));
    asm volatile("s_waitcnt lgkmcnt(0)" ::: "memory");
    int h = t >> 4;                       // 4 channels/lane, 64 ch/head -> head = t>>4
    float mh = mx[h];
    float a4[4] = {};
    float ds = 0.f;
    const __hip_bfloat16* hrow = hb + 4 * t;
#define ACC4(rr, wt) { \
    unsigned q0 = (rr).x, q1 = (rr).y; \
    a4[0] += (wt) * __uint_as_float(q0 << 16); a4[1] += (wt) * __uint_as_float(q0 & 0xFFFF0000u); \
    a4[2] += (wt) * __uint_as_float(q1 << 16); a4[3] += (wt) * __uint_as_float(q1 & 0xFFFF0000u); }
    if (fit) {
        int p = 0;
        for (; p + 8 <= n; p += 8) {
            int s0 = ssrc[wv][p],     s1 = ssrc[wv][p + 1], s2 = ssrc[wv][p + 2], s3 = ssrc[wv][p + 3];
            int s4 = ssrc[wv][p + 4], s5 = ssrc[wv][p + 5], s6 = ssrc[wv][p + 6], s7 = ssrc[wv][p + 7];
            uint2 r0 = *(const uint2*)&hrow[(size_t)s0 * 256];
            uint2 r1 = *(const uint2*)&hrow[(size_t)s1 * 256];
            uint2 r2 = *(const uint2*)&hrow[(size_t)s2 * 256];
            uint2 r3 = *(const uint2*)&hrow[(size_t)s3 * 256];
            uint2 r4 = *(const uint2*)&hrow[(size_t)s4 * 256];
            uint2 r5 = *(const uint2*)&hrow[(size_t)s5 * 256];
            uint2 r6 = *(const uint2*)&hrow[(size_t)s6 * 256];
            uint2 r7 = *(const uint2*)&hrow[(size_t)s7 * 256];
            float w0 = __expf(lg[wv][p * 4 + h] - mh);
            float w1 = __expf(lg[wv][p * 4 + 4 + h] - mh);
            float w2 = __expf(lg[wv][p * 4 + 8 + h] - mh);
            float w3 = __expf(lg[wv][p * 4 + 12 + h] - mh);
            float w4 = __expf(lg[wv][p * 4 + 16 + h] - mh);
            float w5 = __expf(lg[wv][p * 4 + 20 + h] - mh);
            float w6 = __expf(lg[wv][p * 4 + 24 + h] - mh);
            float w7 = __expf(lg[wv][p * 4 + 28 + h] - mh);
            ds += ((w0 + w1) + (w2 + w3)) + ((w4 + w5) + (w6 + w7));
            ACC4(r0, w0); ACC4(r1, w1); ACC4(r2, w2); ACC4(r3, w3);
            ACC4(r4, w4); ACC4(r5, w5); ACC4(r6, w6); ACC4(r7, w7);
        }
        for (; p + 4 <= n; p += 4) {
            int s0 = ssrc[wv][p], s1 = ssrc[wv][p + 1], s2 = ssrc[wv][p + 2], s3 = ssrc[wv][p + 3];
            uint2 r0 = *(const uint2*)&hrow[(size_t)s0 * 256];
            uint2 r1 = *(const uint2*)&hrow[(size_t)s1 * 256];
            uint2 r2 = *(const uint2*)&hrow[(size_t)s2 * 256];
            uint2 r3 = *(const uint2*)&hrow[(size_t)s3 * 256];
            float w0 = __expf(lg[wv][p * 4 + h] - mh);
            float w1 = __expf(lg[wv][p * 4 + 4 + h] - mh);
            float w2 = __expf(lg[wv][p * 4 + 8 + h] - mh);
            float w3 = __expf(lg[wv][p * 4 + 12 + h] - mh);
            ds += (w0 + w1) + (w2 + w3);
            ACC4(r0, w0); ACC4(r1, w1); ACC4(r2, w2); ACC4(r3, w3);
        }
        for (; p < n; ++p) {
            int s0 = ssrc[wv][p];
            uint2 r0 = *(const uint2*)&hrow[(size_t)s0 * 256];
            float w0 = __expf(lg[wv][p * 4 + h] - mh);
            ds += w0;
            ACC4(r0, w0);
        }
    } else {
        for (int p = 0; p < n; ++p) {
            int2 se = cs[beg + p];
            float eav = __int_as_float(se.y);
            float l4[4];
            load_al4(alsp, se.x, np2, l4);
            float l = l4[h] + adh[h] + eav * sb4[h];
            l = l > 0.f ? l : 0.2f * l;
            float w = __expf(l - mh);
            uint2 r0 = *(const uint2*)&hrow[(size_t)se.x * 256];
            ds += w;
            ACC4(r0, w);
        }
    }
#undef ACC4
    float rdn = 1.0f / (ds + 1e-16f);
#pragma unroll
    for (int j = 0; j < 4; ++j) {
        float v = a4[j] * rdn;
        v += __shfl_xor(v, 16);
        v += __shfl_xor(v, 32);
        a4[j] = v * 0.25f;
    }
    if (t < 16)
        *(float4*)&out2[(size_t)d * 64 + 4 * t] = make_float4(a4[0], a4[1], a4[2], a4[3]);
}

// ---- BN1 stats: per-block partials ----
__global__ __launch_bounds__(256) void bn_part_b(const __hip_bfloat16* __restrict__ x,
                                                 float* __restrict__ pmu, float* __restrict__ pm2) {
    int t = threadIdx.x, b = blockIdx.x;
    float s0 = 0.f, s20 = 0.f, s1 = 0.f, s21 = 0.f;
    for (int i = b; i < N_NODES; i += gridDim.x) {
        unsigned u = *(const unsigned*)&x[(size_t)i * 512 + 2 * t];
        float v0 = __uint_as_float(u << 16);
        float v1 = __uint_as_float(u & 0xFFFF0000u);
        s0 += v0; s20 += v0 * v0; s1 += v1; s21 += v1 * v1;
    }
    pmu[b * 512 + 2 * t] = s0;     pm2[b * 512 + 2 * t] = s20;
    pmu[b * 512 + 2 * t + 1] = s1; pm2[b * 512 + 2 * t + 1] = s21;
}

// ---- reduce partials -> affine a,b : parallel (4 splits/channel, fixed-order combine) ----
__global__ __launch_bounds__(256) void bn_reduce_affine(const float* __restrict__ pmu, const float* __restrict__ pm2,
                                 const float* __restrict__ smalls, int s_g, int s_be,
                                 float* __restrict__ a, float* __restrict__ b, int nch) {
    __shared__ float shs[4][64], sh2[4][64];
    int t = threadIdx.x;
    int cl = t & 63, j = t >> 6;
    int c = blockIdx.x * 64 + cl;
    float s = 0.f, s2 = 0.f;
    for (int bk = j * 64; bk < (j + 1) * 64; ++bk) { s += pmu[bk * nch + c]; s2 += pm2[bk * nch + c]; }
    shs[j][cl] = s; sh2[j][cl] = s2;
    __syncthreads();
    if (j == 0) {
        float st  = ((shs[0][cl] + shs[1][cl]) + (shs[2][cl] + shs[3][cl]));
        float st2 = ((sh2[0][cl] + sh2[1][cl]) + (sh2[2][cl] + sh2[3][cl]));
        float m = st * (1.0f / N_NODES);
        float var = st2 * (1.0f / N_NODES) - m * m;
        float aa = smalls[s_g + c] * rsqrtf(var + 1e-5f);
        a[c] = aa;
        b[c] = smalls[s_be + c] - m * aa;
    }
}

// ---- BN2 stats: per-block partials ----
__global__ __launch_bounds__(256) void bn2_stats(const float* __restrict__ x,
                                                 float* __restrict__ pmu, float* __restrict__ pm2) {
    int t = threadIdx.x;
    int c = t & 63, j = t >> 6;
    float ls = 0.f, ls2 = 0.f;
    for (int nd = blockIdx.x * 4 + j; nd < N_NODES; nd += gridDim.x * 4) {
        float v = x[(size_t)nd * 64 + c];
        ls += v; ls2 += v * v;
    }
    __shared__ float shs[4][64], sh2[4][64];
    shs[j][c] = ls; sh2[j][c] = ls2;
    __syncthreads();
    if (j == 0) {
        pmu[blockIdx.x * 64 + c] = shs[0][c] + shs[1][c] + shs[2][c] + shs[3][c];
        pm2[blockIdx.x * 64 + c] = sh2[0][c] + sh2[1][c] + sh2[2][c] + sh2[3][c];
    }
}

// ---- pool stage 1: 8 chunks per graph, BN2 affine+ELU fused, partial sums ----
__global__ __launch_bounds__(256) void pool_part(const float* __restrict__ x, const int* __restrict__ gstart,
                                                 const float* __restrict__ a2, const float* __restrict__ b2,
                                                 float* __restrict__ pp) {
    int g = blockIdx.x >> 3, ck = blockIdx.x & 7;
    int t = threadIdx.x;
    int c = t & 63, j = t >> 6;
    int beg = gstart[g], end = gstart[g + 1], n = end - beg;
    int cb = beg + (n * ck) / 8, ce = beg + (n * (ck + 1)) / 8;
    float ac = a2[c], bc = b2[c];
    float s = 0.f;
    for (int i = cb + j; i < ce; i += 4) {
        float y = ac * x[(size_t)i * 64 + c] + bc;
        s += (y > 0.f ? y : expm1f(y));
    }
    __shared__ float sh[4][64];
    sh[j][c] = s;
    __syncthreads();
    if (j == 0)
        pp[blockIdx.x * 64 + c] = sh[0][c] + sh[1][c] + sh[2][c] + sh[3][c];
}

// ---- pool stage 2: reduce 8 chunks (fixed order) + MLP ----
__global__ __launch_bounds__(64) void pool_mlp_fin(const float* __restrict__ pp, const int* __restrict__ gstart,
                                                   const float* __restrict__ smalls, const int* __restrict__ flag,
                                                   void* __restrict__ outp) {
    int g = blockIdx.x, t = threadIdx.x;
    __shared__ float pooled[64];
    __shared__ float hsh[32];
    float s = 0.f;
    for (int k = 0; k < 8; ++k) s += pp[(g * 8 + k) * 64 + t];
    int n = gstart[g + 1] - gstart[g];
    pooled[t] = s / fmaxf((float)n, 1.0f);
    __syncthreads();
    if (t < 32) {
        float acc = smalls[S_FB1 + t];
        for (int cc = 0; cc < 64; ++cc)
            acc += pooled[cc] * smalls[S_FW1 + cc * 32 + t];
        hsh[t] = acc > 0.f ? acc : expm1f(acc);
    }
    __syncthreads();
    if (t == 0) {
        float o = smalls[S_FB2];
        for (int k = 0; k < 32; ++k) o += hsh[k] * smalls[S_FW2 + k];
        if (flag[0]) ((float*)outp)[g] = o;
        else ((__hip_bfloat16*)outp)[g] = __float2bfloat16(o);
    }
}

extern "C" void kernel_launch(void* const* d_in, const int* in_sizes, int n_in,
                              void* d_out, int out_size, void* d_ws, size_t ws_size,
                              hipStream_t stream) {
    const void* x    = d_in[0];
    const int* ei    = (const int*)d_in[1];
    const int* batch = (const int*)d_in[2];
    const void* ea   = d_in[3];
    const void* W1   = d_in[4];
    const void* as1  = d_in[5];
    const void* ad1  = d_in[6];
    const void* We1  = d_in[7];
    const void* ae1  = d_in[8];
    const void* g1   = d_in[10];
    const void* be1  = d_in[11];
    const void* W2   = d_in[12];
    const void* as2  = d_in[13];
    const void* ad2  = d_in[14];
    const void* We2  = d_in[15];
    const void* ae2  = d_in[16];
    const void* g2   = d_in[18];
    const void* be2  = d_in[19];
    const void* fw1  = d_in[20];
    const void* fb1  = d_in[21];
    const void* fw2  = d_in[22];
    const void* fb2  = d_in[23];

    char* ws = (char*)d_ws;
    __hip_bfloat16* xb   = (__hip_bfloat16*)(ws + XB_OFF);
    __hip_bfloat16* hb1  = (__hip_bfloat16*)(ws + HB1_OFF);
    __hip_bfloat16* agg1 = (__hip_bfloat16*)(ws + AGG1_OFF);
    __hip_bfloat16* hb2  = (__hip_bfloat16*)(ws + HB2_OFF);
    float* out2   = (float*)(ws + OUT2_OFF);
    float* eaf    = (float*)(ws + EAF_OFF);
    __hip_bfloat16* W1bt = (__hip_bfloat16*)(ws + W1BT_OFF);
    __hip_bfloat16* W2bt = (__hip_bfloat16*)(ws + W2BT_OFF);
    int2*  csr_se = (int2*)(ws + CSR_OFF);
    int*   rowptr = (int*)(ws + ROWPTR_OFF);
    int*   gstart = (int*)(ws + GSTART_OFF);
    float* smalls = (float*)(ws + SMALL_OFF);
    float* sbuf   = (float*)(ws + SBUF_OFF);
    float* eap    = (float*)(ws + EAP_OFF);
    float* alsp   = (float*)(ws + ALSP_OFF);
    float* aldp   = (float*)(ws + ALDP_OFF);
    float* pmu1   = (float*)(ws + PMU1_OFF);
    float* pm21   = (float*)(ws + PM21_OFF);
    float* pmu2   = (float*)(ws + PMU2_OFF);
    float* pm22   = (float*)(ws + PM22_OFF);
    float* a1     = (float*)(ws + A1_OFF);
    float* b1     = (float*)(ws + B1_OFF);
    float* a2     = (float*)(ws + A2_OFF);
    float* b2     = (float*)(ws + B2_OFF);
    float* ea_acc = (float*)(ws + EAACC_OFF);
    float* pp     = (float*)(ws + PP_OFF);
    int*   deg    = (int*)(ws + DEG_OFF);
    int*   cursor = (int*)(ws + CURS_OFF);
    int*   flag   = (int*)(ws + FLAGZ_OFF);

    hipMemsetAsync(ws + ZERO0_START, 0, ZERO0_SIZE, stream);

    detect_hist<<<DH_DETECT + HIST_BLOCKS + 79, 256, 0, stream>>>(
        (const unsigned short*)x, flag, ei, deg, batch, gstart);
    prep<<<PREP_BLOCKS, 256, 0, stream>>>(flag, x, ea, W1, W2,
                                          as1, ad1, We1, ae1, g1, be1, as2, ad2,
                                          We2, ae2, g2, be2, fw1, fb1, fw2, fb2,
                                          xb, eaf, eap, W1bt, W2bt, smalls, sbuf);
    deg_scan<<<1, 1024, 0, stream>>>(deg, rowptr, eap, ea_acc);

    // ---------- layer 1 (GEMM overlapped with edge_scatter) ----------
    gemm1_scatter<<<G1_BLOCKS + HIST_BLOCKS, 256, 0, stream>>>(
        (const short*)xb, (const short*)W1bt, hb1,
        alsp, aldp, smalls + S_AS1, smalls + S_AD1,
        ei, rowptr, cursor, csr_se);
    csr_sort_fill<<<N_NODES, 64, 0, stream>>>(rowptr, csr_se, eaf, ea_acc);
    fused_agg1<<<N_NODES / 2, 128, 0, stream>>>(rowptr, csr_se, alsp, aldp, sbuf, hb1, agg1, 2);
    bn_part_b<<<256, 256, 0, stream>>>(agg1, pmu1, pm21);
    bn_reduce_affine<<<8, 256, 0, stream>>>(pmu1, pm21, smalls, S_G1, S_BE1, a1, b1, 512);

    // ---------- layer 2 (BN1+ELU folded into A-staging) ----------
    gemm_mfma_al<<<dim3(256 / 64, MPAD / 128), 256, 0, stream>>>(
        (const short*)agg1, (const short*)W2bt, hb2, 256, 512,
        alsp, aldp, smalls + S_AS2, smalls + S_AD2, 6, a1, b1);
    fused_agg2<<<N_NODES / 2, 128, 0, stream>>>(rowptr, csr_se, alsp, aldp, sbuf, hb2, out2, 1);
    bn2_stats<<<256, 256, 0, stream>>>(out2, pmu2, pm22);
    bn_reduce_affine<<<1, 256, 0, stream>>>(pmu2, pm22, smalls, S_G2, S_BE2, a2, b2, 64);

    // ---------- BN2+ELU+pool (2-stage) + MLP ----------
    pool_part<<<N_GRAPHS * 8, 256, 0, stream>>>(out2, gstart, a2, b2, pp);
    pool_mlp_fin<<<N_GRAPHS, 64, 0, stream>>>(pp, gstart, smalls, flag, d_out);
}